// Round 6
// baseline (241.363 us; speedup 1.0000x reference)
//
#include <hip/hip_runtime.h>
#include <hip/hip_bf16.h>

// EnhancedEdgeLayer R6: composed-conv interior + R5-path border.
// x [8,1,512,512] f32 -> out [8,16,512,512] f32
//
// Key algebra: conv1(feats) where feats = [bank⊛x_pad, x] is linear∘linear =
// (w1∘bank) ⊛ x : a single 7x7 conv (K=49->2 MFMA K-steps of 32). Valid for all
// h positions whose 3x3 feats window stays inside the image -> all tiles not
// touching the border. Interior kernel (30x30x8): no fs2 LDS phase, no masks,
// LDS 22KB -> 7 blocks/CU. Border tiles (124x8 blocks) use the R5 3-phase path.

typedef __attribute__((ext_vector_type(8))) short bf16x8;
typedef __attribute__((ext_vector_type(4))) float f32x4;

#define XS_S 28   // shorts per xs row (24 data + 4 zero pad; 8B-aligned quads)

// ws layout (shorts):
//  A1   [2][5][64][8]  @ 0      (5120)   border conv1 fragments
//  A2   [9][64][8]     @ 5120   (4608)   conv2 fragments (both kernels)
//  SB   [64][8]        @ 9728   (512)    border stencil-bank fragments
//  FLT  floats         @ short 10240: per-lane 20 floats (b1v[2][4],b2v,wrv,brv)
//  WEFF [2][2][64][8]  @ 12800  (2048)   interior composed 7x7 fragments
#define WS_A2   5120
#define WS_SB   9728
#define WS_FLT  5120      // float offset
#define WS_WEFF 12800
#define WS_BYTES 30720

__device__ const float EB[9][5][5] = {
 {{0,0,0,0,0},{0,-1,0,1,0},{0,-2,0,2,0},{0,-1,0,1,0},{0,0,0,0,0}},        // sobel_x
 {{0,0,0,0,0},{0,-1,-2,-1,0},{0,0,0,0,0},{0,1,2,1,0},{0,0,0,0,0}},        // sobel_y
 {{0,0,0,0,0},{0,0,1,2,0},{0,-1,0,1,0},{0,-2,-1,0,0},{0,0,0,0,0}},        // diag1
 {{0,0,0,0,0},{0,-2,-1,0,0},{0,-1,0,1,0},{0,0,1,2,0},{0,0,0,0,0}},        // diag2
 {{0,0,0,0,0},{0,0,1,0,0},{0,1,-4,1,0},{0,0,1,0,0},{0,0,0,0,0}},          // laplacian
 {{-1,-2,0,2,1},{-2,-3,0,3,2},{-3,-4,0,4,3},{-2,-3,0,3,2},{-1,-2,0,2,1}}, // gradient5x5
 {{0,0,0,0,0},{0,-3,0,3,0},{0,-10,0,10,0},{0,-3,0,3,0},{0,0,0,0,0}},      // scharr_x
 {{0,0,0,0,0},{0,-3,-10,-3,0},{0,0,0,0,0},{0,3,10,3,0},{0,0,0,0,0}},      // scharr_y
 {{0,0,0,0,0},{0,0,0,0,0},{0,0,1,0,0},{0,0,0,0,0},{0,0,0,0,0}},           // identity
};

__device__ __forceinline__ unsigned short f2bf(float f) {
    union { float f; unsigned u; } v; v.f = f;
    unsigned u = v.u + 0x7fffu + ((v.u >> 16) & 1u);   // RNE
    return (unsigned short)(u >> 16);
}

__device__ __forceinline__ float weff_tap(const float* __restrict__ w1,
                                          int oc, int dy, int dx) {
    float s = 0.f;
    for (int ch = 0; ch < 9; ++ch)
        for (int ty = 0; ty < 3; ++ty)
            for (int tx = 0; tx < 3; ++tx) {
                int sy = dy - ty, sx = dx - tx;
                if (sy >= 0 && sy < 5 && sx >= 0 && sx < 5)
                    s += w1[(oc * 9 + ch) * 9 + ty * 3 + tx] * EB[ch][sy][sx];
            }
    return s;
}

__global__ __launch_bounds__(64) void setup_frags(
    const float* __restrict__ w1, const float* __restrict__ b1,
    const float* __restrict__ w2, const float* __restrict__ b2,
    const float* __restrict__ wr, const float* __restrict__ br,
    short* __restrict__ ws)
{
    const int lane = threadIdx.x;
    const int n = lane & 15, lg = lane >> 4;
    for (int mt = 0; mt < 2; ++mt)
        for (int ks = 0; ks < 5; ++ks)
            for (int i = 0; i < 8; ++i) {
                int k = 32 * ks + 8 * lg + i;
                int g = k >> 4, ch = k & 15;
                float w = (g < 9 && ch < 9) ? w1[(mt * 16 + n) * 81 + ch * 9 + g] : 0.f;
                ws[((mt * 5 + ks) * 64 + lane) * 8 + i] = (short)f2bf(w);
            }
    for (int ks = 0; ks < 9; ++ks)
        for (int i = 0; i < 8; ++i) {
            int ic = 8 * lg + i;
            ws[WS_A2 + (ks * 64 + lane) * 8 + i] = (short)f2bf(w2[n * 288 + ic * 9 + ks]);
        }
    for (int i = 0; i < 8; ++i) {
        int k = 8 * lg + i;
        float v = (k < 25 && n < 9) ? EB[n][k / 5][k % 5] : 0.f;
        ws[WS_SB + lane * 8 + i] = (short)f2bf(v);
    }
    // composed 7x7: k = dy*8+dx (dy=4*ks+lg, dx=i; dy/dx==7 -> 0)
    for (int mt = 0; mt < 2; ++mt)
        for (int ks = 0; ks < 2; ++ks)
            for (int i = 0; i < 8; ++i) {
                int dy = 4 * ks + lg, dx = i;
                float s = (dy < 7 && dx < 7) ? weff_tap(w1, mt * 16 + n, dy, dx) : 0.f;
                ws[WS_WEFF + ((mt * 2 + ks) * 64 + lane) * 8 + i] = (short)f2bf(s);
            }
    float* wf = (float*)ws + WS_FLT + lane * 20;
    for (int r = 0; r < 4; ++r) {
        wf[r]      = b1[lg * 4 + r];
        wf[4 + r]  = b1[16 + lg * 4 + r];
        wf[8 + r]  = b2[lg * 4 + r];
        wf[12 + r] = wr[lg * 4 + r];
        wf[16 + r] = br[lg * 4 + r];
    }
}

// ---------------- interior kernel (composed 7x7, no masks) ----------------
template<bool USE_WS>
__global__ __launch_bounds__(256, 6) void edge_interior(
    const float* __restrict__ x,  const float* __restrict__ w1, const float* __restrict__ b1,
    const float* __restrict__ w2, const float* __restrict__ b2,
    const float* __restrict__ wr, const float* __restrict__ br,
    const short* __restrict__ ws, float* __restrict__ out)
{
    __shared__ short hs4[4 * 324 * 8];   // 20736 B [ic-block][px 18x18][8]
    __shared__ short xs[24 * XS_S];      //  1344 B bf16 x tile

    const int tid  = threadIdx.x;
    const int lane = tid & 63;
    const int wave = tid >> 6;
    const int n    = lane & 15;
    const int lg   = lane >> 4;
    const int bx = (blockIdx.x + 1) * 16, by = (blockIdx.y + 1) * 16, b = blockIdx.z;

    // ---- P0: x tile -> bf16 LDS, fully in-bounds, vectorized ----
    if (tid < 144) {
        int r = tid / 6, q = tid % 6;
        const float4 v = *reinterpret_cast<const float4*>(
            &x[((size_t)b * 512 + by - 4 + r) * 512 + bx - 4 + 4 * q]);
        __hip_bfloat162 p0 = __float22bfloat162_rn(make_float2(v.x, v.y));
        __hip_bfloat162 p1 = __float22bfloat162_rn(make_float2(v.z, v.w));
        uint2 wv; wv.x = *reinterpret_cast<unsigned*>(&p0);
        wv.y = *reinterpret_cast<unsigned*>(&p1);
        *reinterpret_cast<uint2*>(&xs[r * XS_S + 4 * q]) = wv;
    } else if (tid < 168) {
        int r = tid - 144;
        uint2 z; z.x = 0u; z.y = 0u;
        *reinterpret_cast<uint2*>(&xs[r * XS_S + 24]) = z;   // zero pad cols 24..27
    }

    // ---- P1: fragments -> registers ----
    bf16x8 wa[2][2], a2[9];
    float b1v[2][4], b2v[4], wrv[4], brv[4];
    if (USE_WS) {
#pragma unroll
        for (int mt = 0; mt < 2; ++mt)
#pragma unroll
            for (int ks = 0; ks < 2; ++ks)
                wa[mt][ks] = *reinterpret_cast<const bf16x8*>(
                    &ws[WS_WEFF + ((mt * 2 + ks) * 64 + lane) * 8]);
#pragma unroll
        for (int ks = 0; ks < 9; ++ks)
            a2[ks] = *reinterpret_cast<const bf16x8*>(&ws[WS_A2 + (ks * 64 + lane) * 8]);
        const float* wf = (const float*)ws + WS_FLT + lane * 20;
        f32x4 t0 = *reinterpret_cast<const f32x4*>(wf);
        f32x4 t1 = *reinterpret_cast<const f32x4*>(wf + 4);
        f32x4 t2 = *reinterpret_cast<const f32x4*>(wf + 8);
        f32x4 t3 = *reinterpret_cast<const f32x4*>(wf + 12);
        f32x4 t4 = *reinterpret_cast<const f32x4*>(wf + 16);
#pragma unroll
        for (int r = 0; r < 4; ++r) {
            b1v[0][r] = t0[r]; b1v[1][r] = t1[r];
            b2v[r] = t2[r]; wrv[r] = t3[r]; brv[r] = t4[r];
        }
    } else {
#pragma unroll
        for (int mt = 0; mt < 2; ++mt)
#pragma unroll
            for (int ks = 0; ks < 2; ++ks)
#pragma unroll
                for (int i = 0; i < 8; ++i) {
                    int dy = 4 * ks + lg, dx = i;
                    float s = (dy < 7 && dx < 7) ? weff_tap(w1, mt * 16 + n, dy, dx) : 0.f;
                    wa[mt][ks][i] = (short)f2bf(s);
                }
#pragma unroll
        for (int ks = 0; ks < 9; ++ks)
#pragma unroll
            for (int i = 0; i < 8; ++i)
                a2[ks][i] = (short)f2bf(w2[n * 288 + (8 * lg + i) * 9 + ks]);
#pragma unroll
        for (int r = 0; r < 4; ++r) {
            b1v[0][r] = b1[lg * 4 + r]; b1v[1][r] = b1[16 + lg * 4 + r];
            b2v[r] = b2[lg * 4 + r]; wrv[r] = wr[lg * 4 + r]; brv[r] = br[lg * 4 + r];
        }
    }

    __syncthreads();

    // ---- P3: conv1 = 7x7 composed MFMA -> hs4 ----
    for (int t = wave; t < 21; t += 4) {
        int p  = t * 16 + n;
        int pc = p < 323 ? p : 323;
        int r1 = pc / 18, c1 = pc - 18 * r1;
        int base = r1 * XS_S + c1;
        f32x4 acc0 = {0.f,0.f,0.f,0.f}, acc1 = {0.f,0.f,0.f,0.f};
#pragma unroll
        for (int ks = 0; ks < 2; ++ks) {
            const int dy = 4 * ks + lg;
            bf16x8 bv = {0,0,0,0,0,0,0,0};
            if (dy < 7) {                       // dy==7 lanes: A rows are 0
                const short* rp = &xs[base + dy * XS_S];
#pragma unroll
                for (int i = 0; i < 8; ++i) bv[i] = rp[i];
            }
            acc0 = __builtin_amdgcn_mfma_f32_16x16x32_bf16(wa[0][ks], bv, acc0, 0, 0, 0);
            acc1 = __builtin_amdgcn_mfma_f32_16x16x32_bf16(wa[1][ks], bv, acc1, 0, 0, 0);
        }
        if (p < 324) {
            __hip_bfloat162 q0 = __float22bfloat162_rn(make_float2(
                fmaxf(acc0[0] + b1v[0][0], 0.f), fmaxf(acc0[1] + b1v[0][1], 0.f)));
            __hip_bfloat162 q1 = __float22bfloat162_rn(make_float2(
                fmaxf(acc0[2] + b1v[0][2], 0.f), fmaxf(acc0[3] + b1v[0][3], 0.f)));
            uint2 W0; W0.x = *reinterpret_cast<unsigned*>(&q0);
            W0.y = *reinterpret_cast<unsigned*>(&q1);
            *reinterpret_cast<uint2*>(&hs4[((lg >> 1) * 324 + p) * 8 + 4 * (lg & 1)]) = W0;
            __hip_bfloat162 q2 = __float22bfloat162_rn(make_float2(
                fmaxf(acc1[0] + b1v[1][0], 0.f), fmaxf(acc1[1] + b1v[1][1], 0.f)));
            __hip_bfloat162 q3 = __float22bfloat162_rn(make_float2(
                fmaxf(acc1[2] + b1v[1][2], 0.f), fmaxf(acc1[3] + b1v[1][3], 0.f)));
            uint2 W1; W1.x = *reinterpret_cast<unsigned*>(&q2);
            W1.y = *reinterpret_cast<unsigned*>(&q3);
            *reinterpret_cast<uint2*>(&hs4[((2 + (lg >> 1)) * 324 + p) * 8 + 4 * (lg & 1)]) = W1;
        }
    }
    __syncthreads();

    // ---- P4: conv2 MFMA + epilogue ----
    const int hbase = lg * 324 * 8;
#pragma unroll
    for (int j = 0; j < 4; ++j) {
        int oy = wave + 4 * j;
        f32x4 acc = {0.f,0.f,0.f,0.f};
#pragma unroll
        for (int ks = 0; ks < 9; ++ks) {
            const int dy = ks / 3, dx = ks - 3 * (ks / 3);
            bf16x8 hf = *reinterpret_cast<const bf16x8*>(
                &hs4[hbase + ((oy + dy) * 18 + n + dx) * 8]);
            acc = __builtin_amdgcn_mfma_f32_16x16x32_bf16(a2[ks], hf, acc, 0, 0, 0);
        }
        __hip_bfloat16 xh = *reinterpret_cast<const __hip_bfloat16*>(&xs[(oy + 4) * XS_S + n + 4]);
        float xv = __bfloat162float(xh);
        float* op = out + (((size_t)(b * 16 + lg * 4) * 512 + (by + oy)) * 512) + bx + n;
#pragma unroll
        for (int r = 0; r < 4; ++r) {
            float o = fmaxf(acc[r] + b2v[r], 0.f) + wrv[r] * xv + brv[r];
            __builtin_nontemporal_store(o, op);
            op += 262144;   // next oc plane
        }
    }
}

// ---------------- border kernel (R5 path, remapped to 124 border tiles) ----------------
template<bool USE_WS>
__global__ __launch_bounds__(256, 4) void edge_border(
    const float* __restrict__ x,  const float* __restrict__ w1, const float* __restrict__ b1,
    const float* __restrict__ w2, const float* __restrict__ b2,
    const float* __restrict__ wr, const float* __restrict__ br,
    const short* __restrict__ ws, float* __restrict__ out)
{
    __shared__ short fs2[2 * 400 * 8];   // 12800 B [ch-half][px 20x20][8]
    __shared__ short hs4[4 * 324 * 8];   // 20736 B
    __shared__ short xs[24 * XS_S];

    const int tid  = threadIdx.x;
    const int lane = tid & 63;
    const int wave = tid >> 6;
    const int n    = lane & 15;
    const int lg   = lane >> 4;

    int idx = blockIdx.x, tx, ty;
    if      (idx < 32) { tx = idx;      ty = 0;  }
    else if (idx < 64) { tx = idx - 32; ty = 31; }
    else if (idx < 94) { tx = 0;        ty = idx - 63; }
    else               { tx = 31;       ty = idx - 93; }
    const int bx = tx * 16, by = ty * 16, b = blockIdx.z;

    // ---- P0: x tile -> bf16 LDS (zero-padded at image borders) ----
    for (int i = tid; i < 576; i += 256) {
        int r = i / 24, c = i % 24;
        int gy = by - 4 + r, gx = bx - 4 + c;
        float v = 0.f;
        if (gy >= 0 && gy < 512 && gx >= 0 && gx < 512) v = x[((size_t)b * 512 + gy) * 512 + gx];
        __hip_bfloat16 h = __float2bfloat16(v);
        xs[r * XS_S + c] = *reinterpret_cast<short*>(&h);
    }

    // ---- P1: fragments ----
    bf16x8 a1[2][5], a2[9], sb;
    float b1v[2][4], b2v[4], wrv[4], brv[4];
    if (USE_WS) {
#pragma unroll
        for (int mt = 0; mt < 2; ++mt)
#pragma unroll
            for (int ks = 0; ks < 5; ++ks)
                a1[mt][ks] = *reinterpret_cast<const bf16x8*>(&ws[((mt * 5 + ks) * 64 + lane) * 8]);
#pragma unroll
        for (int ks = 0; ks < 9; ++ks)
            a2[ks] = *reinterpret_cast<const bf16x8*>(&ws[WS_A2 + (ks * 64 + lane) * 8]);
        sb = *reinterpret_cast<const bf16x8*>(&ws[WS_SB + lane * 8]);
        const float* wf = (const float*)ws + WS_FLT + lane * 20;
        f32x4 t0 = *reinterpret_cast<const f32x4*>(wf);
        f32x4 t1 = *reinterpret_cast<const f32x4*>(wf + 4);
        f32x4 t2 = *reinterpret_cast<const f32x4*>(wf + 8);
        f32x4 t3 = *reinterpret_cast<const f32x4*>(wf + 12);
        f32x4 t4 = *reinterpret_cast<const f32x4*>(wf + 16);
#pragma unroll
        for (int r = 0; r < 4; ++r) {
            b1v[0][r] = t0[r]; b1v[1][r] = t1[r];
            b2v[r] = t2[r]; wrv[r] = t3[r]; brv[r] = t4[r];
        }
    } else {
#pragma unroll
        for (int mt = 0; mt < 2; ++mt)
#pragma unroll
            for (int ks = 0; ks < 5; ++ks)
#pragma unroll
                for (int i = 0; i < 8; ++i) {
                    int k = 32 * ks + 8 * lg + i;
                    int g = k >> 4, ch = k & 15;
                    float w = (g < 9 && ch < 9) ? w1[(mt * 16 + n) * 81 + ch * 9 + g] : 0.f;
                    a1[mt][ks][i] = (short)f2bf(w);
                }
#pragma unroll
        for (int ks = 0; ks < 9; ++ks)
#pragma unroll
            for (int i = 0; i < 8; ++i)
                a2[ks][i] = (short)f2bf(w2[n * 288 + (8 * lg + i) * 9 + ks]);
#pragma unroll
        for (int i = 0; i < 8; ++i) {
            int k = 8 * lg + i;
            float v = (k < 25 && n < 9) ? EB[n][k / 5][k % 5] : 0.f;
            sb[i] = (short)f2bf(v);
        }
#pragma unroll
        for (int r = 0; r < 4; ++r) {
            b1v[0][r] = b1[lg * 4 + r]; b1v[1][r] = b1[16 + lg * 4 + r];
            b2v[r] = b2[lg * 4 + r]; wrv[r] = wr[lg * 4 + r]; brv[r] = br[lg * 4 + r];
        }
    }

    int toff[8];
#pragma unroll
    for (int i = 0; i < 8; ++i) {
        int k = 8 * lg + i;
        int t = k < 25 ? k : 24;
        toff[i] = (t / 5) * XS_S + (t % 5);
    }
    int boff[5];
#pragma unroll
    for (int ks = 0; ks < 5; ++ks) {
        int g = 2 * ks + (lg >> 1); if (g > 8) g = 8;
        int dy = g / 3, dx = g - 3 * dy;
        boff[ks] = (lg & 1) * 3200 + (dy * 20 + dx) * 8;
    }

    __syncthreads();

    // ---- P2: stencils via MFMA -> fs2 ----
    for (int t = wave; t < 25; t += 4) {
        int px = t * 16 + n;
        int r = px / 20, c = px - 20 * r;
        const short* base = &xs[r * XS_S + c];
        bf16x8 bv;
#pragma unroll
        for (int i = 0; i < 8; ++i) bv[i] = base[toff[i]];
        f32x4 f = {0.f, 0.f, 0.f, 0.f};
        f = __builtin_amdgcn_mfma_f32_16x16x32_bf16(sb, bv, f, 0, 0, 0);
        int fy = by + r - 2, fx = bx + c - 2;
        float m = (fy >= 0 && fy < 512 && fx >= 0 && fx < 512) ? 1.f : 0.f;
        __hip_bfloat162 p0 = __float22bfloat162_rn(make_float2(f[0] * m, f[1] * m));
        __hip_bfloat162 p1 = __float22bfloat162_rn(make_float2(f[2] * m, f[3] * m));
        uint2 wv;
        wv.x = *reinterpret_cast<unsigned*>(&p0);
        wv.y = *reinterpret_cast<unsigned*>(&p1);
        *reinterpret_cast<uint2*>(&fs2[((lg >> 1) * 400 + px) * 8 + 4 * (lg & 1)]) = wv;
    }
    __syncthreads();

    // ---- P3: conv1 MFMA -> hs4 ----
    for (int t = wave; t < 21; t += 4) {
        int p  = t * 16 + n;
        int pc = p < 323 ? p : 323;
        int r1 = pc / 18, c1 = pc - 18 * r1;
        int base = (r1 * 20 + c1) * 8;
        f32x4 acc0 = {0.f,0.f,0.f,0.f}, acc1 = {0.f,0.f,0.f,0.f};
#pragma unroll
        for (int ks = 0; ks < 5; ++ks) {
            bf16x8 bf = *reinterpret_cast<const bf16x8*>(&fs2[base + boff[ks]]);
            acc0 = __builtin_amdgcn_mfma_f32_16x16x32_bf16(a1[0][ks], bf, acc0, 0, 0, 0);
            acc1 = __builtin_amdgcn_mfma_f32_16x16x32_bf16(a1[1][ks], bf, acc1, 0, 0, 0);
        }
        if (p < 324) {
            int hy = by - 1 + r1, hx = bx - 1 + c1;
            float m = (hy >= 0 && hy < 512 && hx >= 0 && hx < 512) ? 1.f : 0.f;
            __hip_bfloat162 q0 = __float22bfloat162_rn(make_float2(
                fmaxf(acc0[0] + b1v[0][0], 0.f) * m, fmaxf(acc0[1] + b1v[0][1], 0.f) * m));
            __hip_bfloat162 q1 = __float22bfloat162_rn(make_float2(
                fmaxf(acc0[2] + b1v[0][2], 0.f) * m, fmaxf(acc0[3] + b1v[0][3], 0.f) * m));
            uint2 W0; W0.x = *reinterpret_cast<unsigned*>(&q0);
            W0.y = *reinterpret_cast<unsigned*>(&q1);
            *reinterpret_cast<uint2*>(&hs4[((lg >> 1) * 324 + p) * 8 + 4 * (lg & 1)]) = W0;
            __hip_bfloat162 q2 = __float22bfloat162_rn(make_float2(
                fmaxf(acc1[0] + b1v[1][0], 0.f) * m, fmaxf(acc1[1] + b1v[1][1], 0.f) * m));
            __hip_bfloat162 q3 = __float22bfloat162_rn(make_float2(
                fmaxf(acc1[2] + b1v[1][2], 0.f) * m, fmaxf(acc1[3] + b1v[1][3], 0.f) * m));
            uint2 W1; W1.x = *reinterpret_cast<unsigned*>(&q2);
            W1.y = *reinterpret_cast<unsigned*>(&q3);
            *reinterpret_cast<uint2*>(&hs4[((2 + (lg >> 1)) * 324 + p) * 8 + 4 * (lg & 1)]) = W1;
        }
    }
    __syncthreads();

    // ---- P4: conv2 MFMA + epilogue ----
    const int hbase = lg * 324 * 8;
#pragma unroll
    for (int j = 0; j < 4; ++j) {
        int oy = wave + 4 * j;
        f32x4 acc = {0.f,0.f,0.f,0.f};
#pragma unroll
        for (int ks = 0; ks < 9; ++ks) {
            const int dy = ks / 3, dx = ks - 3 * (ks / 3);
            bf16x8 hf = *reinterpret_cast<const bf16x8*>(
                &hs4[hbase + ((oy + dy) * 18 + n + dx) * 8]);
            acc = __builtin_amdgcn_mfma_f32_16x16x32_bf16(a2[ks], hf, acc, 0, 0, 0);
        }
        __hip_bfloat16 xh = *reinterpret_cast<const __hip_bfloat16*>(&xs[(oy + 4) * XS_S + n + 4]);
        float xv = __bfloat162float(xh);
        float* op = out + (((size_t)(b * 16 + lg * 4) * 512 + (by + oy)) * 512) + bx + n;
#pragma unroll
        for (int r = 0; r < 4; ++r) {
            float o = fmaxf(acc[r] + b2v[r], 0.f) + wrv[r] * xv + brv[r];
            __builtin_nontemporal_store(o, op);
            op += 262144;
        }
    }
}

extern "C" void kernel_launch(void* const* d_in, const int* in_sizes, int n_in,
                              void* d_out, int out_size, void* d_ws, size_t ws_size,
                              hipStream_t stream) {
    const float* x  = (const float*)d_in[0];
    const float* w1 = (const float*)d_in[1];
    const float* b1 = (const float*)d_in[2];
    const float* w2 = (const float*)d_in[3];
    const float* b2 = (const float*)d_in[4];
    const float* wr = (const float*)d_in[5];
    const float* br = (const float*)d_in[6];
    float* out = (float*)d_out;
    short* ws = (short*)d_ws;

    dim3 block(256);
    dim3 gin(30, 30, 8);
    dim3 gbd(124, 1, 8);
    if (ws_size >= WS_BYTES) {
        hipLaunchKernelGGL(setup_frags, dim3(1), dim3(64), 0, stream,
                           w1, b1, w2, b2, wr, br, ws);
        hipLaunchKernelGGL(edge_interior<true>, gin, block, 0, stream,
                           x, w1, b1, w2, b2, wr, br, ws, out);
        hipLaunchKernelGGL(edge_border<true>, gbd, block, 0, stream,
                           x, w1, b1, w2, b2, wr, br, ws, out);
    } else {
        hipLaunchKernelGGL(edge_interior<false>, gin, block, 0, stream,
                           x, w1, b1, w2, b2, wr, br, ws, out);
        hipLaunchKernelGGL(edge_border<false>, gbd, block, 0, stream,
                           x, w1, b1, w2, b2, wr, br, ws, out);
    }
}

// Round 7
// 116.820 us; speedup vs baseline: 2.0661x; 2.0661x over previous
//
#include <hip/hip_runtime.h>
#include <hip/hip_bf16.h>

// EnhancedEdgeLayer R7: composed-conv interior + R5-path border + FAST setup.
// x [8,1,512,512] f32 -> out [8,16,512,512] f32
//
// R7 change vs R6: setup_frags was 158us (1 wave, dependent scattered global
// loads in weff_tap). Now 256 threads, w1/w2/EB staged in LDS, flat work
// partition -> ~5us. Interior/border kernels unchanged.

typedef __attribute__((ext_vector_type(8))) short bf16x8;
typedef __attribute__((ext_vector_type(4))) float f32x4;

#define XS_S 28   // shorts per xs row (24 data + 4 zero pad; 8B-aligned quads)

// ws layout (shorts):
//  A1   [2][5][64][8]  @ 0      (5120)   border conv1 fragments
//  A2   [9][64][8]     @ 5120   (4608)   conv2 fragments (both kernels)
//  SB   [64][8]        @ 9728   (512)    border stencil-bank fragments
//  FLT  floats         @ short 10240: per-lane 20 floats (b1v[2][4],b2v,wrv,brv)
//  WEFF [2][2][64][8]  @ 12800  (2048)   interior composed 7x7 fragments
#define WS_A2   5120
#define WS_SB   9728
#define WS_FLT  5120      // float offset
#define WS_WEFF 12800
#define WS_BYTES 30720

__device__ const float EB[9][5][5] = {
 {{0,0,0,0,0},{0,-1,0,1,0},{0,-2,0,2,0},{0,-1,0,1,0},{0,0,0,0,0}},        // sobel_x
 {{0,0,0,0,0},{0,-1,-2,-1,0},{0,0,0,0,0},{0,1,2,1,0},{0,0,0,0,0}},        // sobel_y
 {{0,0,0,0,0},{0,0,1,2,0},{0,-1,0,1,0},{0,-2,-1,0,0},{0,0,0,0,0}},        // diag1
 {{0,0,0,0,0},{0,-2,-1,0,0},{0,-1,0,1,0},{0,0,1,2,0},{0,0,0,0,0}},        // diag2
 {{0,0,0,0,0},{0,0,1,0,0},{0,1,-4,1,0},{0,0,1,0,0},{0,0,0,0,0}},          // laplacian
 {{-1,-2,0,2,1},{-2,-3,0,3,2},{-3,-4,0,4,3},{-2,-3,0,3,2},{-1,-2,0,2,1}}, // gradient5x5
 {{0,0,0,0,0},{0,-3,0,3,0},{0,-10,0,10,0},{0,-3,0,3,0},{0,0,0,0,0}},      // scharr_x
 {{0,0,0,0,0},{0,-3,-10,-3,0},{0,0,0,0,0},{0,3,10,3,0},{0,0,0,0,0}},      // scharr_y
 {{0,0,0,0,0},{0,0,0,0,0},{0,0,1,0,0},{0,0,0,0,0},{0,0,0,0,0}},           // identity
};

__device__ __forceinline__ unsigned short f2bf(float f) {
    union { float f; unsigned u; } v; v.f = f;
    unsigned u = v.u + 0x7fffu + ((v.u >> 16) & 1u);   // RNE
    return (unsigned short)(u >> 16);
}

__device__ __forceinline__ float weff_tap(const float* __restrict__ w1,
                                          int oc, int dy, int dx) {
    float s = 0.f;
    for (int ch = 0; ch < 9; ++ch)
        for (int ty = 0; ty < 3; ++ty)
            for (int tx = 0; tx < 3; ++tx) {
                int sy = dy - ty, sx = dx - tx;
                if (sy >= 0 && sy < 5 && sx >= 0 && sx < 5)
                    s += w1[(oc * 9 + ch) * 9 + ty * 3 + tx] * EB[ch][sy][sx];
            }
    return s;
}

// ---- fast setup: 256 threads, LDS-staged weights, flat work split ----
__global__ __launch_bounds__(256) void setup_frags(
    const float* __restrict__ w1, const float* __restrict__ b1,
    const float* __restrict__ w2, const float* __restrict__ b2,
    const float* __restrict__ wr, const float* __restrict__ br,
    short* __restrict__ ws)
{
    __shared__ float w1s[2592];   // 32*9*9
    __shared__ float w2s[4608];   // 16*32*9
    __shared__ float ebs[225];    // 9*5*5
    const int tid = threadIdx.x;

    for (int i = tid; i < 2592; i += 256) w1s[i] = w1[i];
    for (int i = tid; i < 4608; i += 256) w2s[i] = w2[i];
    if (tid < 225) ebs[tid] = ((const float*)EB)[tid];
    __syncthreads();

    // A1: idx = ((mt*5+ks)*64+lane)*8+i
    for (int idx = tid; idx < 5120; idx += 256) {
        int i = idx & 7, lane = (idx >> 3) & 63, rest = idx >> 9;
        int mt = rest / 5, ks = rest - 5 * mt;
        int n = lane & 15, lg = lane >> 4;
        int k = 32 * ks + 8 * lg + i;
        int g = k >> 4, ch = k & 15;
        float w = (g < 9 && ch < 9) ? w1s[(mt * 16 + n) * 81 + ch * 9 + g] : 0.f;
        ws[idx] = (short)f2bf(w);
    }
    // A2: idx = (ks*64+lane)*8+i
    for (int idx = tid; idx < 4608; idx += 256) {
        int i = idx & 7, lane = (idx >> 3) & 63, ks = idx >> 9;
        int n = lane & 15, lg = lane >> 4;
        int ic = 8 * lg + i;
        ws[WS_A2 + idx] = (short)f2bf(w2s[n * 288 + ic * 9 + ks]);
    }
    // SB: idx = lane*8+i
    for (int idx = tid; idx < 512; idx += 256) {
        int i = idx & 7, lane = idx >> 3;
        int n = lane & 15, lg = lane >> 4;
        int k = 8 * lg + i;
        float v = (k < 25 && n < 9) ? ebs[n * 25 + k] : 0.f;
        ws[WS_SB + idx] = (short)f2bf(v);
    }
    // WEFF: idx = ((mt*2+ks)*64+lane)*8+i ; tap (dy,dx) = (4*ks+lg, i)
    for (int idx = tid; idx < 2048; idx += 256) {
        int i = idx & 7, lane = (idx >> 3) & 63, rest = idx >> 9;
        int mt = rest >> 1, ks = rest & 1;
        int n = lane & 15, lg = lane >> 4;
        int dy = 4 * ks + lg, dx = i;
        float s = 0.f;
        if (dy < 7 && dx < 7) {
            int oc = mt * 16 + n;
            for (int ch = 0; ch < 9; ++ch)
                for (int ty = 0; ty < 3; ++ty) {
                    int sy = dy - ty;
                    if (sy < 0 || sy >= 5) continue;
                    for (int tx = 0; tx < 3; ++tx) {
                        int sx = dx - tx;
                        if (sx >= 0 && sx < 5)
                            s += w1s[(oc * 9 + ch) * 9 + ty * 3 + tx] * ebs[ch * 25 + sy * 5 + sx];
                    }
                }
        }
        ws[WS_WEFF + idx] = (short)f2bf(s);
    }
    // FLT: per-lane 20 floats
    if (tid < 64) {
        int lg = tid >> 4;
        float* wf = (float*)ws + WS_FLT + tid * 20;
        for (int r = 0; r < 4; ++r) {
            wf[r]      = b1[lg * 4 + r];
            wf[4 + r]  = b1[16 + lg * 4 + r];
            wf[8 + r]  = b2[lg * 4 + r];
            wf[12 + r] = wr[lg * 4 + r];
            wf[16 + r] = br[lg * 4 + r];
        }
    }
}

// ---------------- interior kernel (composed 7x7, no masks) ----------------
template<bool USE_WS>
__global__ __launch_bounds__(256, 6) void edge_interior(
    const float* __restrict__ x,  const float* __restrict__ w1, const float* __restrict__ b1,
    const float* __restrict__ w2, const float* __restrict__ b2,
    const float* __restrict__ wr, const float* __restrict__ br,
    const short* __restrict__ ws, float* __restrict__ out)
{
    __shared__ short hs4[4 * 324 * 8];   // 20736 B [ic-block][px 18x18][8]
    __shared__ short xs[24 * XS_S];      //  1344 B bf16 x tile

    const int tid  = threadIdx.x;
    const int lane = tid & 63;
    const int wave = tid >> 6;
    const int n    = lane & 15;
    const int lg   = lane >> 4;
    const int bx = (blockIdx.x + 1) * 16, by = (blockIdx.y + 1) * 16, b = blockIdx.z;

    // ---- P0: x tile -> bf16 LDS, fully in-bounds, vectorized ----
    if (tid < 144) {
        int r = tid / 6, q = tid % 6;
        const float4 v = *reinterpret_cast<const float4*>(
            &x[((size_t)b * 512 + by - 4 + r) * 512 + bx - 4 + 4 * q]);
        __hip_bfloat162 p0 = __float22bfloat162_rn(make_float2(v.x, v.y));
        __hip_bfloat162 p1 = __float22bfloat162_rn(make_float2(v.z, v.w));
        uint2 wv; wv.x = *reinterpret_cast<unsigned*>(&p0);
        wv.y = *reinterpret_cast<unsigned*>(&p1);
        *reinterpret_cast<uint2*>(&xs[r * XS_S + 4 * q]) = wv;
    } else if (tid < 168) {
        int r = tid - 144;
        uint2 z; z.x = 0u; z.y = 0u;
        *reinterpret_cast<uint2*>(&xs[r * XS_S + 24]) = z;   // zero pad cols 24..27
    }

    // ---- P1: fragments -> registers ----
    bf16x8 wa[2][2], a2[9];
    float b1v[2][4], b2v[4], wrv[4], brv[4];
    if (USE_WS) {
#pragma unroll
        for (int mt = 0; mt < 2; ++mt)
#pragma unroll
            for (int ks = 0; ks < 2; ++ks)
                wa[mt][ks] = *reinterpret_cast<const bf16x8*>(
                    &ws[WS_WEFF + ((mt * 2 + ks) * 64 + lane) * 8]);
#pragma unroll
        for (int ks = 0; ks < 9; ++ks)
            a2[ks] = *reinterpret_cast<const bf16x8*>(&ws[WS_A2 + (ks * 64 + lane) * 8]);
        const float* wf = (const float*)ws + WS_FLT + lane * 20;
        f32x4 t0 = *reinterpret_cast<const f32x4*>(wf);
        f32x4 t1 = *reinterpret_cast<const f32x4*>(wf + 4);
        f32x4 t2 = *reinterpret_cast<const f32x4*>(wf + 8);
        f32x4 t3 = *reinterpret_cast<const f32x4*>(wf + 12);
        f32x4 t4 = *reinterpret_cast<const f32x4*>(wf + 16);
#pragma unroll
        for (int r = 0; r < 4; ++r) {
            b1v[0][r] = t0[r]; b1v[1][r] = t1[r];
            b2v[r] = t2[r]; wrv[r] = t3[r]; brv[r] = t4[r];
        }
    } else {
#pragma unroll
        for (int mt = 0; mt < 2; ++mt)
#pragma unroll
            for (int ks = 0; ks < 2; ++ks)
#pragma unroll
                for (int i = 0; i < 8; ++i) {
                    int dy = 4 * ks + lg, dx = i;
                    float s = (dy < 7 && dx < 7) ? weff_tap(w1, mt * 16 + n, dy, dx) : 0.f;
                    wa[mt][ks][i] = (short)f2bf(s);
                }
#pragma unroll
        for (int ks = 0; ks < 9; ++ks)
#pragma unroll
            for (int i = 0; i < 8; ++i)
                a2[ks][i] = (short)f2bf(w2[n * 288 + (8 * lg + i) * 9 + ks]);
#pragma unroll
        for (int r = 0; r < 4; ++r) {
            b1v[0][r] = b1[lg * 4 + r]; b1v[1][r] = b1[16 + lg * 4 + r];
            b2v[r] = b2[lg * 4 + r]; wrv[r] = wr[lg * 4 + r]; brv[r] = br[lg * 4 + r];
        }
    }

    __syncthreads();

    // ---- P3: conv1 = 7x7 composed MFMA -> hs4 ----
    for (int t = wave; t < 21; t += 4) {
        int p  = t * 16 + n;
        int pc = p < 323 ? p : 323;
        int r1 = pc / 18, c1 = pc - 18 * r1;
        int base = r1 * XS_S + c1;
        f32x4 acc0 = {0.f,0.f,0.f,0.f}, acc1 = {0.f,0.f,0.f,0.f};
#pragma unroll
        for (int ks = 0; ks < 2; ++ks) {
            const int dy = 4 * ks + lg;
            bf16x8 bv = {0,0,0,0,0,0,0,0};
            if (dy < 7) {                       // dy==7 lanes: A rows are 0
                const short* rp = &xs[base + dy * XS_S];
#pragma unroll
                for (int i = 0; i < 8; ++i) bv[i] = rp[i];
            }
            acc0 = __builtin_amdgcn_mfma_f32_16x16x32_bf16(wa[0][ks], bv, acc0, 0, 0, 0);
            acc1 = __builtin_amdgcn_mfma_f32_16x16x32_bf16(wa[1][ks], bv, acc1, 0, 0, 0);
        }
        if (p < 324) {
            __hip_bfloat162 q0 = __float22bfloat162_rn(make_float2(
                fmaxf(acc0[0] + b1v[0][0], 0.f), fmaxf(acc0[1] + b1v[0][1], 0.f)));
            __hip_bfloat162 q1 = __float22bfloat162_rn(make_float2(
                fmaxf(acc0[2] + b1v[0][2], 0.f), fmaxf(acc0[3] + b1v[0][3], 0.f)));
            uint2 W0; W0.x = *reinterpret_cast<unsigned*>(&q0);
            W0.y = *reinterpret_cast<unsigned*>(&q1);
            *reinterpret_cast<uint2*>(&hs4[((lg >> 1) * 324 + p) * 8 + 4 * (lg & 1)]) = W0;
            __hip_bfloat162 q2 = __float22bfloat162_rn(make_float2(
                fmaxf(acc1[0] + b1v[1][0], 0.f), fmaxf(acc1[1] + b1v[1][1], 0.f)));
            __hip_bfloat162 q3 = __float22bfloat162_rn(make_float2(
                fmaxf(acc1[2] + b1v[1][2], 0.f), fmaxf(acc1[3] + b1v[1][3], 0.f)));
            uint2 W1; W1.x = *reinterpret_cast<unsigned*>(&q2);
            W1.y = *reinterpret_cast<unsigned*>(&q3);
            *reinterpret_cast<uint2*>(&hs4[((2 + (lg >> 1)) * 324 + p) * 8 + 4 * (lg & 1)]) = W1;
        }
    }
    __syncthreads();

    // ---- P4: conv2 MFMA + epilogue ----
    const int hbase = lg * 324 * 8;
#pragma unroll
    for (int j = 0; j < 4; ++j) {
        int oy = wave + 4 * j;
        f32x4 acc = {0.f,0.f,0.f,0.f};
#pragma unroll
        for (int ks = 0; ks < 9; ++ks) {
            const int dy = ks / 3, dx = ks - 3 * (ks / 3);
            bf16x8 hf = *reinterpret_cast<const bf16x8*>(
                &hs4[hbase + ((oy + dy) * 18 + n + dx) * 8]);
            acc = __builtin_amdgcn_mfma_f32_16x16x32_bf16(a2[ks], hf, acc, 0, 0, 0);
        }
        __hip_bfloat16 xh = *reinterpret_cast<const __hip_bfloat16*>(&xs[(oy + 4) * XS_S + n + 4]);
        float xv = __bfloat162float(xh);
        float* op = out + (((size_t)(b * 16 + lg * 4) * 512 + (by + oy)) * 512) + bx + n;
#pragma unroll
        for (int r = 0; r < 4; ++r) {
            float o = fmaxf(acc[r] + b2v[r], 0.f) + wrv[r] * xv + brv[r];
            __builtin_nontemporal_store(o, op);
            op += 262144;   // next oc plane
        }
    }
}

// ---------------- border kernel (R5 path, remapped to 124 border tiles) ----------------
template<bool USE_WS>
__global__ __launch_bounds__(256, 4) void edge_border(
    const float* __restrict__ x,  const float* __restrict__ w1, const float* __restrict__ b1,
    const float* __restrict__ w2, const float* __restrict__ b2,
    const float* __restrict__ wr, const float* __restrict__ br,
    const short* __restrict__ ws, float* __restrict__ out)
{
    __shared__ short fs2[2 * 400 * 8];   // 12800 B [ch-half][px 20x20][8]
    __shared__ short hs4[4 * 324 * 8];   // 20736 B
    __shared__ short xs[24 * XS_S];

    const int tid  = threadIdx.x;
    const int lane = tid & 63;
    const int wave = tid >> 6;
    const int n    = lane & 15;
    const int lg   = lane >> 4;

    int idx = blockIdx.x, tx, ty;
    if      (idx < 32) { tx = idx;      ty = 0;  }
    else if (idx < 64) { tx = idx - 32; ty = 31; }
    else if (idx < 94) { tx = 0;        ty = idx - 63; }
    else               { tx = 31;       ty = idx - 93; }
    const int bx = tx * 16, by = ty * 16, b = blockIdx.z;

    // ---- P0: x tile -> bf16 LDS (zero-padded at image borders) ----
    for (int i = tid; i < 576; i += 256) {
        int r = i / 24, c = i % 24;
        int gy = by - 4 + r, gx = bx - 4 + c;
        float v = 0.f;
        if (gy >= 0 && gy < 512 && gx >= 0 && gx < 512) v = x[((size_t)b * 512 + gy) * 512 + gx];
        __hip_bfloat16 h = __float2bfloat16(v);
        xs[r * XS_S + c] = *reinterpret_cast<short*>(&h);
    }

    // ---- P1: fragments ----
    bf16x8 a1[2][5], a2[9], sb;
    float b1v[2][4], b2v[4], wrv[4], brv[4];
    if (USE_WS) {
#pragma unroll
        for (int mt = 0; mt < 2; ++mt)
#pragma unroll
            for (int ks = 0; ks < 5; ++ks)
                a1[mt][ks] = *reinterpret_cast<const bf16x8*>(&ws[((mt * 5 + ks) * 64 + lane) * 8]);
#pragma unroll
        for (int ks = 0; ks < 9; ++ks)
            a2[ks] = *reinterpret_cast<const bf16x8*>(&ws[WS_A2 + (ks * 64 + lane) * 8]);
        sb = *reinterpret_cast<const bf16x8*>(&ws[WS_SB + lane * 8]);
        const float* wf = (const float*)ws + WS_FLT + lane * 20;
        f32x4 t0 = *reinterpret_cast<const f32x4*>(wf);
        f32x4 t1 = *reinterpret_cast<const f32x4*>(wf + 4);
        f32x4 t2 = *reinterpret_cast<const f32x4*>(wf + 8);
        f32x4 t3 = *reinterpret_cast<const f32x4*>(wf + 12);
        f32x4 t4 = *reinterpret_cast<const f32x4*>(wf + 16);
#pragma unroll
        for (int r = 0; r < 4; ++r) {
            b1v[0][r] = t0[r]; b1v[1][r] = t1[r];
            b2v[r] = t2[r]; wrv[r] = t3[r]; brv[r] = t4[r];
        }
    } else {
#pragma unroll
        for (int mt = 0; mt < 2; ++mt)
#pragma unroll
            for (int ks = 0; ks < 5; ++ks)
#pragma unroll
                for (int i = 0; i < 8; ++i) {
                    int k = 32 * ks + 8 * lg + i;
                    int g = k >> 4, ch = k & 15;
                    float w = (g < 9 && ch < 9) ? w1[(mt * 16 + n) * 81 + ch * 9 + g] : 0.f;
                    a1[mt][ks][i] = (short)f2bf(w);
                }
#pragma unroll
        for (int ks = 0; ks < 9; ++ks)
#pragma unroll
            for (int i = 0; i < 8; ++i)
                a2[ks][i] = (short)f2bf(w2[n * 288 + (8 * lg + i) * 9 + ks]);
#pragma unroll
        for (int i = 0; i < 8; ++i) {
            int k = 8 * lg + i;
            float v = (k < 25 && n < 9) ? EB[n][k / 5][k % 5] : 0.f;
            sb[i] = (short)f2bf(v);
        }
#pragma unroll
        for (int r = 0; r < 4; ++r) {
            b1v[0][r] = b1[lg * 4 + r]; b1v[1][r] = b1[16 + lg * 4 + r];
            b2v[r] = b2[lg * 4 + r]; wrv[r] = wr[lg * 4 + r]; brv[r] = br[lg * 4 + r];
        }
    }

    int toff[8];
#pragma unroll
    for (int i = 0; i < 8; ++i) {
        int k = 8 * lg + i;
        int t = k < 25 ? k : 24;
        toff[i] = (t / 5) * XS_S + (t % 5);
    }
    int boff[5];
#pragma unroll
    for (int ks = 0; ks < 5; ++ks) {
        int g = 2 * ks + (lg >> 1); if (g > 8) g = 8;
        int dy = g / 3, dx = g - 3 * dy;
        boff[ks] = (lg & 1) * 3200 + (dy * 20 + dx) * 8;
    }

    __syncthreads();

    // ---- P2: stencils via MFMA -> fs2 ----
    for (int t = wave; t < 25; t += 4) {
        int px = t * 16 + n;
        int r = px / 20, c = px - 20 * r;
        const short* base = &xs[r * XS_S + c];
        bf16x8 bv;
#pragma unroll
        for (int i = 0; i < 8; ++i) bv[i] = base[toff[i]];
        f32x4 f = {0.f, 0.f, 0.f, 0.f};
        f = __builtin_amdgcn_mfma_f32_16x16x32_bf16(sb, bv, f, 0, 0, 0);
        int fy = by + r - 2, fx = bx + c - 2;
        float m = (fy >= 0 && fy < 512 && fx >= 0 && fx < 512) ? 1.f : 0.f;
        __hip_bfloat162 p0 = __float22bfloat162_rn(make_float2(f[0] * m, f[1] * m));
        __hip_bfloat162 p1 = __float22bfloat162_rn(make_float2(f[2] * m, f[3] * m));
        uint2 wv;
        wv.x = *reinterpret_cast<unsigned*>(&p0);
        wv.y = *reinterpret_cast<unsigned*>(&p1);
        *reinterpret_cast<uint2*>(&fs2[((lg >> 1) * 400 + px) * 8 + 4 * (lg & 1)]) = wv;
    }
    __syncthreads();

    // ---- P3: conv1 MFMA -> hs4 ----
    for (int t = wave; t < 21; t += 4) {
        int p  = t * 16 + n;
        int pc = p < 323 ? p : 323;
        int r1 = pc / 18, c1 = pc - 18 * r1;
        int base = (r1 * 20 + c1) * 8;
        f32x4 acc0 = {0.f,0.f,0.f,0.f}, acc1 = {0.f,0.f,0.f,0.f};
#pragma unroll
        for (int ks = 0; ks < 5; ++ks) {
            bf16x8 bf = *reinterpret_cast<const bf16x8*>(&fs2[base + boff[ks]]);
            acc0 = __builtin_amdgcn_mfma_f32_16x16x32_bf16(a1[0][ks], bf, acc0, 0, 0, 0);
            acc1 = __builtin_amdgcn_mfma_f32_16x16x32_bf16(a1[1][ks], bf, acc1, 0, 0, 0);
        }
        if (p < 324) {
            int hy = by - 1 + r1, hx = bx - 1 + c1;
            float m = (hy >= 0 && hy < 512 && hx >= 0 && hx < 512) ? 1.f : 0.f;
            __hip_bfloat162 q0 = __float22bfloat162_rn(make_float2(
                fmaxf(acc0[0] + b1v[0][0], 0.f) * m, fmaxf(acc0[1] + b1v[0][1], 0.f) * m));
            __hip_bfloat162 q1 = __float22bfloat162_rn(make_float2(
                fmaxf(acc0[2] + b1v[0][2], 0.f) * m, fmaxf(acc0[3] + b1v[0][3], 0.f) * m));
            uint2 W0; W0.x = *reinterpret_cast<unsigned*>(&q0);
            W0.y = *reinterpret_cast<unsigned*>(&q1);
            *reinterpret_cast<uint2*>(&hs4[((lg >> 1) * 324 + p) * 8 + 4 * (lg & 1)]) = W0;
            __hip_bfloat162 q2 = __float22bfloat162_rn(make_float2(
                fmaxf(acc1[0] + b1v[1][0], 0.f) * m, fmaxf(acc1[1] + b1v[1][1], 0.f) * m));
            __hip_bfloat162 q3 = __float22bfloat162_rn(make_float2(
                fmaxf(acc1[2] + b1v[1][2], 0.f) * m, fmaxf(acc1[3] + b1v[1][3], 0.f) * m));
            uint2 W1; W1.x = *reinterpret_cast<unsigned*>(&q2);
            W1.y = *reinterpret_cast<unsigned*>(&q3);
            *reinterpret_cast<uint2*>(&hs4[((2 + (lg >> 1)) * 324 + p) * 8 + 4 * (lg & 1)]) = W1;
        }
    }
    __syncthreads();

    // ---- P4: conv2 MFMA + epilogue ----
    const int hbase = lg * 324 * 8;
#pragma unroll
    for (int j = 0; j < 4; ++j) {
        int oy = wave + 4 * j;
        f32x4 acc = {0.f,0.f,0.f,0.f};
#pragma unroll
        for (int ks = 0; ks < 9; ++ks) {
            const int dy = ks / 3, dx = ks - 3 * (ks / 3);
            bf16x8 hf = *reinterpret_cast<const bf16x8*>(
                &hs4[hbase + ((oy + dy) * 18 + n + dx) * 8]);
            acc = __builtin_amdgcn_mfma_f32_16x16x32_bf16(a2[ks], hf, acc, 0, 0, 0);
        }
        __hip_bfloat16 xh = *reinterpret_cast<const __hip_bfloat16*>(&xs[(oy + 4) * XS_S + n + 4]);
        float xv = __bfloat162float(xh);
        float* op = out + (((size_t)(b * 16 + lg * 4) * 512 + (by + oy)) * 512) + bx + n;
#pragma unroll
        for (int r = 0; r < 4; ++r) {
            float o = fmaxf(acc[r] + b2v[r], 0.f) + wrv[r] * xv + brv[r];
            __builtin_nontemporal_store(o, op);
            op += 262144;
        }
    }
}

extern "C" void kernel_launch(void* const* d_in, const int* in_sizes, int n_in,
                              void* d_out, int out_size, void* d_ws, size_t ws_size,
                              hipStream_t stream) {
    const float* x  = (const float*)d_in[0];
    const float* w1 = (const float*)d_in[1];
    const float* b1 = (const float*)d_in[2];
    const float* w2 = (const float*)d_in[3];
    const float* b2 = (const float*)d_in[4];
    const float* wr = (const float*)d_in[5];
    const float* br = (const float*)d_in[6];
    float* out = (float*)d_out;
    short* ws = (short*)d_ws;

    dim3 block(256);
    dim3 gin(30, 30, 8);
    dim3 gbd(124, 1, 8);
    if (ws_size >= WS_BYTES) {
        hipLaunchKernelGGL(setup_frags, dim3(1), dim3(256), 0, stream,
                           w1, b1, w2, b2, wr, br, ws);
        hipLaunchKernelGGL(edge_interior<true>, gin, block, 0, stream,
                           x, w1, b1, w2, b2, wr, br, ws, out);
        hipLaunchKernelGGL(edge_border<true>, gbd, block, 0, stream,
                           x, w1, b1, w2, b2, wr, br, ws, out);
    } else {
        hipLaunchKernelGGL(edge_interior<false>, gin, block, 0, stream,
                           x, w1, b1, w2, b2, wr, br, ws, out);
        hipLaunchKernelGGL(edge_border<false>, gbd, block, 0, stream,
                           x, w1, b1, w2, b2, wr, br, ws, out);
    }
}

// Round 9
// 114.307 us; speedup vs baseline: 2.1115x; 1.0220x over previous
//
#include <hip/hip_runtime.h>
#include <hip/hip_bf16.h>

// EnhancedEdgeLayer R9 (= R8 with ext-vector NT store fix): composed-conv
// interior (16x32 tiles, LDS-staged full-line NT stores) + R5-path border
// overwrite + fast setup.
// x [8,1,512,512] f32 -> out [8,16,512,512] f32

typedef __attribute__((ext_vector_type(8))) short bf16x8;
typedef __attribute__((ext_vector_type(4))) float f32x4;

#define XS_S 28   // border kernel xs stride (shorts)

// ws layout (shorts):
//  A1   [2][5][64][8]  @ 0      border conv1 fragments
//  A2   [9][64][8]     @ 5120   conv2 fragments (both kernels)
//  SB   [64][8]        @ 9728   border stencil-bank fragments
//  FLT  floats         @ short 10240: per-lane 20 floats (b1v[2][4],b2v,wrv,brv)
//  WEFF [2][2][64][8]  @ 12800  composed 7x7 fragments
#define WS_A2   5120
#define WS_SB   9728
#define WS_FLT  5120      // float offset
#define WS_WEFF 12800
#define WS_BYTES 30720

__device__ const float EB[9][5][5] = {
 {{0,0,0,0,0},{0,-1,0,1,0},{0,-2,0,2,0},{0,-1,0,1,0},{0,0,0,0,0}},        // sobel_x
 {{0,0,0,0,0},{0,-1,-2,-1,0},{0,0,0,0,0},{0,1,2,1,0},{0,0,0,0,0}},        // sobel_y
 {{0,0,0,0,0},{0,0,1,2,0},{0,-1,0,1,0},{0,-2,-1,0,0},{0,0,0,0,0}},        // diag1
 {{0,0,0,0,0},{0,-2,-1,0,0},{0,-1,0,1,0},{0,0,1,2,0},{0,0,0,0,0}},        // diag2
 {{0,0,0,0,0},{0,0,1,0,0},{0,1,-4,1,0},{0,0,1,0,0},{0,0,0,0,0}},          // laplacian
 {{-1,-2,0,2,1},{-2,-3,0,3,2},{-3,-4,0,4,3},{-2,-3,0,3,2},{-1,-2,0,2,1}}, // gradient5x5
 {{0,0,0,0,0},{0,-3,0,3,0},{0,-10,0,10,0},{0,-3,0,3,0},{0,0,0,0,0}},      // scharr_x
 {{0,0,0,0,0},{0,-3,-10,-3,0},{0,0,0,0,0},{0,3,10,3,0},{0,0,0,0,0}},      // scharr_y
 {{0,0,0,0,0},{0,0,0,0,0},{0,0,1,0,0},{0,0,0,0,0},{0,0,0,0,0}},           // identity
};

__device__ __forceinline__ unsigned short f2bf(float f) {
    union { float f; unsigned u; } v; v.f = f;
    unsigned u = v.u + 0x7fffu + ((v.u >> 16) & 1u);   // RNE
    return (unsigned short)(u >> 16);
}

__device__ __forceinline__ float weff_tap(const float* __restrict__ w1,
                                          int oc, int dy, int dx) {
    float s = 0.f;
    for (int ch = 0; ch < 9; ++ch)
        for (int ty = 0; ty < 3; ++ty)
            for (int tx = 0; tx < 3; ++tx) {
                int sy = dy - ty, sx = dx - tx;
                if (sy >= 0 && sy < 5 && sx >= 0 && sx < 5)
                    s += w1[(oc * 9 + ch) * 9 + ty * 3 + tx] * EB[ch][sy][sx];
            }
    return s;
}

// ---- fast setup: 256 threads, LDS-staged weights, flat work split ----
__global__ __launch_bounds__(256) void setup_frags(
    const float* __restrict__ w1, const float* __restrict__ b1,
    const float* __restrict__ w2, const float* __restrict__ b2,
    const float* __restrict__ wr, const float* __restrict__ br,
    short* __restrict__ ws)
{
    __shared__ float w1s[2592];
    __shared__ float w2s[4608];
    __shared__ float ebs[225];
    const int tid = threadIdx.x;

    for (int i = tid; i < 2592; i += 256) w1s[i] = w1[i];
    for (int i = tid; i < 4608; i += 256) w2s[i] = w2[i];
    if (tid < 225) ebs[tid] = ((const float*)EB)[tid];
    __syncthreads();

    for (int idx = tid; idx < 5120; idx += 256) {
        int i = idx & 7, lane = (idx >> 3) & 63, rest = idx >> 9;
        int mt = rest / 5, ks = rest - 5 * mt;
        int n = lane & 15, lg = lane >> 4;
        int k = 32 * ks + 8 * lg + i;
        int g = k >> 4, ch = k & 15;
        float w = (g < 9 && ch < 9) ? w1s[(mt * 16 + n) * 81 + ch * 9 + g] : 0.f;
        ws[idx] = (short)f2bf(w);
    }
    for (int idx = tid; idx < 4608; idx += 256) {
        int i = idx & 7, lane = (idx >> 3) & 63, ks = idx >> 9;
        int n = lane & 15, lg = lane >> 4;
        int ic = 8 * lg + i;
        ws[WS_A2 + idx] = (short)f2bf(w2s[n * 288 + ic * 9 + ks]);
    }
    for (int idx = tid; idx < 512; idx += 256) {
        int i = idx & 7, lane = idx >> 3;
        int n = lane & 15, lg = lane >> 4;
        int k = 8 * lg + i;
        float v = (k < 25 && n < 9) ? ebs[n * 25 + k] : 0.f;
        ws[WS_SB + idx] = (short)f2bf(v);
    }
    for (int idx = tid; idx < 2048; idx += 256) {
        int i = idx & 7, lane = (idx >> 3) & 63, rest = idx >> 9;
        int mt = rest >> 1, ks = rest & 1;
        int n = lane & 15, lg = lane >> 4;
        int dy = 4 * ks + lg, dx = i;
        float s = 0.f;
        if (dy < 7 && dx < 7) {
            int oc = mt * 16 + n;
            for (int ch = 0; ch < 9; ++ch)
                for (int ty = 0; ty < 3; ++ty) {
                    int sy = dy - ty;
                    if (sy < 0 || sy >= 5) continue;
                    for (int tx = 0; tx < 3; ++tx) {
                        int sx = dx - tx;
                        if (sx >= 0 && sx < 5)
                            s += w1s[(oc * 9 + ch) * 9 + ty * 3 + tx] * ebs[ch * 25 + sy * 5 + sx];
                    }
                }
        }
        ws[WS_WEFF + idx] = (short)f2bf(s);
    }
    if (tid < 64) {
        int lg = tid >> 4;
        float* wf = (float*)ws + WS_FLT + tid * 20;
        for (int r = 0; r < 4; ++r) {
            wf[r]      = b1[lg * 4 + r];
            wf[4 + r]  = b1[16 + lg * 4 + r];
            wf[8 + r]  = b2[lg * 4 + r];
            wf[12 + r] = wr[lg * 4 + r];
            wf[16 + r] = br[lg * 4 + r];
        }
    }
}

// ---------------- interior kernel: 16x32 tiles, composed 7x7 ----------------
// covers FULL image; 2px output ring is garbage -> border kernel overwrites.
template<bool USE_WS>
__global__ __launch_bounds__(256, 3) void edge_interior2(
    const float* __restrict__ x,  const float* __restrict__ w1, const float* __restrict__ b1,
    const float* __restrict__ w2, const float* __restrict__ b2,
    const float* __restrict__ wr, const float* __restrict__ br,
    const short* __restrict__ ws, float* __restrict__ out)
{
    // pool: hs [4 icb][624 px][8] shorts (39936B)  UNION  stage [16oc][16row][36] f32 (36864B)
    __shared__ long long pool[39936 / 8];
    __shared__ short xs[24 * 40 + 8];   // bf16 x tile, rows 24 x cols 40 (+8 pad for dx==7 overread)
    short* hs    = (short*)pool;
    float* stage = (float*)pool;

    const int tid  = threadIdx.x;
    const int lane = tid & 63;
    const int wave = tid >> 6;
    const int n    = lane & 15;
    const int lg   = lane >> 4;
    const int bx = blockIdx.x * 32, by = blockIdx.y * 16, b = blockIdx.z;

    // ---- P0: x tile -> bf16 LDS (clamped; garbage only affects overwritten ring) ----
    for (int i = tid; i < 480; i += 256) {
        int r = i / 20, c2 = i % 20;
        int gy = by - 4 + r;  gy = gy < 0 ? 0 : (gy > 511 ? 511 : gy);
        int gx = bx - 4 + 2 * c2; gx = gx < 0 ? 0 : (gx > 510 ? 510 : gx);
        const float2 v = *reinterpret_cast<const float2*>(&x[((size_t)b * 512 + gy) * 512 + gx]);
        __hip_bfloat162 p0 = __float22bfloat162_rn(make_float2(v.x, v.y));
        *reinterpret_cast<unsigned*>(&xs[r * 40 + 2 * c2]) = *reinterpret_cast<unsigned*>(&p0);
    }

    // ---- P1: fragments -> registers ----
    bf16x8 wa[2][2], a2[9];
    float b1v[2][4], b2v[4], wrv[4], brv[4];
    if (USE_WS) {
#pragma unroll
        for (int mt = 0; mt < 2; ++mt)
#pragma unroll
            for (int ks = 0; ks < 2; ++ks)
                wa[mt][ks] = *reinterpret_cast<const bf16x8*>(
                    &ws[WS_WEFF + ((mt * 2 + ks) * 64 + lane) * 8]);
#pragma unroll
        for (int ks = 0; ks < 9; ++ks)
            a2[ks] = *reinterpret_cast<const bf16x8*>(&ws[WS_A2 + (ks * 64 + lane) * 8]);
        const float* wf = (const float*)ws + WS_FLT + lane * 20;
        f32x4 t0 = *reinterpret_cast<const f32x4*>(wf);
        f32x4 t1 = *reinterpret_cast<const f32x4*>(wf + 4);
        f32x4 t2 = *reinterpret_cast<const f32x4*>(wf + 8);
        f32x4 t3 = *reinterpret_cast<const f32x4*>(wf + 12);
        f32x4 t4 = *reinterpret_cast<const f32x4*>(wf + 16);
#pragma unroll
        for (int r = 0; r < 4; ++r) {
            b1v[0][r] = t0[r]; b1v[1][r] = t1[r];
            b2v[r] = t2[r]; wrv[r] = t3[r]; brv[r] = t4[r];
        }
    } else {
#pragma unroll
        for (int mt = 0; mt < 2; ++mt)
#pragma unroll
            for (int ks = 0; ks < 2; ++ks)
#pragma unroll
                for (int i = 0; i < 8; ++i) {
                    int dy = 4 * ks + lg, dx = i;
                    float s = (dy < 7 && dx < 7) ? weff_tap(w1, mt * 16 + n, dy, dx) : 0.f;
                    wa[mt][ks][i] = (short)f2bf(s);
                }
#pragma unroll
        for (int ks = 0; ks < 9; ++ks)
#pragma unroll
            for (int i = 0; i < 8; ++i)
                a2[ks][i] = (short)f2bf(w2[n * 288 + (8 * lg + i) * 9 + ks]);
#pragma unroll
        for (int r = 0; r < 4; ++r) {
            b1v[0][r] = b1[lg * 4 + r]; b1v[1][r] = b1[16 + lg * 4 + r];
            b2v[r] = b2[lg * 4 + r]; wrv[r] = wr[lg * 4 + r]; brv[r] = br[lg * 4 + r];
        }
    }

    __syncthreads();

    // ---- P3: conv1 = composed 7x7 MFMA -> hs ----
    // h region: rows 18 (by-1..by+16) x cols 34 (bx-1..bx+32), px = r*34+c in [0,612)
    for (int t = wave; t < 39; t += 4) {
        int p  = t * 16 + n;
        int pc = p < 611 ? p : 611;
        int r1 = pc / 34, c1 = pc - 34 * r1;
        int base = r1 * 40 + c1;
        f32x4 acc0 = {0.f,0.f,0.f,0.f}, acc1 = {0.f,0.f,0.f,0.f};
#pragma unroll
        for (int ks = 0; ks < 2; ++ks) {
            const int dy = 4 * ks + lg;
            bf16x8 bv = {0,0,0,0,0,0,0,0};
            if (dy < 7) {                       // dy==7 lanes: A rows are 0
                const short* rp = &xs[base + dy * 40];
#pragma unroll
                for (int i = 0; i < 8; ++i) bv[i] = rp[i];
            }
            acc0 = __builtin_amdgcn_mfma_f32_16x16x32_bf16(wa[0][ks], bv, acc0, 0, 0, 0);
            acc1 = __builtin_amdgcn_mfma_f32_16x16x32_bf16(wa[1][ks], bv, acc1, 0, 0, 0);
        }
        if (p < 612) {
            __hip_bfloat162 q0 = __float22bfloat162_rn(make_float2(
                fmaxf(acc0[0] + b1v[0][0], 0.f), fmaxf(acc0[1] + b1v[0][1], 0.f)));
            __hip_bfloat162 q1 = __float22bfloat162_rn(make_float2(
                fmaxf(acc0[2] + b1v[0][2], 0.f), fmaxf(acc0[3] + b1v[0][3], 0.f)));
            uint2 W0; W0.x = *reinterpret_cast<unsigned*>(&q0);
            W0.y = *reinterpret_cast<unsigned*>(&q1);
            *reinterpret_cast<uint2*>(&hs[(((lg >> 1)) * 624 + p) * 8 + 4 * (lg & 1)]) = W0;
            __hip_bfloat162 q2 = __float22bfloat162_rn(make_float2(
                fmaxf(acc1[0] + b1v[1][0], 0.f), fmaxf(acc1[1] + b1v[1][1], 0.f)));
            __hip_bfloat162 q3 = __float22bfloat162_rn(make_float2(
                fmaxf(acc1[2] + b1v[1][2], 0.f), fmaxf(acc1[3] + b1v[1][3], 0.f)));
            uint2 W1; W1.x = *reinterpret_cast<unsigned*>(&q2);
            W1.y = *reinterpret_cast<unsigned*>(&q3);
            *reinterpret_cast<uint2*>(&hs[((2 + (lg >> 1)) * 624 + p) * 8 + 4 * (lg & 1)]) = W1;
        }
    }
    __syncthreads();

    // ---- P4: conv2 MFMA + epilogue into registers ----
    const int hbase = lg * 624 * 8;
    f32x4 oreg[8];
#pragma unroll
    for (int j = 0; j < 8; ++j) {
        const int tj = wave + 4 * j;        // 0..31 across waves
        const int oy = tj >> 1, hh = tj & 1;
        f32x4 acc = {0.f,0.f,0.f,0.f};
#pragma unroll
        for (int ks = 0; ks < 9; ++ks) {
            const int dy = ks / 3, dx = ks - 3 * (ks / 3);
            const int px = (oy + dy) * 34 + 16 * hh + n + dx;
            bf16x8 hf = *reinterpret_cast<const bf16x8*>(&hs[hbase + px * 8]);
            acc = __builtin_amdgcn_mfma_f32_16x16x32_bf16(a2[ks], hf, acc, 0, 0, 0);
        }
        __hip_bfloat16 xh = *reinterpret_cast<const __hip_bfloat16*>(
            &xs[(oy + 4) * 40 + 16 * hh + n + 4]);
        float xv = __bfloat162float(xh);
        f32x4 o;
#pragma unroll
        for (int r = 0; r < 4; ++r)
            o[r] = fmaxf(acc[r] + b2v[r], 0.f) + wrv[r] * xv + brv[r];
        oreg[j] = o;
    }
    __syncthreads();   // all hs reads done; safe to overwrite pool as stage

    // ---- stage outputs: [oc][row][36] f32 ----
#pragma unroll
    for (int j = 0; j < 8; ++j) {
        const int tj = wave + 4 * j;
        const int oy = tj >> 1, hh = tj & 1;
#pragma unroll
        for (int r = 0; r < 4; ++r)
            stage[(lg * 4 + r) * 576 + oy * 36 + 16 * hh + n] = oreg[j][r];
    }
    __syncthreads();

    // ---- copy: f32x4 NT stores, 8 lanes = one full 128B line ----
#pragma unroll
    for (int k = 0; k < 8; ++k) {
        int idx = k * 256 + tid;               // 2048 float4s
        int c   = idx & 7;
        int row = (idx >> 3) & 15;
        int oc  = idx >> 7;
        f32x4 v = *reinterpret_cast<const f32x4*>(&stage[oc * 576 + row * 36 + 4 * c]);
        __builtin_nontemporal_store(v, reinterpret_cast<f32x4*>(
            &out[(((size_t)b * 16 + oc) * 512 + (by + row)) * 512 + bx + 4 * c]));
    }
}

// ---------------- border kernel (R5 path, 124 border tiles, overwrites ring) ----------------
template<bool USE_WS>
__global__ __launch_bounds__(256, 4) void edge_border(
    const float* __restrict__ x,  const float* __restrict__ w1, const float* __restrict__ b1,
    const float* __restrict__ w2, const float* __restrict__ b2,
    const float* __restrict__ wr, const float* __restrict__ br,
    const short* __restrict__ ws, float* __restrict__ out)
{
    __shared__ short fs2[2 * 400 * 8];
    __shared__ short hs4[4 * 324 * 8];
    __shared__ short xs[24 * XS_S];

    const int tid  = threadIdx.x;
    const int lane = tid & 63;
    const int wave = tid >> 6;
    const int n    = lane & 15;
    const int lg   = lane >> 4;

    int idx = blockIdx.x, tx, ty;
    if      (idx < 32) { tx = idx;      ty = 0;  }
    else if (idx < 64) { tx = idx - 32; ty = 31; }
    else if (idx < 94) { tx = 0;        ty = idx - 63; }
    else               { tx = 31;       ty = idx - 93; }
    const int bx = tx * 16, by = ty * 16, b = blockIdx.z;

    for (int i = tid; i < 576; i += 256) {
        int r = i / 24, c = i % 24;
        int gy = by - 4 + r, gx = bx - 4 + c;
        float v = 0.f;
        if (gy >= 0 && gy < 512 && gx >= 0 && gx < 512) v = x[((size_t)b * 512 + gy) * 512 + gx];
        __hip_bfloat16 h = __float2bfloat16(v);
        xs[r * XS_S + c] = *reinterpret_cast<short*>(&h);
    }

    bf16x8 a1[2][5], a2[9], sb;
    float b1v[2][4], b2v[4], wrv[4], brv[4];
    if (USE_WS) {
#pragma unroll
        for (int mt = 0; mt < 2; ++mt)
#pragma unroll
            for (int ks = 0; ks < 5; ++ks)
                a1[mt][ks] = *reinterpret_cast<const bf16x8*>(&ws[((mt * 5 + ks) * 64 + lane) * 8]);
#pragma unroll
        for (int ks = 0; ks < 9; ++ks)
            a2[ks] = *reinterpret_cast<const bf16x8*>(&ws[WS_A2 + (ks * 64 + lane) * 8]);
        sb = *reinterpret_cast<const bf16x8*>(&ws[WS_SB + lane * 8]);
        const float* wf = (const float*)ws + WS_FLT + lane * 20;
        f32x4 t0 = *reinterpret_cast<const f32x4*>(wf);
        f32x4 t1 = *reinterpret_cast<const f32x4*>(wf + 4);
        f32x4 t2 = *reinterpret_cast<const f32x4*>(wf + 8);
        f32x4 t3 = *reinterpret_cast<const f32x4*>(wf + 12);
        f32x4 t4 = *reinterpret_cast<const f32x4*>(wf + 16);
#pragma unroll
        for (int r = 0; r < 4; ++r) {
            b1v[0][r] = t0[r]; b1v[1][r] = t1[r];
            b2v[r] = t2[r]; wrv[r] = t3[r]; brv[r] = t4[r];
        }
    } else {
#pragma unroll
        for (int mt = 0; mt < 2; ++mt)
#pragma unroll
            for (int ks = 0; ks < 5; ++ks)
#pragma unroll
                for (int i = 0; i < 8; ++i) {
                    int k = 32 * ks + 8 * lg + i;
                    int g = k >> 4, ch = k & 15;
                    float w = (g < 9 && ch < 9) ? w1[(mt * 16 + n) * 81 + ch * 9 + g] : 0.f;
                    a1[mt][ks][i] = (short)f2bf(w);
                }
#pragma unroll
        for (int ks = 0; ks < 9; ++ks)
#pragma unroll
            for (int i = 0; i < 8; ++i)
                a2[ks][i] = (short)f2bf(w2[n * 288 + (8 * lg + i) * 9 + ks]);
#pragma unroll
        for (int i = 0; i < 8; ++i) {
            int k = 8 * lg + i;
            float v = (k < 25 && n < 9) ? EB[n][k / 5][k % 5] : 0.f;
            sb[i] = (short)f2bf(v);
        }
#pragma unroll
        for (int r = 0; r < 4; ++r) {
            b1v[0][r] = b1[lg * 4 + r]; b1v[1][r] = b1[16 + lg * 4 + r];
            b2v[r] = b2[lg * 4 + r]; wrv[r] = wr[lg * 4 + r]; brv[r] = br[lg * 4 + r];
        }
    }

    int toff[8];
#pragma unroll
    for (int i = 0; i < 8; ++i) {
        int k = 8 * lg + i;
        int t = k < 25 ? k : 24;
        toff[i] = (t / 5) * XS_S + (t % 5);
    }
    int boff[5];
#pragma unroll
    for (int ks = 0; ks < 5; ++ks) {
        int g = 2 * ks + (lg >> 1); if (g > 8) g = 8;
        int dy = g / 3, dx = g - 3 * dy;
        boff[ks] = (lg & 1) * 3200 + (dy * 20 + dx) * 8;
    }

    __syncthreads();

    for (int t = wave; t < 25; t += 4) {
        int px = t * 16 + n;
        int r = px / 20, c = px - 20 * r;
        const short* base = &xs[r * XS_S + c];
        bf16x8 bv;
#pragma unroll
        for (int i = 0; i < 8; ++i) bv[i] = base[toff[i]];
        f32x4 f = {0.f, 0.f, 0.f, 0.f};
        f = __builtin_amdgcn_mfma_f32_16x16x32_bf16(sb, bv, f, 0, 0, 0);
        int fy = by + r - 2, fx = bx + c - 2;
        float m = (fy >= 0 && fy < 512 && fx >= 0 && fx < 512) ? 1.f : 0.f;
        __hip_bfloat162 p0 = __float22bfloat162_rn(make_float2(f[0] * m, f[1] * m));
        __hip_bfloat162 p1 = __float22bfloat162_rn(make_float2(f[2] * m, f[3] * m));
        uint2 wv;
        wv.x = *reinterpret_cast<unsigned*>(&p0);
        wv.y = *reinterpret_cast<unsigned*>(&p1);
        *reinterpret_cast<uint2*>(&fs2[((lg >> 1) * 400 + px) * 8 + 4 * (lg & 1)]) = wv;
    }
    __syncthreads();

    for (int t = wave; t < 21; t += 4) {
        int p  = t * 16 + n;
        int pc = p < 323 ? p : 323;
        int r1 = pc / 18, c1 = pc - 18 * r1;
        int base = (r1 * 20 + c1) * 8;
        f32x4 acc0 = {0.f,0.f,0.f,0.f}, acc1 = {0.f,0.f,0.f,0.f};
#pragma unroll
        for (int ks = 0; ks < 5; ++ks) {
            bf16x8 bf = *reinterpret_cast<const bf16x8*>(&fs2[base + boff[ks]]);
            acc0 = __builtin_amdgcn_mfma_f32_16x16x32_bf16(a1[0][ks], bf, acc0, 0, 0, 0);
            acc1 = __builtin_amdgcn_mfma_f32_16x16x32_bf16(a1[1][ks], bf, acc1, 0, 0, 0);
        }
        if (p < 324) {
            int hy = by - 1 + r1, hx = bx - 1 + c1;
            float m = (hy >= 0 && hy < 512 && hx >= 0 && hx < 512) ? 1.f : 0.f;
            __hip_bfloat162 q0 = __float22bfloat162_rn(make_float2(
                fmaxf(acc0[0] + b1v[0][0], 0.f) * m, fmaxf(acc0[1] + b1v[0][1], 0.f) * m));
            __hip_bfloat162 q1 = __float22bfloat162_rn(make_float2(
                fmaxf(acc0[2] + b1v[0][2], 0.f) * m, fmaxf(acc0[3] + b1v[0][3], 0.f) * m));
            uint2 W0; W0.x = *reinterpret_cast<unsigned*>(&q0);
            W0.y = *reinterpret_cast<unsigned*>(&q1);
            *reinterpret_cast<uint2*>(&hs4[((lg >> 1) * 324 + p) * 8 + 4 * (lg & 1)]) = W0;
            __hip_bfloat162 q2 = __float22bfloat162_rn(make_float2(
                fmaxf(acc1[0] + b1v[1][0], 0.f) * m, fmaxf(acc1[1] + b1v[1][1], 0.f) * m));
            __hip_bfloat162 q3 = __float22bfloat162_rn(make_float2(
                fmaxf(acc1[2] + b1v[1][2], 0.f) * m, fmaxf(acc1[3] + b1v[1][3], 0.f) * m));
            uint2 W1; W1.x = *reinterpret_cast<unsigned*>(&q2);
            W1.y = *reinterpret_cast<unsigned*>(&q3);
            *reinterpret_cast<uint2*>(&hs4[((2 + (lg >> 1)) * 324 + p) * 8 + 4 * (lg & 1)]) = W1;
        }
    }
    __syncthreads();

    const int hbase = lg * 324 * 8;
#pragma unroll
    for (int j = 0; j < 4; ++j) {
        int oy = wave + 4 * j;
        f32x4 acc = {0.f,0.f,0.f,0.f};
#pragma unroll
        for (int ks = 0; ks < 9; ++ks) {
            const int dy = ks / 3, dx = ks - 3 * (ks / 3);
            bf16x8 hf = *reinterpret_cast<const bf16x8*>(
                &hs4[hbase + ((oy + dy) * 18 + n + dx) * 8]);
            acc = __builtin_amdgcn_mfma_f32_16x16x32_bf16(a2[ks], hf, acc, 0, 0, 0);
        }
        __hip_bfloat16 xh = *reinterpret_cast<const __hip_bfloat16*>(&xs[(oy + 4) * XS_S + n + 4]);
        float xv = __bfloat162float(xh);
        float* op = out + (((size_t)(b * 16 + lg * 4) * 512 + (by + oy)) * 512) + bx + n;
#pragma unroll
        for (int r = 0; r < 4; ++r) {
            float o = fmaxf(acc[r] + b2v[r], 0.f) + wrv[r] * xv + brv[r];
            __builtin_nontemporal_store(o, op);
            op += 262144;
        }
    }
}

extern "C" void kernel_launch(void* const* d_in, const int* in_sizes, int n_in,
                              void* d_out, int out_size, void* d_ws, size_t ws_size,
                              hipStream_t stream) {
    const float* x  = (const float*)d_in[0];
    const float* w1 = (const float*)d_in[1];
    const float* b1 = (const float*)d_in[2];
    const float* w2 = (const float*)d_in[3];
    const float* b2 = (const float*)d_in[4];
    const float* wr = (const float*)d_in[5];
    const float* br = (const float*)d_in[6];
    float* out = (float*)d_out;
    short* ws = (short*)d_ws;

    dim3 block(256);
    dim3 gin(16, 32, 8);    // 16x32-tile full grid
    dim3 gbd(124, 1, 8);    // border overwrite
    if (ws_size >= WS_BYTES) {
        hipLaunchKernelGGL(setup_frags, dim3(1), dim3(256), 0, stream,
                           w1, b1, w2, b2, wr, br, ws);
        hipLaunchKernelGGL(edge_interior2<true>, gin, block, 0, stream,
                           x, w1, b1, w2, b2, wr, br, ws, out);
        hipLaunchKernelGGL(edge_border<true>, gbd, block, 0, stream,
                           x, w1, b1, w2, b2, wr, br, ws, out);
    } else {
        hipLaunchKernelGGL(edge_interior2<false>, gin, block, 0, stream,
                           x, w1, b1, w2, b2, wr, br, ws, out);
        hipLaunchKernelGGL(edge_border<false>, gbd, block, 0, stream,
                           x, w1, b1, w2, b2, wr, br, ws, out);
    }
}

// Round 10
// 107.853 us; speedup vs baseline: 2.2379x; 1.0598x over previous
//
#include <hip/hip_runtime.h>
#include <hip/hip_bf16.h>

// EnhancedEdgeLayer R10: composed-conv interior, LDS-pipe-minimized.
//  - P3 (7x7 conv1) B-windows read from GLOBAL x (L1-hot, clamped) -> VMEM pipe,
//    not LDS; xs tile eliminated.
//  - hs layout [612 px][32 k] bf16, K-bijection ic=((i&1)<<4)|(lg<<2)|((i>>1)&3)
//    -> P3 writes ONE b128/lane, P4 reads ONE b128/lane; 16B-group XOR swizzle
//    grp = lg ^ (px&3) keeps service groups 2-way (free).
//  - P4 quad-row blocking: 4 out rows from 6 h-rows x 3 dx = 18 reads (was 36).
//  - LDS 39168B (hs UNION stage) -> 4 blocks/CU. 3 barriers total.
//  - interior grid skips y-edge tiles (border kernel owns them); border kernel
//    uses plain stores (NT 64B segments caused HBM RMW).

typedef __attribute__((ext_vector_type(8))) short bf16x8;
typedef __attribute__((ext_vector_type(4))) float f32x4;

#define XS_S 28   // border kernel xs stride (shorts)

// ws layout (shorts):
//  A1   [2][5][64][8]  @ 0      border conv1 fragments
//  A2   [9][64][8]     @ 5120   border conv2 fragments (old bijection)
//  SB   [64][8]        @ 9728   border stencil-bank fragments
//  FLT  floats         @ short 10240 (float off 5120): per-lane 20 floats
//  WEFF [2][2][64][8]  @ 12800  composed 7x7 fragments
//  A2I  [9][64][8]     @ 14848  interior conv2 fragments (interleaved bijection)
#define WS_A2   5120
#define WS_SB   9728
#define WS_FLT  5120      // float offset
#define WS_WEFF 12800
#define WS_A2I  14848
#define WS_BYTES 38912

__device__ const float EB[9][5][5] = {
 {{0,0,0,0,0},{0,-1,0,1,0},{0,-2,0,2,0},{0,-1,0,1,0},{0,0,0,0,0}},        // sobel_x
 {{0,0,0,0,0},{0,-1,-2,-1,0},{0,0,0,0,0},{0,1,2,1,0},{0,0,0,0,0}},        // sobel_y
 {{0,0,0,0,0},{0,0,1,2,0},{0,-1,0,1,0},{0,-2,-1,0,0},{0,0,0,0,0}},        // diag1
 {{0,0,0,0,0},{0,-2,-1,0,0},{0,-1,0,1,0},{0,0,1,2,0},{0,0,0,0,0}},        // diag2
 {{0,0,0,0,0},{0,0,1,0,0},{0,1,-4,1,0},{0,0,1,0,0},{0,0,0,0,0}},          // laplacian
 {{-1,-2,0,2,1},{-2,-3,0,3,2},{-3,-4,0,4,3},{-2,-3,0,3,2},{-1,-2,0,2,1}}, // gradient5x5
 {{0,0,0,0,0},{0,-3,0,3,0},{0,-10,0,10,0},{0,-3,0,3,0},{0,0,0,0,0}},      // scharr_x
 {{0,0,0,0,0},{0,-3,-10,-3,0},{0,0,0,0,0},{0,3,10,3,0},{0,0,0,0,0}},      // scharr_y
 {{0,0,0,0,0},{0,0,0,0,0},{0,0,1,0,0},{0,0,0,0,0},{0,0,0,0,0}},           // identity
};

__device__ __forceinline__ unsigned short f2bf(float f) {
    union { float f; unsigned u; } v; v.f = f;
    unsigned u = v.u + 0x7fffu + ((v.u >> 16) & 1u);   // RNE
    return (unsigned short)(u >> 16);
}
__device__ __forceinline__ unsigned pk(float lo, float hi) {
    return (unsigned)f2bf(lo) | ((unsigned)f2bf(hi) << 16);
}

__device__ __forceinline__ float weff_tap(const float* __restrict__ w1,
                                          int oc, int dy, int dx) {
    float s = 0.f;
    for (int ch = 0; ch < 9; ++ch)
        for (int ty = 0; ty < 3; ++ty)
            for (int tx = 0; tx < 3; ++tx) {
                int sy = dy - ty, sx = dx - tx;
                if (sy >= 0 && sy < 5 && sx >= 0 && sx < 5)
                    s += w1[(oc * 9 + ch) * 9 + ty * 3 + tx] * EB[ch][sy][sx];
            }
    return s;
}

// ---- fast setup: 256 threads, LDS-staged weights, flat work split ----
__global__ __launch_bounds__(256) void setup_frags(
    const float* __restrict__ w1, const float* __restrict__ b1,
    const float* __restrict__ w2, const float* __restrict__ b2,
    const float* __restrict__ wr, const float* __restrict__ br,
    short* __restrict__ ws)
{
    __shared__ float w1s[2592];
    __shared__ float w2s[4608];
    __shared__ float ebs[225];
    const int tid = threadIdx.x;

    for (int i = tid; i < 2592; i += 256) w1s[i] = w1[i];
    for (int i = tid; i < 4608; i += 256) w2s[i] = w2[i];
    if (tid < 225) ebs[tid] = ((const float*)EB)[tid];
    __syncthreads();

    for (int idx = tid; idx < 5120; idx += 256) {           // A1 (border)
        int i = idx & 7, lane = (idx >> 3) & 63, rest = idx >> 9;
        int mt = rest / 5, ks = rest - 5 * mt;
        int n = lane & 15, lg = lane >> 4;
        int k = 32 * ks + 8 * lg + i;
        int g = k >> 4, ch = k & 15;
        float w = (g < 9 && ch < 9) ? w1s[(mt * 16 + n) * 81 + ch * 9 + g] : 0.f;
        ws[idx] = (short)f2bf(w);
    }
    for (int idx = tid; idx < 4608; idx += 256) {           // A2 (border, old)
        int i = idx & 7, lane = (idx >> 3) & 63, ks = idx >> 9;
        int n = lane & 15, lg = lane >> 4;
        int ic = 8 * lg + i;
        ws[WS_A2 + idx] = (short)f2bf(w2s[n * 288 + ic * 9 + ks]);
    }
    for (int idx = tid; idx < 4608; idx += 256) {           // A2I (interior, interleaved)
        int i = idx & 7, lane = (idx >> 3) & 63, ks = idx >> 9;
        int n = lane & 15, lg = lane >> 4;
        int ic = ((i & 1) << 4) | (lg << 2) | ((i >> 1) & 3);
        ws[WS_A2I + idx] = (short)f2bf(w2s[n * 288 + ic * 9 + ks]);
    }
    for (int idx = tid; idx < 512; idx += 256) {            // SB (border)
        int i = idx & 7, lane = idx >> 3;
        int n = lane & 15, lg = lane >> 4;
        int k = 8 * lg + i;
        float v = (k < 25 && n < 9) ? ebs[n * 25 + k] : 0.f;
        ws[WS_SB + idx] = (short)f2bf(v);
    }
    for (int idx = tid; idx < 2048; idx += 256) {           // WEFF
        int i = idx & 7, lane = (idx >> 3) & 63, rest = idx >> 9;
        int mt = rest >> 1, ks = rest & 1;
        int n = lane & 15, lg = lane >> 4;
        int dy = 4 * ks + lg, dx = i;
        float s = 0.f;
        if (dy < 7 && dx < 7) {
            int oc = mt * 16 + n;
            for (int ch = 0; ch < 9; ++ch)
                for (int ty = 0; ty < 3; ++ty) {
                    int sy = dy - ty;
                    if (sy < 0 || sy >= 5) continue;
                    for (int tx = 0; tx < 3; ++tx) {
                        int sx = dx - tx;
                        if (sx >= 0 && sx < 5)
                            s += w1s[(oc * 9 + ch) * 9 + ty * 3 + tx] * ebs[ch * 25 + sy * 5 + sx];
                    }
                }
        }
        ws[WS_WEFF + idx] = (short)f2bf(s);
    }
    if (tid < 64) {                                         // FLT
        int lg = tid >> 4;
        float* wf = (float*)ws + WS_FLT + tid * 20;
        for (int r = 0; r < 4; ++r) {
            wf[r]      = b1[lg * 4 + r];
            wf[4 + r]  = b1[16 + lg * 4 + r];
            wf[8 + r]  = b2[lg * 4 + r];
            wf[12 + r] = wr[lg * 4 + r];
            wf[16 + r] = br[lg * 4 + r];
        }
    }
}

// ---------------- interior kernel: 16x32 tiles, composed 7x7, global-gather ----
template<bool USE_WS>
__global__ __launch_bounds__(256, 4) void edge_interior3(
    const float* __restrict__ x,  const float* __restrict__ w1, const float* __restrict__ b1,
    const float* __restrict__ w2, const float* __restrict__ b2,
    const float* __restrict__ wr, const float* __restrict__ br,
    const short* __restrict__ ws, float* __restrict__ out)
{
    // pool: hs [612 px][32 k] shorts (39168B)  UNION  stage [16oc][16row][36] f32 (36864B)
    __shared__ long long pool[39168 / 8];
    short* hsS   = (short*)pool;
    float* stage = (float*)pool;

    const int tid  = threadIdx.x;
    const int lane = tid & 63;
    const int wave = tid >> 6;
    const int n    = lane & 15;
    const int lg   = lane >> 4;
    const int bx = blockIdx.x * 32;
    const int by = (blockIdx.y + 1) * 16;   // y-edge tiles owned by border kernel
    const int b  = blockIdx.z;
    const float* xb = x + ((size_t)b << 18);

    // ---- P1: fragments -> registers ----
    bf16x8 wa[2][2], a2[9];
    float b1v[2][4], b2v[4], wrv[4], brv[4];
    if (USE_WS) {
#pragma unroll
        for (int mt = 0; mt < 2; ++mt)
#pragma unroll
            for (int ks = 0; ks < 2; ++ks)
                wa[mt][ks] = *reinterpret_cast<const bf16x8*>(
                    &ws[WS_WEFF + ((mt * 2 + ks) * 64 + lane) * 8]);
#pragma unroll
        for (int ks = 0; ks < 9; ++ks)
            a2[ks] = *reinterpret_cast<const bf16x8*>(&ws[WS_A2I + (ks * 64 + lane) * 8]);
        const float* wf = (const float*)ws + WS_FLT + lane * 20;
        f32x4 t0 = *reinterpret_cast<const f32x4*>(wf);
        f32x4 t1 = *reinterpret_cast<const f32x4*>(wf + 4);
        f32x4 t2 = *reinterpret_cast<const f32x4*>(wf + 8);
        f32x4 t3 = *reinterpret_cast<const f32x4*>(wf + 12);
        f32x4 t4 = *reinterpret_cast<const f32x4*>(wf + 16);
#pragma unroll
        for (int r = 0; r < 4; ++r) {
            b1v[0][r] = t0[r]; b1v[1][r] = t1[r];
            b2v[r] = t2[r]; wrv[r] = t3[r]; brv[r] = t4[r];
        }
    } else {
#pragma unroll
        for (int mt = 0; mt < 2; ++mt)
#pragma unroll
            for (int ks = 0; ks < 2; ++ks)
#pragma unroll
                for (int i = 0; i < 8; ++i) {
                    int dy = 4 * ks + lg, dx = i;
                    float s = (dy < 7 && dx < 7) ? weff_tap(w1, mt * 16 + n, dy, dx) : 0.f;
                    wa[mt][ks][i] = (short)f2bf(s);
                }
#pragma unroll
        for (int ks = 0; ks < 9; ++ks)
#pragma unroll
            for (int i = 0; i < 8; ++i) {
                int ic = ((i & 1) << 4) | (lg << 2) | ((i >> 1) & 3);
                a2[ks][i] = (short)f2bf(w2[(n * 32 + ic) * 9 + ks]);
            }
#pragma unroll
        for (int r = 0; r < 4; ++r) {
            b1v[0][r] = b1[lg * 4 + r]; b1v[1][r] = b1[16 + lg * 4 + r];
            b2v[r] = b2[lg * 4 + r]; wrv[r] = wr[lg * 4 + r]; brv[r] = br[lg * 4 + r];
        }
    }

    // ---- P3: conv1 = composed 7x7, B-windows from GLOBAL x -> hs ----
    // h region: rows 18 (by-1..by+16) x cols 34 (bx-1..bx+32), px = r1*34+c1
    for (int t = wave; t < 39; t += 4) {
        int p  = t * 16 + n;
        int pc = p < 611 ? p : 611;
        int r1 = pc / 34, c1 = pc - 34 * r1;
        int gxb = bx - 4 + c1; gxb = gxb < 0 ? 0 : (gxb > 504 ? 504 : gxb);
        int gyb = by - 4 + r1;
        f32x4 acc0 = {0.f,0.f,0.f,0.f}, acc1 = {0.f,0.f,0.f,0.f};
#pragma unroll
        for (int ks = 0; ks < 2; ++ks) {
            const int dy = 4 * ks + lg;
            bf16x8 bv = {0,0,0,0,0,0,0,0};
            if (dy < 7) {
                int gy = gyb + dy; gy = gy < 0 ? 0 : (gy > 511 ? 511 : gy);
                const float* xp = xb + ((size_t)gy << 9) + gxb;
                uint4 u;
                u.x = pk(xp[0], xp[1]); u.y = pk(xp[2], xp[3]);
                u.z = pk(xp[4], xp[5]); u.w = pk(xp[6], xp[7]);
                bv = *reinterpret_cast<bf16x8*>(&u);
            }
            acc0 = __builtin_amdgcn_mfma_f32_16x16x32_bf16(wa[0][ks], bv, acc0, 0, 0, 0);
            acc1 = __builtin_amdgcn_mfma_f32_16x16x32_bf16(wa[1][ks], bv, acc1, 0, 0, 0);
        }
        if (p < 612) {
            // interleave: group lg, short j = 2r+mt  -> ic = 16mt + 4lg + r
            float h0 = fmaxf(acc0[0] + b1v[0][0], 0.f), g0 = fmaxf(acc1[0] + b1v[1][0], 0.f);
            float h1 = fmaxf(acc0[1] + b1v[0][1], 0.f), g1 = fmaxf(acc1[1] + b1v[1][1], 0.f);
            float h2 = fmaxf(acc0[2] + b1v[0][2], 0.f), g2 = fmaxf(acc1[2] + b1v[1][2], 0.f);
            float h3 = fmaxf(acc0[3] + b1v[0][3], 0.f), g3 = fmaxf(acc1[3] + b1v[1][3], 0.f);
            uint4 W;
            W.x = pk(h0, g0); W.y = pk(h1, g1); W.z = pk(h2, g2); W.w = pk(h3, g3);
            int grp = lg ^ (p & 3);
            *reinterpret_cast<uint4*>(&hsS[p * 32 + grp * 8]) = W;
        }
    }
    __syncthreads();

    // ---- P4: conv2, quad-row blocking ----
    const int q0 = wave >> 1;
    const int hh = wave & 1;
    f32x4 oreg[8];
#pragma unroll
    for (int j = 0; j < 2; ++j) {
        const int q = q0 + 2 * j;            // quad index 0..3 -> out rows 4q..4q+3
        f32x4 acc[4] = {{0.f,0.f,0.f,0.f},{0.f,0.f,0.f,0.f},
                        {0.f,0.f,0.f,0.f},{0.f,0.f,0.f,0.f}};
#pragma unroll
        for (int rr = 0; rr < 6; ++rr) {     // h rows 4q..4q+5
#pragma unroll
            for (int dx = 0; dx < 3; ++dx) {
                const int px = (4 * q + rr) * 34 + 16 * hh + n + dx;
                const int grp = lg ^ (px & 3);
                bf16x8 hf = *reinterpret_cast<const bf16x8*>(&hsS[px * 32 + grp * 8]);
#pragma unroll
                for (int o = 0; o < 4; ++o) {
                    const int dy = rr - o;
                    if (dy >= 0 && dy < 3)
                        acc[o] = __builtin_amdgcn_mfma_f32_16x16x32_bf16(
                            a2[dy * 3 + dx], hf, acc[o], 0, 0, 0);
                }
            }
        }
#pragma unroll
        for (int o = 0; o < 4; ++o) {
            const int oy = 4 * q + o;
            float xv = xb[((size_t)(by + oy) << 9) + bx + 16 * hh + n];
            f32x4 ov;
#pragma unroll
            for (int r = 0; r < 4; ++r)
                ov[r] = fmaxf(acc[o][r] + b2v[r], 0.f) + wrv[r] * xv + brv[r];
            oreg[4 * j + o] = ov;
        }
    }
    __syncthreads();   // hs reads done; pool becomes stage

    // ---- stage outputs: [oc][row][36] f32 ----
#pragma unroll
    for (int j = 0; j < 2; ++j) {
        const int q = q0 + 2 * j;
#pragma unroll
        for (int o = 0; o < 4; ++o)
#pragma unroll
            for (int r = 0; r < 4; ++r)
                stage[(lg * 4 + r) * 576 + (4 * q + o) * 36 + 16 * hh + n] = oreg[4 * j + o][r];
    }
    __syncthreads();

    // ---- copy: f32x4 NT stores, 8 lanes = one full 128B line ----
#pragma unroll
    for (int k = 0; k < 8; ++k) {
        int idx = k * 256 + tid;               // 2048 float4s
        int c   = idx & 7;
        int row = (idx >> 3) & 15;
        int oc  = idx >> 7;
        f32x4 v = *reinterpret_cast<const f32x4*>(&stage[oc * 576 + row * 36 + 4 * c]);
        __builtin_nontemporal_store(v, reinterpret_cast<f32x4*>(
            &out[(((size_t)b * 16 + oc) * 512 + (by + row)) * 512 + bx + 4 * c]));
    }
}

// ---------------- border kernel (R5 path, 124 border tiles; plain stores) ----
template<bool USE_WS>
__global__ __launch_bounds__(256, 4) void edge_border(
    const float* __restrict__ x,  const float* __restrict__ w1, const float* __restrict__ b1,
    const float* __restrict__ w2, const float* __restrict__ b2,
    const float* __restrict__ wr, const float* __restrict__ br,
    const short* __restrict__ ws, float* __restrict__ out)
{
    __shared__ short fs2[2 * 400 * 8];
    __shared__ short hs4[4 * 324 * 8];
    __shared__ short xs[24 * XS_S];

    const int tid  = threadIdx.x;
    const int lane = tid & 63;
    const int wave = tid >> 6;
    const int n    = lane & 15;
    const int lg   = lane >> 4;

    int idx = blockIdx.x, tx, ty;
    if      (idx < 32) { tx = idx;      ty = 0;  }
    else if (idx < 64) { tx = idx - 32; ty = 31; }
    else if (idx < 94) { tx = 0;        ty = idx - 63; }
    else               { tx = 31;       ty = idx - 93; }
    const int bx = tx * 16, by = ty * 16, b = blockIdx.z;

    for (int i = tid; i < 576; i += 256) {
        int r = i / 24, c = i % 24;
        int gy = by - 4 + r, gx = bx - 4 + c;
        float v = 0.f;
        if (gy >= 0 && gy < 512 && gx >= 0 && gx < 512) v = x[((size_t)b * 512 + gy) * 512 + gx];
        __hip_bfloat16 h = __float2bfloat16(v);
        xs[r * XS_S + c] = *reinterpret_cast<short*>(&h);
    }

    bf16x8 a1[2][5], a2[9], sb;
    float b1v[2][4], b2v[4], wrv[4], brv[4];
    if (USE_WS) {
#pragma unroll
        for (int mt = 0; mt < 2; ++mt)
#pragma unroll
            for (int ks = 0; ks < 5; ++ks)
                a1[mt][ks] = *reinterpret_cast<const bf16x8*>(&ws[((mt * 5 + ks) * 64 + lane) * 8]);
#pragma unroll
        for (int ks = 0; ks < 9; ++ks)
            a2[ks] = *reinterpret_cast<const bf16x8*>(&ws[WS_A2 + (ks * 64 + lane) * 8]);
        sb = *reinterpret_cast<const bf16x8*>(&ws[WS_SB + lane * 8]);
        const float* wf = (const float*)ws + WS_FLT + lane * 20;
        f32x4 t0 = *reinterpret_cast<const f32x4*>(wf);
        f32x4 t1 = *reinterpret_cast<const f32x4*>(wf + 4);
        f32x4 t2 = *reinterpret_cast<const f32x4*>(wf + 8);
        f32x4 t3 = *reinterpret_cast<const f32x4*>(wf + 12);
        f32x4 t4 = *reinterpret_cast<const f32x4*>(wf + 16);
#pragma unroll
        for (int r = 0; r < 4; ++r) {
            b1v[0][r] = t0[r]; b1v[1][r] = t1[r];
            b2v[r] = t2[r]; wrv[r] = t3[r]; brv[r] = t4[r];
        }
    } else {
#pragma unroll
        for (int mt = 0; mt < 2; ++mt)
#pragma unroll
            for (int ks = 0; ks < 5; ++ks)
#pragma unroll
                for (int i = 0; i < 8; ++i) {
                    int k = 32 * ks + 8 * lg + i;
                    int g = k >> 4, ch = k & 15;
                    float w = (g < 9 && ch < 9) ? w1[(mt * 16 + n) * 81 + ch * 9 + g] : 0.f;
                    a1[mt][ks][i] = (short)f2bf(w);
                }
#pragma unroll
        for (int ks = 0; ks < 9; ++ks)
#pragma unroll
            for (int i = 0; i < 8; ++i)
                a2[ks][i] = (short)f2bf(w2[n * 288 + (8 * lg + i) * 9 + ks]);
#pragma unroll
        for (int i = 0; i < 8; ++i) {
            int k = 8 * lg + i;
            float v = (k < 25 && n < 9) ? EB[n][k / 5][k % 5] : 0.f;
            sb[i] = (short)f2bf(v);
        }
#pragma unroll
        for (int r = 0; r < 4; ++r) {
            b1v[0][r] = b1[lg * 4 + r]; b1v[1][r] = b1[16 + lg * 4 + r];
            b2v[r] = b2[lg * 4 + r]; wrv[r] = wr[lg * 4 + r]; brv[r] = br[lg * 4 + r];
        }
    }

    int toff[8];
#pragma unroll
    for (int i = 0; i < 8; ++i) {
        int k = 8 * lg + i;
        int t = k < 25 ? k : 24;
        toff[i] = (t / 5) * XS_S + (t % 5);
    }
    int boff[5];
#pragma unroll
    for (int ks = 0; ks < 5; ++ks) {
        int g = 2 * ks + (lg >> 1); if (g > 8) g = 8;
        int dy = g / 3, dx = g - 3 * dy;
        boff[ks] = (lg & 1) * 3200 + (dy * 20 + dx) * 8;
    }

    __syncthreads();

    for (int t = wave; t < 25; t += 4) {
        int px = t * 16 + n;
        int r = px / 20, c = px - 20 * r;
        const short* base = &xs[r * XS_S + c];
        bf16x8 bv;
#pragma unroll
        for (int i = 0; i < 8; ++i) bv[i] = base[toff[i]];
        f32x4 f = {0.f, 0.f, 0.f, 0.f};
        f = __builtin_amdgcn_mfma_f32_16x16x32_bf16(sb, bv, f, 0, 0, 0);
        int fy = by + r - 2, fx = bx + c - 2;
        float m = (fy >= 0 && fy < 512 && fx >= 0 && fx < 512) ? 1.f : 0.f;
        uint2 wv;
        wv.x = pk(f[0] * m, f[1] * m);
        wv.y = pk(f[2] * m, f[3] * m);
        *reinterpret_cast<uint2*>(&fs2[((lg >> 1) * 400 + px) * 8 + 4 * (lg & 1)]) = wv;
    }
    __syncthreads();

    for (int t = wave; t < 21; t += 4) {
        int p  = t * 16 + n;
        int pc = p < 323 ? p : 323;
        int r1 = pc / 18, c1 = pc - 18 * r1;
        int base = (r1 * 20 + c1) * 8;
        f32x4 acc0 = {0.f,0.f,0.f,0.f}, acc1 = {0.f,0.f,0.f,0.f};
#pragma unroll
        for (int ks = 0; ks < 5; ++ks) {
            bf16x8 bf = *reinterpret_cast<const bf16x8*>(&fs2[base + boff[ks]]);
            acc0 = __builtin_amdgcn_mfma_f32_16x16x32_bf16(a1[0][ks], bf, acc0, 0, 0, 0);
            acc1 = __builtin_amdgcn_mfma_f32_16x16x32_bf16(a1[1][ks], bf, acc1, 0, 0, 0);
        }
        if (p < 324) {
            int hy = by - 1 + r1, hx = bx - 1 + c1;
            float m = (hy >= 0 && hy < 512 && hx >= 0 && hx < 512) ? 1.f : 0.f;
            uint2 W0;
            W0.x = pk(fmaxf(acc0[0] + b1v[0][0], 0.f) * m, fmaxf(acc0[1] + b1v[0][1], 0.f) * m);
            W0.y = pk(fmaxf(acc0[2] + b1v[0][2], 0.f) * m, fmaxf(acc0[3] + b1v[0][3], 0.f) * m);
            *reinterpret_cast<uint2*>(&hs4[((lg >> 1) * 324 + p) * 8 + 4 * (lg & 1)]) = W0;
            uint2 W1;
            W1.x = pk(fmaxf(acc1[0] + b1v[1][0], 0.f) * m, fmaxf(acc1[1] + b1v[1][1], 0.f) * m);
            W1.y = pk(fmaxf(acc1[2] + b1v[1][2], 0.f) * m, fmaxf(acc1[3] + b1v[1][3], 0.f) * m);
            *reinterpret_cast<uint2*>(&hs4[((2 + (lg >> 1)) * 324 + p) * 8 + 4 * (lg & 1)]) = W1;
        }
    }
    __syncthreads();

    const int hbase = lg * 324 * 8;
#pragma unroll
    for (int j = 0; j < 4; ++j) {
        int oy = wave + 4 * j;
        f32x4 acc = {0.f,0.f,0.f,0.f};
#pragma unroll
        for (int ks = 0; ks < 9; ++ks) {
            const int dy = ks / 3, dx = ks - 3 * (ks / 3);
            bf16x8 hf = *reinterpret_cast<const bf16x8*>(
                &hs4[hbase + ((oy + dy) * 18 + n + dx) * 8]);
            acc = __builtin_amdgcn_mfma_f32_16x16x32_bf16(a2[ks], hf, acc, 0, 0, 0);
        }
        __hip_bfloat16 xh = *reinterpret_cast<const __hip_bfloat16*>(&xs[(oy + 4) * XS_S + n + 4]);
        float xv = __bfloat162float(xh);
        float* op = out + (((size_t)(b * 16 + lg * 4) * 512 + (by + oy)) * 512) + bx + n;
#pragma unroll
        for (int r = 0; r < 4; ++r) {
            float o = fmaxf(acc[r] + b2v[r], 0.f) + wrv[r] * xv + brv[r];
            *op = o;                     // plain store: L2 absorbs 64B segments
            op += 262144;
        }
    }
}

extern "C" void kernel_launch(void* const* d_in, const int* in_sizes, int n_in,
                              void* d_out, int out_size, void* d_ws, size_t ws_size,
                              hipStream_t stream) {
    const float* x  = (const float*)d_in[0];
    const float* w1 = (const float*)d_in[1];
    const float* b1 = (const float*)d_in[2];
    const float* w2 = (const float*)d_in[3];
    const float* b2 = (const float*)d_in[4];
    const float* wr = (const float*)d_in[5];
    const float* br = (const float*)d_in[6];
    float* out = (float*)d_out;
    short* ws = (short*)d_ws;

    dim3 block(256);
    dim3 gin(16, 30, 8);    // 16x32 tiles, y-edge rows excluded (border owns them)
    dim3 gbd(124, 1, 8);    // border tiles
    if (ws_size >= WS_BYTES) {
        hipLaunchKernelGGL(setup_frags, dim3(1), dim3(256), 0, stream,
                           w1, b1, w2, b2, wr, br, ws);
        hipLaunchKernelGGL(edge_interior3<true>, gin, block, 0, stream,
                           x, w1, b1, w2, b2, wr, br, ws, out);
        hipLaunchKernelGGL(edge_border<true>, gbd, block, 0, stream,
                           x, w1, b1, w2, b2, wr, br, ws, out);
    } else {
        hipLaunchKernelGGL(edge_interior3<false>, gin, block, 0, stream,
                           x, w1, b1, w2, b2, wr, br, ws, out);
        hipLaunchKernelGGL(edge_border<false>, gbd, block, 0, stream,
                           x, w1, b1, w2, b2, wr, br, ws, out);
    }
}

// Round 11
// 106.520 us; speedup vs baseline: 2.2659x; 1.0125x over previous
//
#include <hip/hip_runtime.h>
#include <hip/hip_bf16.h>

// EnhancedEdgeLayer R11: R10 + (a) hw cvt_pk packs (no manual f2bf in hot path),
// (b) proper XOR swizzle grp = lg ^ (px&3) ^ ((px>>2)&3) (kills 4-way conflicts),
// (c) dead-clamp removal. Structure unchanged:
//  interior: composed 7x7 conv from global x -> hs[612][32] LDS -> conv2 -> staged
//  full-line NT stores; border: R5 path on 124 edge tiles; setup: fragment tables.

typedef __attribute__((ext_vector_type(8))) short bf16x8;
typedef __attribute__((ext_vector_type(4))) float f32x4;

#define XS_S 28   // border kernel xs stride (shorts)

// ws layout (shorts):
//  A1   [2][5][64][8]  @ 0      border conv1 fragments
//  A2   [9][64][8]     @ 5120   border conv2 fragments (old bijection)
//  SB   [64][8]        @ 9728   border stencil-bank fragments
//  FLT  floats         @ short 10240 (float off 5120): per-lane 20 floats
//  WEFF [2][2][64][8]  @ 12800  composed 7x7 fragments
//  A2I  [9][64][8]     @ 14848  interior conv2 fragments (interleaved bijection)
#define WS_A2   5120
#define WS_SB   9728
#define WS_FLT  5120      // float offset
#define WS_WEFF 12800
#define WS_A2I  14848
#define WS_BYTES 38912

__device__ const float EB[9][5][5] = {
 {{0,0,0,0,0},{0,-1,0,1,0},{0,-2,0,2,0},{0,-1,0,1,0},{0,0,0,0,0}},        // sobel_x
 {{0,0,0,0,0},{0,-1,-2,-1,0},{0,0,0,0,0},{0,1,2,1,0},{0,0,0,0,0}},        // sobel_y
 {{0,0,0,0,0},{0,0,1,2,0},{0,-1,0,1,0},{0,-2,-1,0,0},{0,0,0,0,0}},        // diag1
 {{0,0,0,0,0},{0,-2,-1,0,0},{0,-1,0,1,0},{0,0,1,2,0},{0,0,0,0,0}},        // diag2
 {{0,0,0,0,0},{0,0,1,0,0},{0,1,-4,1,0},{0,0,1,0,0},{0,0,0,0,0}},          // laplacian
 {{-1,-2,0,2,1},{-2,-3,0,3,2},{-3,-4,0,4,3},{-2,-3,0,3,2},{-1,-2,0,2,1}}, // gradient5x5
 {{0,0,0,0,0},{0,-3,0,3,0},{0,-10,0,10,0},{0,-3,0,3,0},{0,0,0,0,0}},      // scharr_x
 {{0,0,0,0,0},{0,-3,-10,-3,0},{0,0,0,0,0},{0,3,10,3,0},{0,0,0,0,0}},      // scharr_y
 {{0,0,0,0,0},{0,0,0,0,0},{0,0,1,0,0},{0,0,0,0,0},{0,0,0,0,0}},           // identity
};

__device__ __forceinline__ unsigned short f2bf(float f) {   // cold paths only
    union { float f; unsigned u; } v; v.f = f;
    unsigned u = v.u + 0x7fffu + ((v.u >> 16) & 1u);   // RNE
    return (unsigned short)(u >> 16);
}
// hot-path pack: compiler emits v_cvt_pk_bf16_f32 (single VALU op)
__device__ __forceinline__ unsigned pk2(float lo, float hi) {
    __hip_bfloat162 h = __float22bfloat162_rn(make_float2(lo, hi));
    return *reinterpret_cast<unsigned*>(&h);
}

__device__ __forceinline__ float weff_tap(const float* __restrict__ w1,
                                          int oc, int dy, int dx) {
    float s = 0.f;
    for (int ch = 0; ch < 9; ++ch)
        for (int ty = 0; ty < 3; ++ty)
            for (int tx = 0; tx < 3; ++tx) {
                int sy = dy - ty, sx = dx - tx;
                if (sy >= 0 && sy < 5 && sx >= 0 && sx < 5)
                    s += w1[(oc * 9 + ch) * 9 + ty * 3 + tx] * EB[ch][sy][sx];
            }
    return s;
}

// ---- fast setup: 256 threads, LDS-staged weights, flat work split ----
__global__ __launch_bounds__(256) void setup_frags(
    const float* __restrict__ w1, const float* __restrict__ b1,
    const float* __restrict__ w2, const float* __restrict__ b2,
    const float* __restrict__ wr, const float* __restrict__ br,
    short* __restrict__ ws)
{
    __shared__ float w1s[2592];
    __shared__ float w2s[4608];
    __shared__ float ebs[225];
    const int tid = threadIdx.x;

    for (int i = tid; i < 2592; i += 256) w1s[i] = w1[i];
    for (int i = tid; i < 4608; i += 256) w2s[i] = w2[i];
    if (tid < 225) ebs[tid] = ((const float*)EB)[tid];
    __syncthreads();

    for (int idx = tid; idx < 5120; idx += 256) {           // A1 (border)
        int i = idx & 7, lane = (idx >> 3) & 63, rest = idx >> 9;
        int mt = rest / 5, ks = rest - 5 * mt;
        int n = lane & 15, lg = lane >> 4;
        int k = 32 * ks + 8 * lg + i;
        int g = k >> 4, ch = k & 15;
        float w = (g < 9 && ch < 9) ? w1s[(mt * 16 + n) * 81 + ch * 9 + g] : 0.f;
        ws[idx] = (short)f2bf(w);
    }
    for (int idx = tid; idx < 4608; idx += 256) {           // A2 (border, old)
        int i = idx & 7, lane = (idx >> 3) & 63, ks = idx >> 9;
        int n = lane & 15, lg = lane >> 4;
        int ic = 8 * lg + i;
        ws[WS_A2 + idx] = (short)f2bf(w2s[n * 288 + ic * 9 + ks]);
    }
    for (int idx = tid; idx < 4608; idx += 256) {           // A2I (interior)
        int i = idx & 7, lane = (idx >> 3) & 63, ks = idx >> 9;
        int n = lane & 15, lg = lane >> 4;
        int ic = ((i & 1) << 4) | (lg << 2) | ((i >> 1) & 3);
        ws[WS_A2I + idx] = (short)f2bf(w2s[n * 288 + ic * 9 + ks]);
    }
    for (int idx = tid; idx < 512; idx += 256) {            // SB (border)
        int i = idx & 7, lane = idx >> 3;
        int n = lane & 15, lg = lane >> 4;
        int k = 8 * lg + i;
        float v = (k < 25 && n < 9) ? ebs[n * 25 + k] : 0.f;
        ws[WS_SB + idx] = (short)f2bf(v);
    }
    for (int idx = tid; idx < 2048; idx += 256) {           // WEFF
        int i = idx & 7, lane = (idx >> 3) & 63, rest = idx >> 9;
        int mt = rest >> 1, ks = rest & 1;
        int n = lane & 15, lg = lane >> 4;
        int dy = 4 * ks + lg, dx = i;
        float s = 0.f;
        if (dy < 7 && dx < 7) {
            int oc = mt * 16 + n;
            for (int ch = 0; ch < 9; ++ch)
                for (int ty = 0; ty < 3; ++ty) {
                    int sy = dy - ty;
                    if (sy < 0 || sy >= 5) continue;
                    for (int tx = 0; tx < 3; ++tx) {
                        int sx = dx - tx;
                        if (sx >= 0 && sx < 5)
                            s += w1s[(oc * 9 + ch) * 9 + ty * 3 + tx] * ebs[ch * 25 + sy * 5 + sx];
                    }
                }
        }
        ws[WS_WEFF + idx] = (short)f2bf(s);
    }
    if (tid < 64) {                                         // FLT
        int lg = tid >> 4;
        float* wf = (float*)ws + WS_FLT + tid * 20;
        for (int r = 0; r < 4; ++r) {
            wf[r]      = b1[lg * 4 + r];
            wf[4 + r]  = b1[16 + lg * 4 + r];
            wf[8 + r]  = b2[lg * 4 + r];
            wf[12 + r] = wr[lg * 4 + r];
            wf[16 + r] = br[lg * 4 + r];
        }
    }
}

// ---------------- interior kernel: 16x32 tiles, composed 7x7, global-gather ----
template<bool USE_WS>
__global__ __launch_bounds__(256, 4) void edge_interior4(
    const float* __restrict__ x,  const float* __restrict__ w1, const float* __restrict__ b1,
    const float* __restrict__ w2, const float* __restrict__ b2,
    const float* __restrict__ wr, const float* __restrict__ br,
    const short* __restrict__ ws, float* __restrict__ out)
{
    // pool: hs [612 px][32 k] shorts (39168B)  UNION  stage [16oc][16row][36] f32 (36864B)
    __shared__ long long pool[39168 / 8];
    short* hsS   = (short*)pool;
    float* stage = (float*)pool;

    const int tid  = threadIdx.x;
    const int lane = tid & 63;
    const int wave = tid >> 6;
    const int n    = lane & 15;
    const int lg   = lane >> 4;
    const int bx = blockIdx.x * 32;
    const int by = (blockIdx.y + 1) * 16;   // y-edge tiles owned by border kernel
    const int b  = blockIdx.z;
    const float* xb = x + ((size_t)b << 18);

    // ---- P1: fragments -> registers ----
    bf16x8 wa[2][2], a2[9];
    float b1v[2][4], b2v[4], wrv[4], brv[4];
    if (USE_WS) {
#pragma unroll
        for (int mt = 0; mt < 2; ++mt)
#pragma unroll
            for (int ks = 0; ks < 2; ++ks)
                wa[mt][ks] = *reinterpret_cast<const bf16x8*>(
                    &ws[WS_WEFF + ((mt * 2 + ks) * 64 + lane) * 8]);
#pragma unroll
        for (int ks = 0; ks < 9; ++ks)
            a2[ks] = *reinterpret_cast<const bf16x8*>(&ws[WS_A2I + (ks * 64 + lane) * 8]);
        const float* wf = (const float*)ws + WS_FLT + lane * 20;
        f32x4 t0 = *reinterpret_cast<const f32x4*>(wf);
        f32x4 t1 = *reinterpret_cast<const f32x4*>(wf + 4);
        f32x4 t2 = *reinterpret_cast<const f32x4*>(wf + 8);
        f32x4 t3 = *reinterpret_cast<const f32x4*>(wf + 12);
        f32x4 t4 = *reinterpret_cast<const f32x4*>(wf + 16);
#pragma unroll
        for (int r = 0; r < 4; ++r) {
            b1v[0][r] = t0[r]; b1v[1][r] = t1[r];
            b2v[r] = t2[r]; wrv[r] = t3[r]; brv[r] = t4[r];
        }
    } else {
#pragma unroll
        for (int mt = 0; mt < 2; ++mt)
#pragma unroll
            for (int ks = 0; ks < 2; ++ks)
#pragma unroll
                for (int i = 0; i < 8; ++i) {
                    int dy = 4 * ks + lg, dx = i;
                    float s = (dy < 7 && dx < 7) ? weff_tap(w1, mt * 16 + n, dy, dx) : 0.f;
                    wa[mt][ks][i] = (short)f2bf(s);
                }
#pragma unroll
        for (int ks = 0; ks < 9; ++ks)
#pragma unroll
            for (int i = 0; i < 8; ++i) {
                int ic = ((i & 1) << 4) | (lg << 2) | ((i >> 1) & 3);
                a2[ks][i] = (short)f2bf(w2[(n * 32 + ic) * 9 + ks]);
            }
#pragma unroll
        for (int r = 0; r < 4; ++r) {
            b1v[0][r] = b1[lg * 4 + r]; b1v[1][r] = b1[16 + lg * 4 + r];
            b2v[r] = b2[lg * 4 + r]; wrv[r] = wr[lg * 4 + r]; brv[r] = br[lg * 4 + r];
        }
    }

    // ---- P3: conv1 = composed 7x7, B-windows from GLOBAL x -> hs ----
    // h region: rows 18 (by-1..by+16) x cols 34 (bx-1..bx+32), px = r1*34+c1
    for (int t = wave; t < 39; t += 4) {
        int p  = t * 16 + n;
        int pc = p < 611 ? p : 611;
        int r1 = pc / 34, c1 = pc - 34 * r1;
        int gxb = bx - 4 + c1; gxb = gxb < 0 ? 0 : (gxb > 504 ? 504 : gxb);
        const int gyb = by - 4 + r1;          // 12..493+6: always in-bounds
        f32x4 acc0 = {0.f,0.f,0.f,0.f}, acc1 = {0.f,0.f,0.f,0.f};
#pragma unroll
        for (int ks = 0; ks < 2; ++ks) {
            const int dy = 4 * ks + lg;
            bf16x8 bv = {0,0,0,0,0,0,0,0};
            if (dy < 7) {
                const float* xp = xb + ((size_t)(gyb + dy) << 9) + gxb;
                uint4 u;
                u.x = pk2(xp[0], xp[1]); u.y = pk2(xp[2], xp[3]);
                u.z = pk2(xp[4], xp[5]); u.w = pk2(xp[6], xp[7]);
                bv = *reinterpret_cast<bf16x8*>(&u);
            }
            acc0 = __builtin_amdgcn_mfma_f32_16x16x32_bf16(wa[0][ks], bv, acc0, 0, 0, 0);
            acc1 = __builtin_amdgcn_mfma_f32_16x16x32_bf16(wa[1][ks], bv, acc1, 0, 0, 0);
        }
        if (p < 612) {
            float h0 = fmaxf(acc0[0] + b1v[0][0], 0.f), g0 = fmaxf(acc1[0] + b1v[1][0], 0.f);
            float h1 = fmaxf(acc0[1] + b1v[0][1], 0.f), g1 = fmaxf(acc1[1] + b1v[1][1], 0.f);
            float h2 = fmaxf(acc0[2] + b1v[0][2], 0.f), g2 = fmaxf(acc1[2] + b1v[1][2], 0.f);
            float h3 = fmaxf(acc0[3] + b1v[0][3], 0.f), g3 = fmaxf(acc1[3] + b1v[1][3], 0.f);
            uint4 W;
            W.x = pk2(h0, g0); W.y = pk2(h1, g1); W.z = pk2(h2, g2); W.w = pk2(h3, g3);
            const int grp = lg ^ (p & 3) ^ ((p >> 2) & 3);
            *reinterpret_cast<uint4*>(&hsS[p * 32 + grp * 8]) = W;
        }
    }
    __syncthreads();

    // ---- P4: conv2, quad-row blocking ----
    const int q0 = wave >> 1;
    const int hh = wave & 1;
    f32x4 oreg[8];
#pragma unroll
    for (int j = 0; j < 2; ++j) {
        const int q = q0 + 2 * j;            // quad index 0..3 -> out rows 4q..4q+3
        f32x4 acc[4] = {{0.f,0.f,0.f,0.f},{0.f,0.f,0.f,0.f},
                        {0.f,0.f,0.f,0.f},{0.f,0.f,0.f,0.f}};
#pragma unroll
        for (int rr = 0; rr < 6; ++rr) {     // h rows 4q..4q+5
            const int pxb = (4 * q + rr) * 34 + 16 * hh + n;
#pragma unroll
            for (int dx = 0; dx < 3; ++dx) {
                const int px = pxb + dx;
                const int grp = lg ^ (px & 3) ^ ((px >> 2) & 3);
                bf16x8 hf = *reinterpret_cast<const bf16x8*>(&hsS[px * 32 + grp * 8]);
#pragma unroll
                for (int o = 0; o < 4; ++o) {
                    const int dy = rr - o;
                    if (dy >= 0 && dy < 3)
                        acc[o] = __builtin_amdgcn_mfma_f32_16x16x32_bf16(
                            a2[dy * 3 + dx], hf, acc[o], 0, 0, 0);
                }
            }
        }
#pragma unroll
        for (int o = 0; o < 4; ++o) {
            const int oy = 4 * q + o;
            float xv = xb[((size_t)(by + oy) << 9) + bx + 16 * hh + n];
            f32x4 ov;
#pragma unroll
            for (int r = 0; r < 4; ++r)
                ov[r] = fmaxf(acc[o][r] + b2v[r], 0.f) + wrv[r] * xv + brv[r];
            oreg[4 * j + o] = ov;
        }
    }
    __syncthreads();   // hs reads done; pool becomes stage

    // ---- stage outputs: [oc][row][36] f32 ----
#pragma unroll
    for (int j = 0; j < 2; ++j) {
        const int q = q0 + 2 * j;
#pragma unroll
        for (int o = 0; o < 4; ++o)
#pragma unroll
            for (int r = 0; r < 4; ++r)
                stage[(lg * 4 + r) * 576 + (4 * q + o) * 36 + 16 * hh + n] = oreg[4 * j + o][r];
    }
    __syncthreads();

    // ---- copy: f32x4 NT stores, 8 lanes = one full 128B line ----
#pragma unroll
    for (int k = 0; k < 8; ++k) {
        int idx = k * 256 + tid;               // 2048 float4s
        int c   = idx & 7;
        int row = (idx >> 3) & 15;
        int oc  = idx >> 7;
        f32x4 v = *reinterpret_cast<const f32x4*>(&stage[oc * 576 + row * 36 + 4 * c]);
        __builtin_nontemporal_store(v, reinterpret_cast<f32x4*>(
            &out[(((size_t)b * 16 + oc) * 512 + (by + row)) * 512 + bx + 4 * c]));
    }
}

// ---------------- border kernel (R5 path, 124 border tiles; plain stores) ----
template<bool USE_WS>
__global__ __launch_bounds__(256, 4) void edge_border(
    const float* __restrict__ x,  const float* __restrict__ w1, const float* __restrict__ b1,
    const float* __restrict__ w2, const float* __restrict__ b2,
    const float* __restrict__ wr, const float* __restrict__ br,
    const short* __restrict__ ws, float* __restrict__ out)
{
    __shared__ short fs2[2 * 400 * 8];
    __shared__ short hs4[4 * 324 * 8];
    __shared__ short xs[24 * XS_S];

    const int tid  = threadIdx.x;
    const int lane = tid & 63;
    const int wave = tid >> 6;
    const int n    = lane & 15;
    const int lg   = lane >> 4;

    int idx = blockIdx.x, tx, ty;
    if      (idx < 32) { tx = idx;      ty = 0;  }
    else if (idx < 64) { tx = idx - 32; ty = 31; }
    else if (idx < 94) { tx = 0;        ty = idx - 63; }
    else               { tx = 31;       ty = idx - 93; }
    const int bx = tx * 16, by = ty * 16, b = blockIdx.z;

    for (int i = tid; i < 576; i += 256) {
        int r = i / 24, c = i % 24;
        int gy = by - 4 + r, gx = bx - 4 + c;
        float v = 0.f;
        if (gy >= 0 && gy < 512 && gx >= 0 && gx < 512) v = x[((size_t)b * 512 + gy) * 512 + gx];
        __hip_bfloat16 h = __float2bfloat16(v);
        xs[r * XS_S + c] = *reinterpret_cast<short*>(&h);
    }

    bf16x8 a1[2][5], a2[9], sb;
    float b1v[2][4], b2v[4], wrv[4], brv[4];
    if (USE_WS) {
#pragma unroll
        for (int mt = 0; mt < 2; ++mt)
#pragma unroll
            for (int ks = 0; ks < 5; ++ks)
                a1[mt][ks] = *reinterpret_cast<const bf16x8*>(&ws[((mt * 5 + ks) * 64 + lane) * 8]);
#pragma unroll
        for (int ks = 0; ks < 9; ++ks)
            a2[ks] = *reinterpret_cast<const bf16x8*>(&ws[WS_A2 + (ks * 64 + lane) * 8]);
        sb = *reinterpret_cast<const bf16x8*>(&ws[WS_SB + lane * 8]);
        const float* wf = (const float*)ws + WS_FLT + lane * 20;
        f32x4 t0 = *reinterpret_cast<const f32x4*>(wf);
        f32x4 t1 = *reinterpret_cast<const f32x4*>(wf + 4);
        f32x4 t2 = *reinterpret_cast<const f32x4*>(wf + 8);
        f32x4 t3 = *reinterpret_cast<const f32x4*>(wf + 12);
        f32x4 t4 = *reinterpret_cast<const f32x4*>(wf + 16);
#pragma unroll
        for (int r = 0; r < 4; ++r) {
            b1v[0][r] = t0[r]; b1v[1][r] = t1[r];
            b2v[r] = t2[r]; wrv[r] = t3[r]; brv[r] = t4[r];
        }
    } else {
#pragma unroll
        for (int mt = 0; mt < 2; ++mt)
#pragma unroll
            for (int ks = 0; ks < 5; ++ks)
#pragma unroll
                for (int i = 0; i < 8; ++i) {
                    int k = 32 * ks + 8 * lg + i;
                    int g = k >> 4, ch = k & 15;
                    float w = (g < 9 && ch < 9) ? w1[(mt * 16 + n) * 81 + ch * 9 + g] : 0.f;
                    a1[mt][ks][i] = (short)f2bf(w);
                }
#pragma unroll
        for (int ks = 0; ks < 9; ++ks)
#pragma unroll
            for (int i = 0; i < 8; ++i)
                a2[ks][i] = (short)f2bf(w2[n * 288 + (8 * lg + i) * 9 + ks]);
#pragma unroll
        for (int i = 0; i < 8; ++i) {
            int k = 8 * lg + i;
            float v = (k < 25 && n < 9) ? EB[n][k / 5][k % 5] : 0.f;
            sb[i] = (short)f2bf(v);
        }
#pragma unroll
        for (int r = 0; r < 4; ++r) {
            b1v[0][r] = b1[lg * 4 + r]; b1v[1][r] = b1[16 + lg * 4 + r];
            b2v[r] = b2[lg * 4 + r]; wrv[r] = wr[lg * 4 + r]; brv[r] = br[lg * 4 + r];
        }
    }

    int toff[8];
#pragma unroll
    for (int i = 0; i < 8; ++i) {
        int k = 8 * lg + i;
        int t = k < 25 ? k : 24;
        toff[i] = (t / 5) * XS_S + (t % 5);
    }
    int boff[5];
#pragma unroll
    for (int ks = 0; ks < 5; ++ks) {
        int g = 2 * ks + (lg >> 1); if (g > 8) g = 8;
        int dy = g / 3, dx = g - 3 * dy;
        boff[ks] = (lg & 1) * 3200 + (dy * 20 + dx) * 8;
    }

    __syncthreads();

    for (int t = wave; t < 25; t += 4) {
        int px = t * 16 + n;
        int r = px / 20, c = px - 20 * r;
        const short* base = &xs[r * XS_S + c];
        bf16x8 bv;
#pragma unroll
        for (int i = 0; i < 8; ++i) bv[i] = base[toff[i]];
        f32x4 f = {0.f, 0.f, 0.f, 0.f};
        f = __builtin_amdgcn_mfma_f32_16x16x32_bf16(sb, bv, f, 0, 0, 0);
        int fy = by + r - 2, fx = bx + c - 2;
        float m = (fy >= 0 && fy < 512 && fx >= 0 && fx < 512) ? 1.f : 0.f;
        uint2 wv;
        wv.x = pk2(f[0] * m, f[1] * m);
        wv.y = pk2(f[2] * m, f[3] * m);
        *reinterpret_cast<uint2*>(&fs2[((lg >> 1) * 400 + px) * 8 + 4 * (lg & 1)]) = wv;
    }
    __syncthreads();

    for (int t = wave; t < 21; t += 4) {
        int p  = t * 16 + n;
        int pc = p < 323 ? p : 323;
        int r1 = pc / 18, c1 = pc - 18 * r1;
        int base = (r1 * 20 + c1) * 8;
        f32x4 acc0 = {0.f,0.f,0.f,0.f}, acc1 = {0.f,0.f,0.f,0.f};
#pragma unroll
        for (int ks = 0; ks < 5; ++ks) {
            bf16x8 bf = *reinterpret_cast<const bf16x8*>(&fs2[base + boff[ks]]);
            acc0 = __builtin_amdgcn_mfma_f32_16x16x32_bf16(a1[0][ks], bf, acc0, 0, 0, 0);
            acc1 = __builtin_amdgcn_mfma_f32_16x16x32_bf16(a1[1][ks], bf, acc1, 0, 0, 0);
        }
        if (p < 324) {
            int hy = by - 1 + r1, hx = bx - 1 + c1;
            float m = (hy >= 0 && hy < 512 && hx >= 0 && hx < 512) ? 1.f : 0.f;
            uint2 W0;
            W0.x = pk2(fmaxf(acc0[0] + b1v[0][0], 0.f) * m, fmaxf(acc0[1] + b1v[0][1], 0.f) * m);
            W0.y = pk2(fmaxf(acc0[2] + b1v[0][2], 0.f) * m, fmaxf(acc0[3] + b1v[0][3], 0.f) * m);
            *reinterpret_cast<uint2*>(&hs4[((lg >> 1) * 324 + p) * 8 + 4 * (lg & 1)]) = W0;
            uint2 W1;
            W1.x = pk2(fmaxf(acc1[0] + b1v[1][0], 0.f) * m, fmaxf(acc1[1] + b1v[1][1], 0.f) * m);
            W1.y = pk2(fmaxf(acc1[2] + b1v[1][2], 0.f) * m, fmaxf(acc1[3] + b1v[1][3], 0.f) * m);
            *reinterpret_cast<uint2*>(&hs4[((2 + (lg >> 1)) * 324 + p) * 8 + 4 * (lg & 1)]) = W1;
        }
    }
    __syncthreads();

    const int hbase = lg * 324 * 8;
#pragma unroll
    for (int j = 0; j < 4; ++j) {
        int oy = wave + 4 * j;
        f32x4 acc = {0.f,0.f,0.f,0.f};
#pragma unroll
        for (int ks = 0; ks < 9; ++ks) {
            const int dy = ks / 3, dx = ks - 3 * (ks / 3);
            bf16x8 hf = *reinterpret_cast<const bf16x8*>(
                &hs4[hbase + ((oy + dy) * 18 + n + dx) * 8]);
            acc = __builtin_amdgcn_mfma_f32_16x16x32_bf16(a2[ks], hf, acc, 0, 0, 0);
        }
        __hip_bfloat16 xh = *reinterpret_cast<const __hip_bfloat16*>(&xs[(oy + 4) * XS_S + n + 4]);
        float xv = __bfloat162float(xh);
        float* op = out + (((size_t)(b * 16 + lg * 4) * 512 + (by + oy)) * 512) + bx + n;
#pragma unroll
        for (int r = 0; r < 4; ++r) {
            float o = fmaxf(acc[r] + b2v[r], 0.f) + wrv[r] * xv + brv[r];
            *op = o;                     // plain store: L2 absorbs 64B segments
            op += 262144;
        }
    }
}

extern "C" void kernel_launch(void* const* d_in, const int* in_sizes, int n_in,
                              void* d_out, int out_size, void* d_ws, size_t ws_size,
                              hipStream_t stream) {
    const float* x  = (const float*)d_in[0];
    const float* w1 = (const float*)d_in[1];
    const float* b1 = (const float*)d_in[2];
    const float* w2 = (const float*)d_in[3];
    const float* b2 = (const float*)d_in[4];
    const float* wr = (const float*)d_in[5];
    const float* br = (const float*)d_in[6];
    float* out = (float*)d_out;
    short* ws = (short*)d_ws;

    dim3 block(256);
    dim3 gin(16, 30, 8);    // 16x32 tiles, y-edge rows excluded (border owns them)
    dim3 gbd(124, 1, 8);    // border tiles
    if (ws_size >= WS_BYTES) {
        hipLaunchKernelGGL(setup_frags, dim3(1), dim3(256), 0, stream,
                           w1, b1, w2, b2, wr, br, ws);
        hipLaunchKernelGGL(edge_interior4<true>, gin, block, 0, stream,
                           x, w1, b1, w2, b2, wr, br, ws, out);
        hipLaunchKernelGGL(edge_border<true>, gbd, block, 0, stream,
                           x, w1, b1, w2, b2, wr, br, ws, out);
    } else {
        hipLaunchKernelGGL(edge_interior4<false>, gin, block, 0, stream,
                           x, w1, b1, w2, b2, wr, br, ws, out);
        hipLaunchKernelGGL(edge_border<false>, gbd, block, 0, stream,
                           x, w1, b1, w2, b2, wr, br, ws, out);
    }
}

// Round 13
// 93.324 us; speedup vs baseline: 2.5863x; 1.1414x over previous
//
#include <hip/hip_runtime.h>
#include <hip/hip_bf16.h>

// EnhancedEdgeLayer R13 (= R12 + race fix):
//  (1) x pre-converted to bf16 in d_ws (dual copies xA[i]=bf(x[i]), xB[i]=bf(x[i+1]))
//      -> P3 window loads are 4B-aligned 16B vector loads, ZERO per-use cvt.
//  (2) border merged into main dispatch; interior blocks SKIP stores to
//      border-owned x-edge strips (cols 0..15 / 496..511) -> disjoint writes,
//      no ordering dependence (R12 raced here).
//  (3) dy==7 branch removed (loads always in-bounds; WEFF zero rows nullify).
// Fallbacks: ws too small for x_bf -> R11 two-kernel path; no ws -> inline path.

typedef __attribute__((ext_vector_type(8))) short bf16x8;
typedef __attribute__((ext_vector_type(4))) float f32x4;
typedef unsigned int uint4a __attribute__((ext_vector_type(4), aligned(4)));

#define XS_S 28   // border xs stride (shorts)

// ws layout (shorts unless noted):
//  A1 [2][5][64][8] @0 ; A2 [9][64][8] @5120 ; SB [64][8] @9728
//  FLT floats @ float-off 5120 ; WEFF [2][2][64][8] @12800 ; A2I [9][64][8] @14848
//  xA bf16 @ short 20480 (byte 40960), 2,097,152 shorts ; xB follows (+2,097,152)
#define WS_A2   5120
#define WS_SB   9728
#define WS_FLT  5120      // float offset
#define WS_WEFF 12800
#define WS_A2I  14848
#define WS_XA   20480     // short offset
#define XB_OFF  2097152   // shorts, xB relative to xA
#define WS_BYTES 38912
#define WS_FULL  8429568u // 40960 + 2*4194304

__device__ const float EB[9][5][5] = {
 {{0,0,0,0,0},{0,-1,0,1,0},{0,-2,0,2,0},{0,-1,0,1,0},{0,0,0,0,0}},
 {{0,0,0,0,0},{0,-1,-2,-1,0},{0,0,0,0,0},{0,1,2,1,0},{0,0,0,0,0}},
 {{0,0,0,0,0},{0,0,1,2,0},{0,-1,0,1,0},{0,-2,-1,0,0},{0,0,0,0,0}},
 {{0,0,0,0,0},{0,-2,-1,0,0},{0,-1,0,1,0},{0,0,1,2,0},{0,0,0,0,0}},
 {{0,0,0,0,0},{0,0,1,0,0},{0,1,-4,1,0},{0,0,1,0,0},{0,0,0,0,0}},
 {{-1,-2,0,2,1},{-2,-3,0,3,2},{-3,-4,0,4,3},{-2,-3,0,3,2},{-1,-2,0,2,1}},
 {{0,0,0,0,0},{0,-3,0,3,0},{0,-10,0,10,0},{0,-3,0,3,0},{0,0,0,0,0}},
 {{0,0,0,0,0},{0,-3,-10,-3,0},{0,0,0,0,0},{0,3,10,3,0},{0,0,0,0,0}},
 {{0,0,0,0,0},{0,0,0,0,0},{0,0,1,0,0},{0,0,0,0,0},{0,0,0,0,0}},
};

__device__ __forceinline__ unsigned short f2bf(float f) {   // cold paths only
    union { float f; unsigned u; } v; v.f = f;
    unsigned u = v.u + 0x7fffu + ((v.u >> 16) & 1u);
    return (unsigned short)(u >> 16);
}
__device__ __forceinline__ unsigned pk2(float lo, float hi) {
    __hip_bfloat162 h = __float22bfloat162_rn(make_float2(lo, hi));
    return *reinterpret_cast<unsigned*>(&h);
}

__device__ __forceinline__ float weff_tap(const float* __restrict__ w1,
                                          int oc, int dy, int dx) {
    float s = 0.f;
    for (int ch = 0; ch < 9; ++ch)
        for (int ty = 0; ty < 3; ++ty)
            for (int tx = 0; tx < 3; ++tx) {
                int sy = dy - ty, sx = dx - tx;
                if (sy >= 0 && sy < 5 && sx >= 0 && sx < 5)
                    s += w1[(oc * 9 + ch) * 9 + ty * 3 + tx] * EB[ch][sy][sx];
            }
    return s;
}

// ---- setup_all: block 0 = fragment tables; blocks 1..1024 = x->bf16 prepass ----
__global__ __launch_bounds__(256) void setup_all(
    const float* __restrict__ x,
    const float* __restrict__ w1, const float* __restrict__ b1,
    const float* __restrict__ w2, const float* __restrict__ b2,
    const float* __restrict__ wr, const float* __restrict__ br,
    short* __restrict__ ws, int do_cvt)
{
    const int tid = threadIdx.x;
    if (blockIdx.x != 0) {
        const int j0 = ((blockIdx.x - 1) * 256 + tid) * 8;   // < 2,097,152
        float4 va = *reinterpret_cast<const float4*>(&x[j0]);
        float4 vb = *reinterpret_cast<const float4*>(&x[j0 + 4]);
        float xn = (j0 + 8 < 2097152) ? x[j0 + 8] : 0.f;
        uint4 A; A.x = pk2(va.x, va.y); A.y = pk2(va.z, va.w);
        A.z = pk2(vb.x, vb.y); A.w = pk2(vb.z, vb.w);
        uint4 B; B.x = pk2(va.y, va.z); B.y = pk2(va.w, vb.x);
        B.z = pk2(vb.y, vb.z); B.w = pk2(vb.w, xn);
        *reinterpret_cast<uint4*>(&ws[WS_XA + j0]) = A;
        *reinterpret_cast<uint4*>(&ws[WS_XA + XB_OFF + j0]) = B;
        return;
    }

    __shared__ float w1s[2592];
    __shared__ float w2s[4608];
    __shared__ float ebs[225];
    for (int i = tid; i < 2592; i += 256) w1s[i] = w1[i];
    for (int i = tid; i < 4608; i += 256) w2s[i] = w2[i];
    if (tid < 225) ebs[tid] = ((const float*)EB)[tid];
    __syncthreads();

    for (int idx = tid; idx < 5120; idx += 256) {           // A1
        int i = idx & 7, lane = (idx >> 3) & 63, rest = idx >> 9;
        int mt = rest / 5, ks = rest - 5 * mt;
        int n = lane & 15, lg = lane >> 4;
        int k = 32 * ks + 8 * lg + i;
        int g = k >> 4, ch = k & 15;
        float w = (g < 9 && ch < 9) ? w1s[(mt * 16 + n) * 81 + ch * 9 + g] : 0.f;
        ws[idx] = (short)f2bf(w);
    }
    for (int idx = tid; idx < 4608; idx += 256) {           // A2 (border)
        int i = idx & 7, lane = (idx >> 3) & 63, ks = idx >> 9;
        int n = lane & 15, lg = lane >> 4;
        ws[WS_A2 + idx] = (short)f2bf(w2s[n * 288 + (8 * lg + i) * 9 + ks]);
    }
    for (int idx = tid; idx < 4608; idx += 256) {           // A2I (interior)
        int i = idx & 7, lane = (idx >> 3) & 63, ks = idx >> 9;
        int n = lane & 15, lg = lane >> 4;
        int ic = ((i & 1) << 4) | (lg << 2) | ((i >> 1) & 3);
        ws[WS_A2I + idx] = (short)f2bf(w2s[n * 288 + ic * 9 + ks]);
    }
    for (int idx = tid; idx < 512; idx += 256) {            // SB
        int i = idx & 7, lane = idx >> 3;
        int n = lane & 15, lg = lane >> 4;
        int k = 8 * lg + i;
        float v = (k < 25 && n < 9) ? ebs[n * 25 + k] : 0.f;
        ws[WS_SB + idx] = (short)f2bf(v);
    }
    for (int idx = tid; idx < 2048; idx += 256) {           // WEFF
        int i = idx & 7, lane = (idx >> 3) & 63, rest = idx >> 9;
        int mt = rest >> 1, ks = rest & 1;
        int n = lane & 15, lg = lane >> 4;
        int dy = 4 * ks + lg, dx = i;
        float s = 0.f;
        if (dy < 7 && dx < 7) {
            int oc = mt * 16 + n;
            for (int ch = 0; ch < 9; ++ch)
                for (int ty = 0; ty < 3; ++ty) {
                    int sy = dy - ty;
                    if (sy < 0 || sy >= 5) continue;
                    for (int tx = 0; tx < 3; ++tx) {
                        int sx = dx - tx;
                        if (sx >= 0 && sx < 5)
                            s += w1s[(oc * 9 + ch) * 9 + ty * 3 + tx] * ebs[ch * 25 + sy * 5 + sx];
                    }
                }
        }
        ws[WS_WEFF + idx] = (short)f2bf(s);
    }
    if (tid < 64) {                                         // FLT
        int lg = tid >> 4;
        float* wf = (float*)ws + WS_FLT + tid * 20;
        for (int r = 0; r < 4; ++r) {
            wf[r]      = b1[lg * 4 + r];
            wf[4 + r]  = b1[16 + lg * 4 + r];
            wf[8 + r]  = b2[lg * 4 + r];
            wf[12 + r] = wr[lg * 4 + r];
            wf[16 + r] = br[lg * 4 + r];
        }
    }
    (void)do_cvt;
}

// ================= merged main kernel (MODE 2) =================
// blocks [0,992): border tiles (R5 path); blocks [992,4832): interior 16x32 tiles.
// Write sets are DISJOINT: interior skips cols 0..15 / 496..511 (border-owned).
__global__ __launch_bounds__(256, 4) void edge_main(
    const float* __restrict__ x, const short* __restrict__ ws,
    float* __restrict__ out)
{
    __shared__ long long pool[39168 / 8];
    const int tid  = threadIdx.x;
    const int lane = tid & 63;
    const int wave = tid >> 6;
    const int n    = lane & 15;
    const int lg   = lane >> 4;
    const int id   = blockIdx.x;

    if (id >= 992) {
        // ---------------- interior ----------------
        short* hsS   = (short*)pool;
        float* stage = (float*)pool;
        const int id2 = id - 992;
        const int bx = (id2 & 15) * 32;
        const int rem = id2 >> 4;
        const int by = (rem % 30 + 1) * 16;
        const int b  = rem / 30;
        const float* xb = x + ((size_t)b << 18);
        const short* xab = ws + WS_XA + b * 262144;

        // P1: fragments
        bf16x8 wa[2][2], a2[9];
        float b1v[2][4], b2v[4], wrv[4], brv[4];
#pragma unroll
        for (int mt = 0; mt < 2; ++mt)
#pragma unroll
            for (int ks = 0; ks < 2; ++ks)
                wa[mt][ks] = *reinterpret_cast<const bf16x8*>(
                    &ws[WS_WEFF + ((mt * 2 + ks) * 64 + lane) * 8]);
#pragma unroll
        for (int ks = 0; ks < 9; ++ks)
            a2[ks] = *reinterpret_cast<const bf16x8*>(&ws[WS_A2I + (ks * 64 + lane) * 8]);
        {
            const float* wf = (const float*)ws + WS_FLT + lane * 20;
            f32x4 t0 = *reinterpret_cast<const f32x4*>(wf);
            f32x4 t1 = *reinterpret_cast<const f32x4*>(wf + 4);
            f32x4 t2 = *reinterpret_cast<const f32x4*>(wf + 8);
            f32x4 t3 = *reinterpret_cast<const f32x4*>(wf + 12);
            f32x4 t4 = *reinterpret_cast<const f32x4*>(wf + 16);
#pragma unroll
            for (int r = 0; r < 4; ++r) {
                b1v[0][r] = t0[r]; b1v[1][r] = t1[r];
                b2v[r] = t2[r]; wrv[r] = t3[r]; brv[r] = t4[r];
            }
        }

        // P3: composed 7x7 from pre-converted bf16 x
        for (int t = wave; t < 39; t += 4) {
            int p  = t * 16 + n;
            int pc = p < 611 ? p : 611;
            int r1 = pc / 34, c1 = pc - 34 * r1;
            int gxb = bx - 4 + c1; gxb = gxb < 0 ? 0 : (gxb > 504 ? 504 : gxb);
            const int off = (by - 4 + r1) * 512 + gxb;
            const short* basep = (gxb & 1) ? (xab + XB_OFF + off - 1) : (xab + off);
            f32x4 acc0 = {0.f,0.f,0.f,0.f}, acc1 = {0.f,0.f,0.f,0.f};
#pragma unroll
            for (int ks = 0; ks < 2; ++ks) {
                const int dy = 4 * ks + lg;   // dy==7 rows: WEFF zero, load safe
                uint4a u = *reinterpret_cast<const uint4a*>(basep + dy * 512);
                bf16x8 bv = __builtin_bit_cast(bf16x8, u);
                acc0 = __builtin_amdgcn_mfma_f32_16x16x32_bf16(wa[0][ks], bv, acc0, 0, 0, 0);
                acc1 = __builtin_amdgcn_mfma_f32_16x16x32_bf16(wa[1][ks], bv, acc1, 0, 0, 0);
            }
            if (p < 612) {
                float h0 = fmaxf(acc0[0] + b1v[0][0], 0.f), g0 = fmaxf(acc1[0] + b1v[1][0], 0.f);
                float h1 = fmaxf(acc0[1] + b1v[0][1], 0.f), g1 = fmaxf(acc1[1] + b1v[1][1], 0.f);
                float h2 = fmaxf(acc0[2] + b1v[0][2], 0.f), g2 = fmaxf(acc1[2] + b1v[1][2], 0.f);
                float h3 = fmaxf(acc0[3] + b1v[0][3], 0.f), g3 = fmaxf(acc1[3] + b1v[1][3], 0.f);
                uint4 W;
                W.x = pk2(h0, g0); W.y = pk2(h1, g1); W.z = pk2(h2, g2); W.w = pk2(h3, g3);
                const int grp = lg ^ (p & 3) ^ ((p >> 2) & 3);
                *reinterpret_cast<uint4*>(&hsS[p * 32 + grp * 8]) = W;
            }
        }
        __syncthreads();

        // P4: conv2, quad-row blocking
        const int q0 = wave >> 1;
        const int hh = wave & 1;
        f32x4 oreg[8];
#pragma unroll
        for (int j = 0; j < 2; ++j) {
            const int q = q0 + 2 * j;
            f32x4 acc[4] = {{0.f,0.f,0.f,0.f},{0.f,0.f,0.f,0.f},
                            {0.f,0.f,0.f,0.f},{0.f,0.f,0.f,0.f}};
#pragma unroll
            for (int rr = 0; rr < 6; ++rr) {
                const int pxb = (4 * q + rr) * 34 + 16 * hh + n;
#pragma unroll
                for (int dx = 0; dx < 3; ++dx) {
                    const int px = pxb + dx;
                    const int grp = lg ^ (px & 3) ^ ((px >> 2) & 3);
                    bf16x8 hf = *reinterpret_cast<const bf16x8*>(&hsS[px * 32 + grp * 8]);
#pragma unroll
                    for (int o = 0; o < 4; ++o) {
                        const int dy = rr - o;
                        if (dy >= 0 && dy < 3)
                            acc[o] = __builtin_amdgcn_mfma_f32_16x16x32_bf16(
                                a2[dy * 3 + dx], hf, acc[o], 0, 0, 0);
                    }
                }
            }
#pragma unroll
            for (int o = 0; o < 4; ++o) {
                const int oy = 4 * q + o;
                float xv = xb[((size_t)(by + oy) << 9) + bx + 16 * hh + n];
                f32x4 ov;
#pragma unroll
                for (int r = 0; r < 4; ++r)
                    ov[r] = fmaxf(acc[o][r] + b2v[r], 0.f) + wrv[r] * xv + brv[r];
                oreg[4 * j + o] = ov;
            }
        }
        __syncthreads();

        // stage + full-line NT copy (skip border-owned edge strips)
#pragma unroll
        for (int j = 0; j < 2; ++j) {
            const int q = q0 + 2 * j;
#pragma unroll
            for (int o = 0; o < 4; ++o)
#pragma unroll
                for (int r = 0; r < 4; ++r)
                    stage[(lg * 4 + r) * 576 + (4 * q + o) * 36 + 16 * hh + n] = oreg[4 * j + o][r];
        }
        __syncthreads();
#pragma unroll
        for (int k = 0; k < 8; ++k) {
            int idx = k * 256 + tid;
            int c   = idx & 7;
            int row = (idx >> 3) & 15;
            int oc  = idx >> 7;
            // border kernel owns cols [0,16) and [496,512): do not write them
            if ((bx == 0 && c < 4) || (bx == 480 && c >= 4)) continue;
            f32x4 v = *reinterpret_cast<const f32x4*>(&stage[oc * 576 + row * 36 + 4 * c]);
            __builtin_nontemporal_store(v, reinterpret_cast<f32x4*>(
                &out[(((size_t)b * 16 + oc) * 512 + (by + row)) * 512 + bx + 4 * c]));
        }
        return;
    }

    // ---------------- border (R5 path) ----------------
    {
        short* fs2 = (short*)pool;            // 6400 shorts
        short* hs4 = (short*)pool + 6400;     // 10368 shorts
        short* xs  = (short*)pool + 16768;    // 672 shorts

        const int b = id / 124;
        int t4 = id - b * 124, tx, ty;
        if      (t4 < 32) { tx = t4;      ty = 0;  }
        else if (t4 < 64) { tx = t4 - 32; ty = 31; }
        else if (t4 < 94) { tx = 0;       ty = t4 - 63; }
        else              { tx = 31;      ty = t4 - 93; }
        const int bx = tx * 16, by = ty * 16;

        for (int i = tid; i < 576; i += 256) {
            int r = i / 24, c = i % 24;
            int gy = by - 4 + r, gx = bx - 4 + c;
            float v = 0.f;
            if (gy >= 0 && gy < 512 && gx >= 0 && gx < 512)
                v = x[((size_t)b * 512 + gy) * 512 + gx];
            __hip_bfloat16 h = __float2bfloat16(v);
            xs[r * XS_S + c] = *reinterpret_cast<short*>(&h);
        }

        bf16x8 a1[2][5], a2[9], sb;
        float b1v[2][4], b2v[4], wrv[4], brv[4];
#pragma unroll
        for (int mt = 0; mt < 2; ++mt)
#pragma unroll
            for (int ks = 0; ks < 5; ++ks)
                a1[mt][ks] = *reinterpret_cast<const bf16x8*>(&ws[((mt * 5 + ks) * 64 + lane) * 8]);
#pragma unroll
        for (int ks = 0; ks < 9; ++ks)
            a2[ks] = *reinterpret_cast<const bf16x8*>(&ws[WS_A2 + (ks * 64 + lane) * 8]);
        sb = *reinterpret_cast<const bf16x8*>(&ws[WS_SB + lane * 8]);
        {
            const float* wf = (const float*)ws + WS_FLT + lane * 20;
            f32x4 t0 = *reinterpret_cast<const f32x4*>(wf);
            f32x4 t1 = *reinterpret_cast<const f32x4*>(wf + 4);
            f32x4 t2 = *reinterpret_cast<const f32x4*>(wf + 8);
            f32x4 t3 = *reinterpret_cast<const f32x4*>(wf + 12);
            f32x4 t4 = *reinterpret_cast<const f32x4*>(wf + 16);
#pragma unroll
            for (int r = 0; r < 4; ++r) {
                b1v[0][r] = t0[r]; b1v[1][r] = t1[r];
                b2v[r] = t2[r]; wrv[r] = t3[r]; brv[r] = t4[r];
            }
        }

        int toff[8];
#pragma unroll
        for (int i = 0; i < 8; ++i) {
            int k = 8 * lg + i;
            int t = k < 25 ? k : 24;
            toff[i] = (t / 5) * XS_S + (t % 5);
        }
        int boff[5];
#pragma unroll
        for (int ks = 0; ks < 5; ++ks) {
            int g = 2 * ks + (lg >> 1); if (g > 8) g = 8;
            int dy = g / 3, dx = g - 3 * dy;
            boff[ks] = (lg & 1) * 3200 + (dy * 20 + dx) * 8;
        }

        __syncthreads();

        for (int t = wave; t < 25; t += 4) {
            int px = t * 16 + n;
            int r = px / 20, c = px - 20 * r;
            const short* base = &xs[r * XS_S + c];
            bf16x8 bv;
#pragma unroll
            for (int i = 0; i < 8; ++i) bv[i] = base[toff[i]];
            f32x4 f = {0.f, 0.f, 0.f, 0.f};
            f = __builtin_amdgcn_mfma_f32_16x16x32_bf16(sb, bv, f, 0, 0, 0);
            int fy = by + r - 2, fx = bx + c - 2;
            float m = (fy >= 0 && fy < 512 && fx >= 0 && fx < 512) ? 1.f : 0.f;
            uint2 wv;
            wv.x = pk2(f[0] * m, f[1] * m);
            wv.y = pk2(f[2] * m, f[3] * m);
            *reinterpret_cast<uint2*>(&fs2[((lg >> 1) * 400 + px) * 8 + 4 * (lg & 1)]) = wv;
        }
        __syncthreads();

        for (int t = wave; t < 21; t += 4) {
            int p  = t * 16 + n;
            int pc = p < 323 ? p : 323;
            int r1 = pc / 18, c1 = pc - 18 * r1;
            int base = (r1 * 20 + c1) * 8;
            f32x4 acc0 = {0.f,0.f,0.f,0.f}, acc1 = {0.f,0.f,0.f,0.f};
#pragma unroll
            for (int ks = 0; ks < 5; ++ks) {
                bf16x8 bf = *reinterpret_cast<const bf16x8*>(&fs2[base + boff[ks]]);
                acc0 = __builtin_amdgcn_mfma_f32_16x16x32_bf16(a1[0][ks], bf, acc0, 0, 0, 0);
                acc1 = __builtin_amdgcn_mfma_f32_16x16x32_bf16(a1[1][ks], bf, acc1, 0, 0, 0);
            }
            if (p < 324) {
                int hy = by - 1 + r1, hx = bx - 1 + c1;
                float m = (hy >= 0 && hy < 512 && hx >= 0 && hx < 512) ? 1.f : 0.f;
                uint2 W0;
                W0.x = pk2(fmaxf(acc0[0] + b1v[0][0], 0.f) * m, fmaxf(acc0[1] + b1v[0][1], 0.f) * m);
                W0.y = pk2(fmaxf(acc0[2] + b1v[0][2], 0.f) * m, fmaxf(acc0[3] + b1v[0][3], 0.f) * m);
                *reinterpret_cast<uint2*>(&hs4[((lg >> 1) * 324 + p) * 8 + 4 * (lg & 1)]) = W0;
                uint2 W1;
                W1.x = pk2(fmaxf(acc1[0] + b1v[1][0], 0.f) * m, fmaxf(acc1[1] + b1v[1][1], 0.f) * m);
                W1.y = pk2(fmaxf(acc1[2] + b1v[1][2], 0.f) * m, fmaxf(acc1[3] + b1v[1][3], 0.f) * m);
                *reinterpret_cast<uint2*>(&hs4[((2 + (lg >> 1)) * 324 + p) * 8 + 4 * (lg & 1)]) = W1;
            }
        }
        __syncthreads();

        const int hbase = lg * 324 * 8;
#pragma unroll
        for (int j = 0; j < 4; ++j) {
            int oy = wave + 4 * j;
            f32x4 acc = {0.f,0.f,0.f,0.f};
#pragma unroll
            for (int ks = 0; ks < 9; ++ks) {
                const int dy = ks / 3, dx = ks - 3 * (ks / 3);
                bf16x8 hf = *reinterpret_cast<const bf16x8*>(
                    &hs4[hbase + ((oy + dy) * 18 + n + dx) * 8]);
                acc = __builtin_amdgcn_mfma_f32_16x16x32_bf16(a2[ks], hf, acc, 0, 0, 0);
            }
            __hip_bfloat16 xh = *reinterpret_cast<const __hip_bfloat16*>(&xs[(oy + 4) * XS_S + n + 4]);
            float xv = __bfloat162float(xh);
            float* op = out + (((size_t)(b * 16 + lg * 4) * 512 + (by + oy)) * 512) + bx + n;
#pragma unroll
            for (int r = 0; r < 4; ++r) {
                float o = fmaxf(acc[r] + b2v[r], 0.f) + wrv[r] * xv + brv[r];
                *op = o;
                op += 262144;
            }
        }
    }
}

// ================= fallback kernels (MODE 1 / 0) =================
template<bool USE_WS>
__global__ __launch_bounds__(256, 4) void edge_interior4(
    const float* __restrict__ x,  const float* __restrict__ w1, const float* __restrict__ b1,
    const float* __restrict__ w2, const float* __restrict__ b2,
    const float* __restrict__ wr, const float* __restrict__ br,
    const short* __restrict__ ws, float* __restrict__ out)
{
    __shared__ long long pool[39168 / 8];
    short* hsS   = (short*)pool;
    float* stage = (float*)pool;

    const int tid  = threadIdx.x;
    const int lane = tid & 63;
    const int wave = tid >> 6;
    const int n    = lane & 15;
    const int lg   = lane >> 4;
    const int bx = blockIdx.x * 32;
    const int by = (blockIdx.y + 1) * 16;
    const int b  = blockIdx.z;
    const float* xb = x + ((size_t)b << 18);

    bf16x8 wa[2][2], a2[9];
    float b1v[2][4], b2v[4], wrv[4], brv[4];
    if (USE_WS) {
#pragma unroll
        for (int mt = 0; mt < 2; ++mt)
#pragma unroll
            for (int ks = 0; ks < 2; ++ks)
                wa[mt][ks] = *reinterpret_cast<const bf16x8*>(
                    &ws[WS_WEFF + ((mt * 2 + ks) * 64 + lane) * 8]);
#pragma unroll
        for (int ks = 0; ks < 9; ++ks)
            a2[ks] = *reinterpret_cast<const bf16x8*>(&ws[WS_A2I + (ks * 64 + lane) * 8]);
        const float* wf = (const float*)ws + WS_FLT + lane * 20;
        f32x4 t0 = *reinterpret_cast<const f32x4*>(wf);
        f32x4 t1 = *reinterpret_cast<const f32x4*>(wf + 4);
        f32x4 t2 = *reinterpret_cast<const f32x4*>(wf + 8);
        f32x4 t3 = *reinterpret_cast<const f32x4*>(wf + 12);
        f32x4 t4 = *reinterpret_cast<const f32x4*>(wf + 16);
#pragma unroll
        for (int r = 0; r < 4; ++r) {
            b1v[0][r] = t0[r]; b1v[1][r] = t1[r];
            b2v[r] = t2[r]; wrv[r] = t3[r]; brv[r] = t4[r];
        }
    } else {
#pragma unroll
        for (int mt = 0; mt < 2; ++mt)
#pragma unroll
            for (int ks = 0; ks < 2; ++ks)
#pragma unroll
                for (int i = 0; i < 8; ++i) {
                    int dy = 4 * ks + lg, dx = i;
                    float s = (dy < 7 && dx < 7) ? weff_tap(w1, mt * 16 + n, dy, dx) : 0.f;
                    wa[mt][ks][i] = (short)f2bf(s);
                }
#pragma unroll
        for (int ks = 0; ks < 9; ++ks)
#pragma unroll
            for (int i = 0; i < 8; ++i) {
                int ic = ((i & 1) << 4) | (lg << 2) | ((i >> 1) & 3);
                a2[ks][i] = (short)f2bf(w2[(n * 32 + ic) * 9 + ks]);
            }
#pragma unroll
        for (int r = 0; r < 4; ++r) {
            b1v[0][r] = b1[lg * 4 + r]; b1v[1][r] = b1[16 + lg * 4 + r];
            b2v[r] = b2[lg * 4 + r]; wrv[r] = wr[lg * 4 + r]; brv[r] = br[lg * 4 + r];
        }
    }

    for (int t = wave; t < 39; t += 4) {
        int p  = t * 16 + n;
        int pc = p < 611 ? p : 611;
        int r1 = pc / 34, c1 = pc - 34 * r1;
        int gxb = bx - 4 + c1; gxb = gxb < 0 ? 0 : (gxb > 504 ? 504 : gxb);
        const int gyb = by - 4 + r1;
        f32x4 acc0 = {0.f,0.f,0.f,0.f}, acc1 = {0.f,0.f,0.f,0.f};
#pragma unroll
        for (int ks = 0; ks < 2; ++ks) {
            const int dy = 4 * ks + lg;
            bf16x8 bv = {0,0,0,0,0,0,0,0};
            if (dy < 7) {
                const float* xp = xb + ((size_t)(gyb + dy) << 9) + gxb;
                uint4 u;
                u.x = pk2(xp[0], xp[1]); u.y = pk2(xp[2], xp[3]);
                u.z = pk2(xp[4], xp[5]); u.w = pk2(xp[6], xp[7]);
                bv = *reinterpret_cast<bf16x8*>(&u);
            }
            acc0 = __builtin_amdgcn_mfma_f32_16x16x32_bf16(wa[0][ks], bv, acc0, 0, 0, 0);
            acc1 = __builtin_amdgcn_mfma_f32_16x16x32_bf16(wa[1][ks], bv, acc1, 0, 0, 0);
        }
        if (p < 612) {
            float h0 = fmaxf(acc0[0] + b1v[0][0], 0.f), g0 = fmaxf(acc1[0] + b1v[1][0], 0.f);
            float h1 = fmaxf(acc0[1] + b1v[0][1], 0.f), g1 = fmaxf(acc1[1] + b1v[1][1], 0.f);
            float h2 = fmaxf(acc0[2] + b1v[0][2], 0.f), g2 = fmaxf(acc1[2] + b1v[1][2], 0.f);
            float h3 = fmaxf(acc0[3] + b1v[0][3], 0.f), g3 = fmaxf(acc1[3] + b1v[1][3], 0.f);
            uint4 W;
            W.x = pk2(h0, g0); W.y = pk2(h1, g1); W.z = pk2(h2, g2); W.w = pk2(h3, g3);
            const int grp = lg ^ (p & 3) ^ ((p >> 2) & 3);
            *reinterpret_cast<uint4*>(&hsS[p * 32 + grp * 8]) = W;
        }
    }
    __syncthreads();

    const int q0 = wave >> 1;
    const int hh = wave & 1;
    f32x4 oreg[8];
#pragma unroll
    for (int j = 0; j < 2; ++j) {
        const int q = q0 + 2 * j;
        f32x4 acc[4] = {{0.f,0.f,0.f,0.f},{0.f,0.f,0.f,0.f},
                        {0.f,0.f,0.f,0.f},{0.f,0.f,0.f,0.f}};
#pragma unroll
        for (int rr = 0; rr < 6; ++rr) {
            const int pxb = (4 * q + rr) * 34 + 16 * hh + n;
#pragma unroll
            for (int dx = 0; dx < 3; ++dx) {
                const int px = pxb + dx;
                const int grp = lg ^ (px & 3) ^ ((px >> 2) & 3);
                bf16x8 hf = *reinterpret_cast<const bf16x8*>(&hsS[px * 32 + grp * 8]);
#pragma unroll
                for (int o = 0; o < 4; ++o) {
                    const int dy = rr - o;
                    if (dy >= 0 && dy < 3)
                        acc[o] = __builtin_amdgcn_mfma_f32_16x16x32_bf16(
                            a2[dy * 3 + dx], hf, acc[o], 0, 0, 0);
                }
            }
        }
#pragma unroll
        for (int o = 0; o < 4; ++o) {
            const int oy = 4 * q + o;
            float xv = xb[((size_t)(by + oy) << 9) + bx + 16 * hh + n];
            f32x4 ov;
#pragma unroll
            for (int r = 0; r < 4; ++r)
                ov[r] = fmaxf(acc[o][r] + b2v[r], 0.f) + wrv[r] * xv + brv[r];
            oreg[4 * j + o] = ov;
        }
    }
    __syncthreads();

#pragma unroll
    for (int j = 0; j < 2; ++j) {
        const int q = q0 + 2 * j;
#pragma unroll
        for (int o = 0; o < 4; ++o)
#pragma unroll
            for (int r = 0; r < 4; ++r)
                stage[(lg * 4 + r) * 576 + (4 * q + o) * 36 + 16 * hh + n] = oreg[4 * j + o][r];
    }
    __syncthreads();

#pragma unroll
    for (int k = 0; k < 8; ++k) {
        int idx = k * 256 + tid;
        int c   = idx & 7;
        int row = (idx >> 3) & 15;
        int oc  = idx >> 7;
        f32x4 v = *reinterpret_cast<const f32x4*>(&stage[oc * 576 + row * 36 + 4 * c]);
        __builtin_nontemporal_store(v, reinterpret_cast<f32x4*>(
            &out[(((size_t)b * 16 + oc) * 512 + (by + row)) * 512 + bx + 4 * c]));
    }
}

template<bool USE_WS>
__global__ __launch_bounds__(256, 4) void edge_border(
    const float* __restrict__ x,  const float* __restrict__ w1, const float* __restrict__ b1,
    const float* __restrict__ w2, const float* __restrict__ b2,
    const float* __restrict__ wr, const float* __restrict__ br,
    const short* __restrict__ ws, float* __restrict__ out)
{
    __shared__ short fs2[2 * 400 * 8];
    __shared__ short hs4[4 * 324 * 8];
    __shared__ short xs[24 * XS_S];

    const int tid  = threadIdx.x;
    const int lane = tid & 63;
    const int wave = tid >> 6;
    const int n    = lane & 15;
    const int lg   = lane >> 4;

    int idx = blockIdx.x, tx, ty;
    if      (idx < 32) { tx = idx;      ty = 0;  }
    else if (idx < 64) { tx = idx - 32; ty = 31; }
    else if (idx < 94) { tx = 0;        ty = idx - 63; }
    else               { tx = 31;       ty = idx - 93; }
    const int bx = tx * 16, by = ty * 16, b = blockIdx.z;

    for (int i = tid; i < 576; i += 256) {
        int r = i / 24, c = i % 24;
        int gy = by - 4 + r, gx = bx - 4 + c;
        float v = 0.f;
        if (gy >= 0 && gy < 512 && gx >= 0 && gx < 512) v = x[((size_t)b * 512 + gy) * 512 + gx];
        __hip_bfloat16 h = __float2bfloat16(v);
        xs[r * XS_S + c] = *reinterpret_cast<short*>(&h);
    }

    bf16x8 a1[2][5], a2[9], sb;
    float b1v[2][4], b2v[4], wrv[4], brv[4];
    if (USE_WS) {
#pragma unroll
        for (int mt = 0; mt < 2; ++mt)
#pragma unroll
            for (int ks = 0; ks < 5; ++ks)
                a1[mt][ks] = *reinterpret_cast<const bf16x8*>(&ws[((mt * 5 + ks) * 64 + lane) * 8]);
#pragma unroll
        for (int ks = 0; ks < 9; ++ks)
            a2[ks] = *reinterpret_cast<const bf16x8*>(&ws[WS_A2 + (ks * 64 + lane) * 8]);
        sb = *reinterpret_cast<const bf16x8*>(&ws[WS_SB + lane * 8]);
        const float* wf = (const float*)ws + WS_FLT + lane * 20;
        f32x4 t0 = *reinterpret_cast<const f32x4*>(wf);
        f32x4 t1 = *reinterpret_cast<const f32x4*>(wf + 4);
        f32x4 t2 = *reinterpret_cast<const f32x4*>(wf + 8);
        f32x4 t3 = *reinterpret_cast<const f32x4*>(wf + 12);
        f32x4 t4 = *reinterpret_cast<const f32x4*>(wf + 16);
#pragma unroll
        for (int r = 0; r < 4; ++r) {
            b1v[0][r] = t0[r]; b1v[1][r] = t1[r];
            b2v[r] = t2[r]; wrv[r] = t3[r]; brv[r] = t4[r];
        }
    } else {
#pragma unroll
        for (int mt = 0; mt < 2; ++mt)
#pragma unroll
            for (int ks = 0; ks < 5; ++ks)
#pragma unroll
                for (int i = 0; i < 8; ++i) {
                    int k = 32 * ks + 8 * lg + i;
                    int g = k >> 4, ch = k & 15;
                    float w = (g < 9 && ch < 9) ? w1[(mt * 16 + n) * 81 + ch * 9 + g] : 0.f;
                    a1[mt][ks][i] = (short)f2bf(w);
                }
#pragma unroll
        for (int ks = 0; ks < 9; ++ks)
#pragma unroll
            for (int i = 0; i < 8; ++i)
                a2[ks][i] = (short)f2bf(w2[n * 288 + (8 * lg + i) * 9 + ks]);
#pragma unroll
        for (int i = 0; i < 8; ++i) {
            int k = 8 * lg + i;
            float v = (k < 25 && n < 9) ? EB[n][k / 5][k % 5] : 0.f;
            sb[i] = (short)f2bf(v);
        }
#pragma unroll
        for (int r = 0; r < 4; ++r) {
            b1v[0][r] = b1[lg * 4 + r]; b1v[1][r] = b1[16 + lg * 4 + r];
            b2v[r] = b2[lg * 4 + r]; wrv[r] = wr[lg * 4 + r]; brv[r] = br[lg * 4 + r];
        }
    }

    int toff[8];
#pragma unroll
    for (int i = 0; i < 8; ++i) {
        int k = 8 * lg + i;
        int t = k < 25 ? k : 24;
        toff[i] = (t / 5) * XS_S + (t % 5);
    }
    int boff[5];
#pragma unroll
    for (int ks = 0; ks < 5; ++ks) {
        int g = 2 * ks + (lg >> 1); if (g > 8) g = 8;
        int dy = g / 3, dx = g - 3 * dy;
        boff[ks] = (lg & 1) * 3200 + (dy * 20 + dx) * 8;
    }

    __syncthreads();

    for (int t = wave; t < 25; t += 4) {
        int px = t * 16 + n;
        int r = px / 20, c = px - 20 * r;
        const short* base = &xs[r * XS_S + c];
        bf16x8 bv;
#pragma unroll
        for (int i = 0; i < 8; ++i) bv[i] = base[toff[i]];
        f32x4 f = {0.f, 0.f, 0.f, 0.f};
        f = __builtin_amdgcn_mfma_f32_16x16x32_bf16(sb, bv, f, 0, 0, 0);
        int fy = by + r - 2, fx = bx + c - 2;
        float m = (fy >= 0 && fy < 512 && fx >= 0 && fx < 512) ? 1.f : 0.f;
        uint2 wv;
        wv.x = pk2(f[0] * m, f[1] * m);
        wv.y = pk2(f[2] * m, f[3] * m);
        *reinterpret_cast<uint2*>(&fs2[((lg >> 1) * 400 + px) * 8 + 4 * (lg & 1)]) = wv;
    }
    __syncthreads();

    for (int t = wave; t < 21; t += 4) {
        int p  = t * 16 + n;
        int pc = p < 323 ? p : 323;
        int r1 = pc / 18, c1 = pc - 18 * r1;
        int base = (r1 * 20 + c1) * 8;
        f32x4 acc0 = {0.f,0.f,0.f,0.f}, acc1 = {0.f,0.f,0.f,0.f};
#pragma unroll
        for (int ks = 0; ks < 5; ++ks) {
            bf16x8 bf = *reinterpret_cast<const bf16x8*>(&fs2[base + boff[ks]]);
            acc0 = __builtin_amdgcn_mfma_f32_16x16x32_bf16(a1[0][ks], bf, acc0, 0, 0, 0);
            acc1 = __builtin_amdgcn_mfma_f32_16x16x32_bf16(a1[1][ks], bf, acc1, 0, 0, 0);
        }
        if (p < 324) {
            int hy = by - 1 + r1, hx = bx - 1 + c1;
            float m = (hy >= 0 && hy < 512 && hx >= 0 && hx < 512) ? 1.f : 0.f;
            uint2 W0;
            W0.x = pk2(fmaxf(acc0[0] + b1v[0][0], 0.f) * m, fmaxf(acc0[1] + b1v[0][1], 0.f) * m);
            W0.y = pk2(fmaxf(acc0[2] + b1v[0][2], 0.f) * m, fmaxf(acc0[3] + b1v[0][3], 0.f) * m);
            *reinterpret_cast<uint2*>(&hs4[((lg >> 1) * 324 + p) * 8 + 4 * (lg & 1)]) = W0;
            uint2 W1;
            W1.x = pk2(fmaxf(acc1[0] + b1v[1][0], 0.f) * m, fmaxf(acc1[1] + b1v[1][1], 0.f) * m);
            W1.y = pk2(fmaxf(acc1[2] + b1v[1][2], 0.f) * m, fmaxf(acc1[3] + b1v[1][3], 0.f) * m);
            *reinterpret_cast<uint2*>(&hs4[((2 + (lg >> 1)) * 324 + p) * 8 + 4 * (lg & 1)]) = W1;
        }
    }
    __syncthreads();

    const int hbase = lg * 324 * 8;
#pragma unroll
    for (int j = 0; j < 4; ++j) {
        int oy = wave + 4 * j;
        f32x4 acc = {0.f,0.f,0.f,0.f};
#pragma unroll
        for (int ks = 0; ks < 9; ++ks) {
            const int dy = ks / 3, dx = ks - 3 * (ks / 3);
            bf16x8 hf = *reinterpret_cast<const bf16x8*>(
                &hs4[hbase + ((oy + dy) * 18 + n + dx) * 8]);
            acc = __builtin_amdgcn_mfma_f32_16x16x32_bf16(a2[ks], hf, acc, 0, 0, 0);
        }
        __hip_bfloat16 xh = *reinterpret_cast<const __hip_bfloat16*>(&xs[(oy + 4) * XS_S + n + 4]);
        float xv = __bfloat162float(xh);
        float* op = out + (((size_t)(b * 16 + lg * 4) * 512 + (by + oy)) * 512) + bx + n;
#pragma unroll
        for (int r = 0; r < 4; ++r) {
            float o = fmaxf(acc[r] + b2v[r], 0.f) + wrv[r] * xv + brv[r];
            *op = o;
            op += 262144;
        }
    }
}

extern "C" void kernel_launch(void* const* d_in, const int* in_sizes, int n_in,
                              void* d_out, int out_size, void* d_ws, size_t ws_size,
                              hipStream_t stream) {
    const float* x  = (const float*)d_in[0];
    const float* w1 = (const float*)d_in[1];
    const float* b1 = (const float*)d_in[2];
    const float* w2 = (const float*)d_in[3];
    const float* b2 = (const float*)d_in[4];
    const float* wr = (const float*)d_in[5];
    const float* br = (const float*)d_in[6];
    float* out = (float*)d_out;
    short* ws = (short*)d_ws;

    dim3 block(256);
    if (ws_size >= WS_FULL) {
        hipLaunchKernelGGL(setup_all, dim3(1025), block, 0, stream,
                           x, w1, b1, w2, b2, wr, br, ws, 1);
        hipLaunchKernelGGL(edge_main, dim3(4832), block, 0, stream, x, ws, out);
    } else if (ws_size >= WS_BYTES) {
        hipLaunchKernelGGL(setup_all, dim3(1), block, 0, stream,
                           x, w1, b1, w2, b2, wr, br, ws, 0);
        hipLaunchKernelGGL(edge_interior4<true>, dim3(16, 30, 8), block, 0, stream,
                           x, w1, b1, w2, b2, wr, br, ws, out);
        hipLaunchKernelGGL(edge_border<true>, dim3(124, 1, 8), block, 0, stream,
                           x, w1, b1, w2, b2, wr, br, ws, out);
    } else {
        hipLaunchKernelGGL(edge_interior4<false>, dim3(16, 30, 8), block, 0, stream,
                           x, w1, b1, w2, b2, wr, br, ws, out);
        hipLaunchKernelGGL(edge_border<false>, dim3(124, 1, 8), block, 0, stream,
                           x, w1, b1, w2, b2, wr, br, ws, out);
    }
}

// Round 14
// 92.112 us; speedup vs baseline: 2.6203x; 1.0131x over previous
//
#include <hip/hip_runtime.h>
#include <hip/hip_bf16.h>

// EnhancedEdgeLayer R14 (= R13 + stage-conflict fix + P3 deguarding + unroll):
//  - stage oc-stride 576 -> 580 f32 (2320B): lg-groups now hit distinct bank
//    halves -> stage writes 4-way -> 2-way (free). Alignment kept (2320%16==0).
//  - hs pool extended to 624 px: P3 clamp + store-guard removed (rows 612..623
//    are scratch, never read; x reads stay in-bounds for p<=623).
//  - #pragma unroll 2 on P3 slot loop (loads of slot t+1 overlap MFMA of t).
// Structure unchanged: prepass x->bf16 in ws; merged border+interior dispatch
// with disjoint write sets; full-line NT stores from LDS stage.

typedef __attribute__((ext_vector_type(8))) short bf16x8;
typedef __attribute__((ext_vector_type(4))) float f32x4;
typedef unsigned int uint4a __attribute__((ext_vector_type(4), aligned(4)));

#define XS_S 28   // border xs stride (shorts)
#define ST_S 580  // stage oc stride (f32): 2320B, 16B-aligned, bank-spread

// ws layout (shorts unless noted):
//  A1 [2][5][64][8] @0 ; A2 [9][64][8] @5120 ; SB [64][8] @9728
//  FLT floats @ float-off 5120 ; WEFF [2][2][64][8] @12800 ; A2I [9][64][8] @14848
//  xA bf16 @ short 20480 (byte 40960), 2,097,152 shorts ; xB follows
#define WS_A2   5120
#define WS_SB   9728
#define WS_FLT  5120      // float offset
#define WS_WEFF 12800
#define WS_A2I  14848
#define WS_XA   20480     // short offset
#define XB_OFF  2097152   // shorts, xB relative to xA
#define WS_BYTES 38912
#define WS_FULL  8429568u // 40960 + 2*4194304

__device__ const float EB[9][5][5] = {
 {{0,0,0,0,0},{0,-1,0,1,0},{0,-2,0,2,0},{0,-1,0,1,0},{0,0,0,0,0}},
 {{0,0,0,0,0},{0,-1,-2,-1,0},{0,0,0,0,0},{0,1,2,1,0},{0,0,0,0,0}},
 {{0,0,0,0,0},{0,0,1,2,0},{0,-1,0,1,0},{0,-2,-1,0,0},{0,0,0,0,0}},
 {{0,0,0,0,0},{0,-2,-1,0,0},{0,-1,0,1,0},{0,0,1,2,0},{0,0,0,0,0}},
 {{0,0,0,0,0},{0,0,1,0,0},{0,1,-4,1,0},{0,0,1,0,0},{0,0,0,0,0}},
 {{-1,-2,0,2,1},{-2,-3,0,3,2},{-3,-4,0,4,3},{-2,-3,0,3,2},{-1,-2,0,2,1}},
 {{0,0,0,0,0},{0,-3,0,3,0},{0,-10,0,10,0},{0,-3,0,3,0},{0,0,0,0,0}},
 {{0,0,0,0,0},{0,-3,-10,-3,0},{0,0,0,0,0},{0,3,10,3,0},{0,0,0,0,0}},
 {{0,0,0,0,0},{0,0,0,0,0},{0,0,1,0,0},{0,0,0,0,0},{0,0,0,0,0}},
};

__device__ __forceinline__ unsigned short f2bf(float f) {   // cold paths only
    union { float f; unsigned u; } v; v.f = f;
    unsigned u = v.u + 0x7fffu + ((v.u >> 16) & 1u);
    return (unsigned short)(u >> 16);
}
__device__ __forceinline__ unsigned pk2(float lo, float hi) {
    __hip_bfloat162 h = __float22bfloat162_rn(make_float2(lo, hi));
    return *reinterpret_cast<unsigned*>(&h);
}

__device__ __forceinline__ float weff_tap(const float* __restrict__ w1,
                                          int oc, int dy, int dx) {
    float s = 0.f;
    for (int ch = 0; ch < 9; ++ch)
        for (int ty = 0; ty < 3; ++ty)
            for (int tx = 0; tx < 3; ++tx) {
                int sy = dy - ty, sx = dx - tx;
                if (sy >= 0 && sy < 5 && sx >= 0 && sx < 5)
                    s += w1[(oc * 9 + ch) * 9 + ty * 3 + tx] * EB[ch][sy][sx];
            }
    return s;
}

// ---- setup_all: block 0 = fragment tables; blocks 1..1024 = x->bf16 prepass ----
__global__ __launch_bounds__(256) void setup_all(
    const float* __restrict__ x,
    const float* __restrict__ w1, const float* __restrict__ b1,
    const float* __restrict__ w2, const float* __restrict__ b2,
    const float* __restrict__ wr, const float* __restrict__ br,
    short* __restrict__ ws, int do_cvt)
{
    const int tid = threadIdx.x;
    if (blockIdx.x != 0) {
        const int j0 = ((blockIdx.x - 1) * 256 + tid) * 8;   // < 2,097,152
        float4 va = *reinterpret_cast<const float4*>(&x[j0]);
        float4 vb = *reinterpret_cast<const float4*>(&x[j0 + 4]);
        float xn = (j0 + 8 < 2097152) ? x[j0 + 8] : 0.f;
        uint4 A; A.x = pk2(va.x, va.y); A.y = pk2(va.z, va.w);
        A.z = pk2(vb.x, vb.y); A.w = pk2(vb.z, vb.w);
        uint4 B; B.x = pk2(va.y, va.z); B.y = pk2(va.w, vb.x);
        B.z = pk2(vb.y, vb.z); B.w = pk2(vb.w, xn);
        *reinterpret_cast<uint4*>(&ws[WS_XA + j0]) = A;
        *reinterpret_cast<uint4*>(&ws[WS_XA + XB_OFF + j0]) = B;
        return;
    }

    __shared__ float w1s[2592];
    __shared__ float w2s[4608];
    __shared__ float ebs[225];
    for (int i = tid; i < 2592; i += 256) w1s[i] = w1[i];
    for (int i = tid; i < 4608; i += 256) w2s[i] = w2[i];
    if (tid < 225) ebs[tid] = ((const float*)EB)[tid];
    __syncthreads();

    for (int idx = tid; idx < 5120; idx += 256) {           // A1
        int i = idx & 7, lane = (idx >> 3) & 63, rest = idx >> 9;
        int mt = rest / 5, ks = rest - 5 * mt;
        int n = lane & 15, lg = lane >> 4;
        int k = 32 * ks + 8 * lg + i;
        int g = k >> 4, ch = k & 15;
        float w = (g < 9 && ch < 9) ? w1s[(mt * 16 + n) * 81 + ch * 9 + g] : 0.f;
        ws[idx] = (short)f2bf(w);
    }
    for (int idx = tid; idx < 4608; idx += 256) {           // A2 (border)
        int i = idx & 7, lane = (idx >> 3) & 63, ks = idx >> 9;
        int n = lane & 15, lg = lane >> 4;
        ws[WS_A2 + idx] = (short)f2bf(w2s[n * 288 + (8 * lg + i) * 9 + ks]);
    }
    for (int idx = tid; idx < 4608; idx += 256) {           // A2I (interior)
        int i = idx & 7, lane = (idx >> 3) & 63, ks = idx >> 9;
        int n = lane & 15, lg = lane >> 4;
        int ic = ((i & 1) << 4) | (lg << 2) | ((i >> 1) & 3);
        ws[WS_A2I + idx] = (short)f2bf(w2s[n * 288 + ic * 9 + ks]);
    }
    for (int idx = tid; idx < 512; idx += 256) {            // SB
        int i = idx & 7, lane = idx >> 3;
        int n = lane & 15, lg = lane >> 4;
        int k = 8 * lg + i;
        float v = (k < 25 && n < 9) ? ebs[n * 25 + k] : 0.f;
        ws[WS_SB + idx] = (short)f2bf(v);
    }
    for (int idx = tid; idx < 2048; idx += 256) {           // WEFF
        int i = idx & 7, lane = (idx >> 3) & 63, rest = idx >> 9;
        int mt = rest >> 1, ks = rest & 1;
        int n = lane & 15, lg = lane >> 4;
        int dy = 4 * ks + lg, dx = i;
        float s = 0.f;
        if (dy < 7 && dx < 7) {
            int oc = mt * 16 + n;
            for (int ch = 0; ch < 9; ++ch)
                for (int ty = 0; ty < 3; ++ty) {
                    int sy = dy - ty;
                    if (sy < 0 || sy >= 5) continue;
                    for (int tx = 0; tx < 3; ++tx) {
                        int sx = dx - tx;
                        if (sx >= 0 && sx < 5)
                            s += w1s[(oc * 9 + ch) * 9 + ty * 3 + tx] * ebs[ch * 25 + sy * 5 + sx];
                    }
                }
        }
        ws[WS_WEFF + idx] = (short)f2bf(s);
    }
    if (tid < 64) {                                         // FLT
        int lg = tid >> 4;
        float* wf = (float*)ws + WS_FLT + tid * 20;
        for (int r = 0; r < 4; ++r) {
            wf[r]      = b1[lg * 4 + r];
            wf[4 + r]  = b1[16 + lg * 4 + r];
            wf[8 + r]  = b2[lg * 4 + r];
            wf[12 + r] = wr[lg * 4 + r];
            wf[16 + r] = br[lg * 4 + r];
        }
    }
    (void)do_cvt;
}

// ================= merged main kernel (MODE 2) =================
// blocks [0,992): border tiles (R5 path); blocks [992,4832): interior 16x32 tiles.
// Write sets DISJOINT: interior skips cols 0..15 / 496..511 (border-owned).
__global__ __launch_bounds__(256, 4) void edge_main(
    const float* __restrict__ x, const short* __restrict__ ws,
    float* __restrict__ out)
{
    __shared__ long long pool[39936 / 8];   // hs [624 px][32 k] shorts  U  stage [16][ST_S] f32
    const int tid  = threadIdx.x;
    const int lane = tid & 63;
    const int wave = tid >> 6;
    const int n    = lane & 15;
    const int lg   = lane >> 4;
    const int id   = blockIdx.x;

    if (id >= 992) {
        // ---------------- interior ----------------
        short* hsS   = (short*)pool;
        float* stage = (float*)pool;
        const int id2 = id - 992;
        const int bx = (id2 & 15) * 32;
        const int rem = id2 >> 4;
        const int by = (rem % 30 + 1) * 16;
        const int b  = rem / 30;
        const float* xb = x + ((size_t)b << 18);
        const short* xab = ws + WS_XA + b * 262144;

        // P1: fragments
        bf16x8 wa[2][2], a2[9];
        float b1v[2][4], b2v[4], wrv[4], brv[4];
#pragma unroll
        for (int mt = 0; mt < 2; ++mt)
#pragma unroll
            for (int ks = 0; ks < 2; ++ks)
                wa[mt][ks] = *reinterpret_cast<const bf16x8*>(
                    &ws[WS_WEFF + ((mt * 2 + ks) * 64 + lane) * 8]);
#pragma unroll
        for (int ks = 0; ks < 9; ++ks)
            a2[ks] = *reinterpret_cast<const bf16x8*>(&ws[WS_A2I + (ks * 64 + lane) * 8]);
        {
            const float* wf = (const float*)ws + WS_FLT + lane * 20;
            f32x4 t0 = *reinterpret_cast<const f32x4*>(wf);
            f32x4 t1 = *reinterpret_cast<const f32x4*>(wf + 4);
            f32x4 t2 = *reinterpret_cast<const f32x4*>(wf + 8);
            f32x4 t3 = *reinterpret_cast<const f32x4*>(wf + 12);
            f32x4 t4 = *reinterpret_cast<const f32x4*>(wf + 16);
#pragma unroll
            for (int r = 0; r < 4; ++r) {
                b1v[0][r] = t0[r]; b1v[1][r] = t1[r];
                b2v[r] = t2[r]; wrv[r] = t3[r]; brv[r] = t4[r];
            }
        }

        // P3: composed 7x7 from pre-converted bf16 x -> hs (rows 612..623 scratch)
#pragma unroll 2
        for (int t = wave; t < 39; t += 4) {
            int p  = t * 16 + n;
            int r1 = p / 34, c1 = p - 34 * r1;
            int gxb = bx - 4 + c1; gxb = gxb < 0 ? 0 : (gxb > 504 ? 504 : gxb);
            const int off = (by - 4 + r1) * 512 + gxb;
            const short* basep = (gxb & 1) ? (xab + XB_OFF + off - 1) : (xab + off);
            f32x4 acc0 = {0.f,0.f,0.f,0.f}, acc1 = {0.f,0.f,0.f,0.f};
#pragma unroll
            for (int ks = 0; ks < 2; ++ks) {
                const int dy = 4 * ks + lg;   // dy==7 rows: WEFF zero, load safe
                uint4a u = *reinterpret_cast<const uint4a*>(basep + dy * 512);
                bf16x8 bv = __builtin_bit_cast(bf16x8, u);
                acc0 = __builtin_amdgcn_mfma_f32_16x16x32_bf16(wa[0][ks], bv, acc0, 0, 0, 0);
                acc1 = __builtin_amdgcn_mfma_f32_16x16x32_bf16(wa[1][ks], bv, acc1, 0, 0, 0);
            }
            float h0 = fmaxf(acc0[0] + b1v[0][0], 0.f), g0 = fmaxf(acc1[0] + b1v[1][0], 0.f);
            float h1 = fmaxf(acc0[1] + b1v[0][1], 0.f), g1 = fmaxf(acc1[1] + b1v[1][1], 0.f);
            float h2 = fmaxf(acc0[2] + b1v[0][2], 0.f), g2 = fmaxf(acc1[2] + b1v[1][2], 0.f);
            float h3 = fmaxf(acc0[3] + b1v[0][3], 0.f), g3 = fmaxf(acc1[3] + b1v[1][3], 0.f);
            uint4 W;
            W.x = pk2(h0, g0); W.y = pk2(h1, g1); W.z = pk2(h2, g2); W.w = pk2(h3, g3);
            const int grp = lg ^ (p & 3) ^ ((p >> 2) & 3);
            *reinterpret_cast<uint4*>(&hsS[p * 32 + grp * 8]) = W;
        }
        __syncthreads();

        // P4: conv2, quad-row blocking
        const int q0 = wave >> 1;
        const int hh = wave & 1;
        f32x4 oreg[8];
#pragma unroll
        for (int j = 0; j < 2; ++j) {
            const int q = q0 + 2 * j;
            f32x4 acc[4] = {{0.f,0.f,0.f,0.f},{0.f,0.f,0.f,0.f},
                            {0.f,0.f,0.f,0.f},{0.f,0.f,0.f,0.f}};
#pragma unroll
            for (int rr = 0; rr < 6; ++rr) {
                const int pxb = (4 * q + rr) * 34 + 16 * hh + n;
#pragma unroll
                for (int dx = 0; dx < 3; ++dx) {
                    const int px = pxb + dx;
                    const int grp = lg ^ (px & 3) ^ ((px >> 2) & 3);
                    bf16x8 hf = *reinterpret_cast<const bf16x8*>(&hsS[px * 32 + grp * 8]);
#pragma unroll
                    for (int o = 0; o < 4; ++o) {
                        const int dy = rr - o;
                        if (dy >= 0 && dy < 3)
                            acc[o] = __builtin_amdgcn_mfma_f32_16x16x32_bf16(
                                a2[dy * 3 + dx], hf, acc[o], 0, 0, 0);
                    }
                }
            }
#pragma unroll
            for (int o = 0; o < 4; ++o) {
                const int oy = 4 * q + o;
                float xv = xb[((size_t)(by + oy) << 9) + bx + 16 * hh + n];
                f32x4 ov;
#pragma unroll
                for (int r = 0; r < 4; ++r)
                    ov[r] = fmaxf(acc[o][r] + b2v[r], 0.f) + wrv[r] * xv + brv[r];
                oreg[4 * j + o] = ov;
            }
        }
        __syncthreads();

        // stage (oc stride ST_S=580: bank-spread) + full-line NT copy
#pragma unroll
        for (int j = 0; j < 2; ++j) {
            const int q = q0 + 2 * j;
#pragma unroll
            for (int o = 0; o < 4; ++o)
#pragma unroll
                for (int r = 0; r < 4; ++r)
                    stage[(lg * 4 + r) * ST_S + (4 * q + o) * 36 + 16 * hh + n] = oreg[4 * j + o][r];
        }
        __syncthreads();
#pragma unroll
        for (int k = 0; k < 8; ++k) {
            int idx = k * 256 + tid;
            int c   = idx & 7;
            int row = (idx >> 3) & 15;
            int oc  = idx >> 7;
            // border kernel owns cols [0,16) and [496,512): do not write them
            if ((bx == 0 && c < 4) || (bx == 480 && c >= 4)) continue;
            f32x4 v = *reinterpret_cast<const f32x4*>(&stage[oc * ST_S + row * 36 + 4 * c]);
            __builtin_nontemporal_store(v, reinterpret_cast<f32x4*>(
                &out[(((size_t)b * 16 + oc) * 512 + (by + row)) * 512 + bx + 4 * c]));
        }
        return;
    }

    // ---------------- border (R5 path) ----------------
    {
        short* fs2 = (short*)pool;            // 6400 shorts
        short* hs4 = (short*)pool + 6400;     // 10368 shorts
        short* xs  = (short*)pool + 16768;    // 672 shorts

        const int b = id / 124;
        int t4 = id - b * 124, tx, ty;
        if      (t4 < 32) { tx = t4;      ty = 0;  }
        else if (t4 < 64) { tx = t4 - 32; ty = 31; }
        else if (t4 < 94) { tx = 0;       ty = t4 - 63; }
        else              { tx = 31;      ty = t4 - 93; }
        const int bx = tx * 16, by = ty * 16;

        for (int i = tid; i < 576; i += 256) {
            int r = i / 24, c = i % 24;
            int gy = by - 4 + r, gx = bx - 4 + c;
            float v = 0.f;
            if (gy >= 0 && gy < 512 && gx >= 0 && gx < 512)
                v = x[((size_t)b * 512 + gy) * 512 + gx];
            __hip_bfloat16 h = __float2bfloat16(v);
            xs[r * XS_S + c] = *reinterpret_cast<short*>(&h);
        }

        bf16x8 a1[2][5], a2[9], sb;
        float b1v[2][4], b2v[4], wrv[4], brv[4];
#pragma unroll
        for (int mt = 0; mt < 2; ++mt)
#pragma unroll
            for (int ks = 0; ks < 5; ++ks)
                a1[mt][ks] = *reinterpret_cast<const bf16x8*>(&ws[((mt * 5 + ks) * 64 + lane) * 8]);
#pragma unroll
        for (int ks = 0; ks < 9; ++ks)
            a2[ks] = *reinterpret_cast<const bf16x8*>(&ws[WS_A2 + (ks * 64 + lane) * 8]);
        sb = *reinterpret_cast<const bf16x8*>(&ws[WS_SB + lane * 8]);
        {
            const float* wf = (const float*)ws + WS_FLT + lane * 20;
            f32x4 t0 = *reinterpret_cast<const f32x4*>(wf);
            f32x4 t1 = *reinterpret_cast<const f32x4*>(wf + 4);
            f32x4 t2 = *reinterpret_cast<const f32x4*>(wf + 8);
            f32x4 t3 = *reinterpret_cast<const f32x4*>(wf + 12);
            f32x4 t4 = *reinterpret_cast<const f32x4*>(wf + 16);
#pragma unroll
            for (int r = 0; r < 4; ++r) {
                b1v[0][r] = t0[r]; b1v[1][r] = t1[r];
                b2v[r] = t2[r]; wrv[r] = t3[r]; brv[r] = t4[r];
            }
        }

        int toff[8];
#pragma unroll
        for (int i = 0; i < 8; ++i) {
            int k = 8 * lg + i;
            int t = k < 25 ? k : 24;
            toff[i] = (t / 5) * XS_S + (t % 5);
        }
        int boff[5];
#pragma unroll
        for (int ks = 0; ks < 5; ++ks) {
            int g = 2 * ks + (lg >> 1); if (g > 8) g = 8;
            int dy = g / 3, dx = g - 3 * dy;
            boff[ks] = (lg & 1) * 3200 + (dy * 20 + dx) * 8;
        }

        __syncthreads();

        for (int t = wave; t < 25; t += 4) {
            int px = t * 16 + n;
            int r = px / 20, c = px - 20 * r;
            const short* base = &xs[r * XS_S + c];
            bf16x8 bv;
#pragma unroll
            for (int i = 0; i < 8; ++i) bv[i] = base[toff[i]];
            f32x4 f = {0.f, 0.f, 0.f, 0.f};
            f = __builtin_amdgcn_mfma_f32_16x16x32_bf16(sb, bv, f, 0, 0, 0);
            int fy = by + r - 2, fx = bx + c - 2;
            float m = (fy >= 0 && fy < 512 && fx >= 0 && fx < 512) ? 1.f : 0.f;
            uint2 wv;
            wv.x = pk2(f[0] * m, f[1] * m);
            wv.y = pk2(f[2] * m, f[3] * m);
            *reinterpret_cast<uint2*>(&fs2[((lg >> 1) * 400 + px) * 8 + 4 * (lg & 1)]) = wv;
        }
        __syncthreads();

        for (int t = wave; t < 21; t += 4) {
            int p  = t * 16 + n;
            int pc = p < 323 ? p : 323;
            int r1 = pc / 18, c1 = pc - 18 * r1;
            int base = (r1 * 20 + c1) * 8;
            f32x4 acc0 = {0.f,0.f,0.f,0.f}, acc1 = {0.f,0.f,0.f,0.f};
#pragma unroll
            for (int ks = 0; ks < 5; ++ks) {
                bf16x8 bf = *reinterpret_cast<const bf16x8*>(&fs2[base + boff[ks]]);
                acc0 = __builtin_amdgcn_mfma_f32_16x16x32_bf16(a1[0][ks], bf, acc0, 0, 0, 0);
                acc1 = __builtin_amdgcn_mfma_f32_16x16x32_bf16(a1[1][ks], bf, acc1, 0, 0, 0);
            }
            if (p < 324) {
                int hy = by - 1 + r1, hx = bx - 1 + c1;
                float m = (hy >= 0 && hy < 512 && hx >= 0 && hx < 512) ? 1.f : 0.f;
                uint2 W0;
                W0.x = pk2(fmaxf(acc0[0] + b1v[0][0], 0.f) * m, fmaxf(acc0[1] + b1v[0][1], 0.f) * m);
                W0.y = pk2(fmaxf(acc0[2] + b1v[0][2], 0.f) * m, fmaxf(acc0[3] + b1v[0][3], 0.f) * m);
                *reinterpret_cast<uint2*>(&hs4[((lg >> 1) * 324 + p) * 8 + 4 * (lg & 1)]) = W0;
                uint2 W1;
                W1.x = pk2(fmaxf(acc1[0] + b1v[1][0], 0.f) * m, fmaxf(acc1[1] + b1v[1][1], 0.f) * m);
                W1.y = pk2(fmaxf(acc1[2] + b1v[1][2], 0.f) * m, fmaxf(acc1[3] + b1v[1][3], 0.f) * m);
                *reinterpret_cast<uint2*>(&hs4[((2 + (lg >> 1)) * 324 + p) * 8 + 4 * (lg & 1)]) = W1;
            }
        }
        __syncthreads();

        const int hbase = lg * 324 * 8;
#pragma unroll
        for (int j = 0; j < 4; ++j) {
            int oy = wave + 4 * j;
            f32x4 acc = {0.f,0.f,0.f,0.f};
#pragma unroll
            for (int ks = 0; ks < 9; ++ks) {
                const int dy = ks / 3, dx = ks - 3 * (ks / 3);
                bf16x8 hf = *reinterpret_cast<const bf16x8*>(
                    &hs4[hbase + ((oy + dy) * 18 + n + dx) * 8]);
                acc = __builtin_amdgcn_mfma_f32_16x16x32_bf16(a2[ks], hf, acc, 0, 0, 0);
            }
            __hip_bfloat16 xh = *reinterpret_cast<const __hip_bfloat16*>(&xs[(oy + 4) * XS_S + n + 4]);
            float xv = __bfloat162float(xh);
            float* op = out + (((size_t)(b * 16 + lg * 4) * 512 + (by + oy)) * 512) + bx + n;
#pragma unroll
            for (int r = 0; r < 4; ++r) {
                float o = fmaxf(acc[r] + b2v[r], 0.f) + wrv[r] * xv + brv[r];
                *op = o;
                op += 262144;
            }
        }
    }
}

// ================= fallback kernels (MODE 1 / 0), unchanged from R13 =========
template<bool USE_WS>
__global__ __launch_bounds__(256, 4) void edge_interior4(
    const float* __restrict__ x,  const float* __restrict__ w1, const float* __restrict__ b1,
    const float* __restrict__ w2, const float* __restrict__ b2,
    const float* __restrict__ wr, const float* __restrict__ br,
    const short* __restrict__ ws, float* __restrict__ out)
{
    __shared__ long long pool[39168 / 8];
    short* hsS   = (short*)pool;
    float* stage = (float*)pool;

    const int tid  = threadIdx.x;
    const int lane = tid & 63;
    const int wave = tid >> 6;
    const int n    = lane & 15;
    const int lg   = lane >> 4;
    const int bx = blockIdx.x * 32;
    const int by = (blockIdx.y + 1) * 16;
    const int b  = blockIdx.z;
    const float* xb = x + ((size_t)b << 18);

    bf16x8 wa[2][2], a2[9];
    float b1v[2][4], b2v[4], wrv[4], brv[4];
    if (USE_WS) {
#pragma unroll
        for (int mt = 0; mt < 2; ++mt)
#pragma unroll
            for (int ks = 0; ks < 2; ++ks)
                wa[mt][ks] = *reinterpret_cast<const bf16x8*>(
                    &ws[WS_WEFF + ((mt * 2 + ks) * 64 + lane) * 8]);
#pragma unroll
        for (int ks = 0; ks < 9; ++ks)
            a2[ks] = *reinterpret_cast<const bf16x8*>(&ws[WS_A2I + (ks * 64 + lane) * 8]);
        const float* wf = (const float*)ws + WS_FLT + lane * 20;
        f32x4 t0 = *reinterpret_cast<const f32x4*>(wf);
        f32x4 t1 = *reinterpret_cast<const f32x4*>(wf + 4);
        f32x4 t2 = *reinterpret_cast<const f32x4*>(wf + 8);
        f32x4 t3 = *reinterpret_cast<const f32x4*>(wf + 12);
        f32x4 t4 = *reinterpret_cast<const f32x4*>(wf + 16);
#pragma unroll
        for (int r = 0; r < 4; ++r) {
            b1v[0][r] = t0[r]; b1v[1][r] = t1[r];
            b2v[r] = t2[r]; wrv[r] = t3[r]; brv[r] = t4[r];
        }
    } else {
#pragma unroll
        for (int mt = 0; mt < 2; ++mt)
#pragma unroll
            for (int ks = 0; ks < 2; ++ks)
#pragma unroll
                for (int i = 0; i < 8; ++i) {
                    int dy = 4 * ks + lg, dx = i;
                    float s = (dy < 7 && dx < 7) ? weff_tap(w1, mt * 16 + n, dy, dx) : 0.f;
                    wa[mt][ks][i] = (short)f2bf(s);
                }
#pragma unroll
        for (int ks = 0; ks < 9; ++ks)
#pragma unroll
            for (int i = 0; i < 8; ++i) {
                int ic = ((i & 1) << 4) | (lg << 2) | ((i >> 1) & 3);
                a2[ks][i] = (short)f2bf(w2[(n * 32 + ic) * 9 + ks]);
            }
#pragma unroll
        for (int r = 0; r < 4; ++r) {
            b1v[0][r] = b1[lg * 4 + r]; b1v[1][r] = b1[16 + lg * 4 + r];
            b2v[r] = b2[lg * 4 + r]; wrv[r] = wr[lg * 4 + r]; brv[r] = br[lg * 4 + r];
        }
    }

    for (int t = wave; t < 39; t += 4) {
        int p  = t * 16 + n;
        int pc = p < 611 ? p : 611;
        int r1 = pc / 34, c1 = pc - 34 * r1;
        int gxb = bx - 4 + c1; gxb = gxb < 0 ? 0 : (gxb > 504 ? 504 : gxb);
        const int gyb = by - 4 + r1;
        f32x4 acc0 = {0.f,0.f,0.f,0.f}, acc1 = {0.f,0.f,0.f,0.f};
#pragma unroll
        for (int ks = 0; ks < 2; ++ks) {
            const int dy = 4 * ks + lg;
            bf16x8 bv = {0,0,0,0,0,0,0,0};
            if (dy < 7) {
                const float* xp = xb + ((size_t)(gyb + dy) << 9) + gxb;
                uint4 u;
                u.x = pk2(xp[0], xp[1]); u.y = pk2(xp[2], xp[3]);
                u.z = pk2(xp[4], xp[5]); u.w = pk2(xp[6], xp[7]);
                bv = *reinterpret_cast<bf16x8*>(&u);
            }
            acc0 = __builtin_amdgcn_mfma_f32_16x16x32_bf16(wa[0][ks], bv, acc0, 0, 0, 0);
            acc1 = __builtin_amdgcn_mfma_f32_16x16x32_bf16(wa[1][ks], bv, acc1, 0, 0, 0);
        }
        if (p < 612) {
            float h0 = fmaxf(acc0[0] + b1v[0][0], 0.f), g0 = fmaxf(acc1[0] + b1v[1][0], 0.f);
            float h1 = fmaxf(acc0[1] + b1v[0][1], 0.f), g1 = fmaxf(acc1[1] + b1v[1][1], 0.f);
            float h2 = fmaxf(acc0[2] + b1v[0][2], 0.f), g2 = fmaxf(acc1[2] + b1v[1][2], 0.f);
            float h3 = fmaxf(acc0[3] + b1v[0][3], 0.f), g3 = fmaxf(acc1[3] + b1v[1][3], 0.f);
            uint4 W;
            W.x = pk2(h0, g0); W.y = pk2(h1, g1); W.z = pk2(h2, g2); W.w = pk2(h3, g3);
            const int grp = lg ^ (p & 3) ^ ((p >> 2) & 3);
            *reinterpret_cast<uint4*>(&hsS[p * 32 + grp * 8]) = W;
        }
    }
    __syncthreads();

    const int q0 = wave >> 1;
    const int hh = wave & 1;
    f32x4 oreg[8];
#pragma unroll
    for (int j = 0; j < 2; ++j) {
        const int q = q0 + 2 * j;
        f32x4 acc[4] = {{0.f,0.f,0.f,0.f},{0.f,0.f,0.f,0.f},
                        {0.f,0.f,0.f,0.f},{0.f,0.f,0.f,0.f}};
#pragma unroll
        for (int rr = 0; rr < 6; ++rr) {
            const int pxb = (4 * q + rr) * 34 + 16 * hh + n;
#pragma unroll
            for (int dx = 0; dx < 3; ++dx) {
                const int px = pxb + dx;
                const int grp = lg ^ (px & 3) ^ ((px >> 2) & 3);
                bf16x8 hf = *reinterpret_cast<const bf16x8*>(&hsS[px * 32 + grp * 8]);
#pragma unroll
                for (int o = 0; o < 4; ++o) {
                    const int dy = rr - o;
                    if (dy >= 0 && dy < 3)
                        acc[o] = __builtin_amdgcn_mfma_f32_16x16x32_bf16(
                            a2[dy * 3 + dx], hf, acc[o], 0, 0, 0);
                }
            }
        }
#pragma unroll
        for (int o = 0; o < 4; ++o) {
            const int oy = 4 * q + o;
            float xv = xb[((size_t)(by + oy) << 9) + bx + 16 * hh + n];
            f32x4 ov;
#pragma unroll
            for (int r = 0; r < 4; ++r)
                ov[r] = fmaxf(acc[o][r] + b2v[r], 0.f) + wrv[r] * xv + brv[r];
            oreg[4 * j + o] = ov;
        }
    }
    __syncthreads();

#pragma unroll
    for (int j = 0; j < 2; ++j) {
        const int q = q0 + 2 * j;
#pragma unroll
        for (int o = 0; o < 4; ++o)
#pragma unroll
            for (int r = 0; r < 4; ++r)
                stage[(lg * 4 + r) * 576 + (4 * q + o) * 36 + 16 * hh + n] = oreg[4 * j + o][r];
    }
    __syncthreads();

#pragma unroll
    for (int k = 0; k < 8; ++k) {
        int idx = k * 256 + tid;
        int c   = idx & 7;
        int row = (idx >> 3) & 15;
        int oc  = idx >> 7;
        f32x4 v = *reinterpret_cast<const f32x4*>(&stage[oc * 576 + row * 36 + 4 * c]);
        __builtin_nontemporal_store(v, reinterpret_cast<f32x4*>(
            &out[(((size_t)b * 16 + oc) * 512 + (by + row)) * 512 + bx + 4 * c]));
    }
}

template<bool USE_WS>
__global__ __launch_bounds__(256, 4) void edge_border(
    const float* __restrict__ x,  const float* __restrict__ w1, const float* __restrict__ b1,
    const float* __restrict__ w2, const float* __restrict__ b2,
    const float* __restrict__ wr, const float* __restrict__ br,
    const short* __restrict__ ws, float* __restrict__ out)
{
    __shared__ short fs2[2 * 400 * 8];
    __shared__ short hs4[4 * 324 * 8];
    __shared__ short xs[24 * XS_S];

    const int tid  = threadIdx.x;
    const int lane = tid & 63;
    const int wave = tid >> 6;
    const int n    = lane & 15;
    const int lg   = lane >> 4;

    int idx = blockIdx.x, tx, ty;
    if      (idx < 32) { tx = idx;      ty = 0;  }
    else if (idx < 64) { tx = idx - 32; ty = 31; }
    else if (idx < 94) { tx = 0;        ty = idx - 63; }
    else               { tx = 31;       ty = idx - 93; }
    const int bx = tx * 16, by = ty * 16, b = blockIdx.z;

    for (int i = tid; i < 576; i += 256) {
        int r = i / 24, c = i % 24;
        int gy = by - 4 + r, gx = bx - 4 + c;
        float v = 0.f;
        if (gy >= 0 && gy < 512 && gx >= 0 && gx < 512) v = x[((size_t)b * 512 + gy) * 512 + gx];
        __hip_bfloat16 h = __float2bfloat16(v);
        xs[r * XS_S + c] = *reinterpret_cast<short*>(&h);
    }

    bf16x8 a1[2][5], a2[9], sb;
    float b1v[2][4], b2v[4], wrv[4], brv[4];
    if (USE_WS) {
#pragma unroll
        for (int mt = 0; mt < 2; ++mt)
#pragma unroll
            for (int ks = 0; ks < 5; ++ks)
                a1[mt][ks] = *reinterpret_cast<const bf16x8*>(&ws[((mt * 5 + ks) * 64 + lane) * 8]);
#pragma unroll
        for (int ks = 0; ks < 9; ++ks)
            a2[ks] = *reinterpret_cast<const bf16x8*>(&ws[WS_A2 + (ks * 64 + lane) * 8]);
        sb = *reinterpret_cast<const bf16x8*>(&ws[WS_SB + lane * 8]);
        const float* wf = (const float*)ws + WS_FLT + lane * 20;
        f32x4 t0 = *reinterpret_cast<const f32x4*>(wf);
        f32x4 t1 = *reinterpret_cast<const f32x4*>(wf + 4);
        f32x4 t2 = *reinterpret_cast<const f32x4*>(wf + 8);
        f32x4 t3 = *reinterpret_cast<const f32x4*>(wf + 12);
        f32x4 t4 = *reinterpret_cast<const f32x4*>(wf + 16);
#pragma unroll
        for (int r = 0; r < 4; ++r) {
            b1v[0][r] = t0[r]; b1v[1][r] = t1[r];
            b2v[r] = t2[r]; wrv[r] = t3[r]; brv[r] = t4[r];
        }
    } else {
#pragma unroll
        for (int mt = 0; mt < 2; ++mt)
#pragma unroll
            for (int ks = 0; ks < 5; ++ks)
#pragma unroll
                for (int i = 0; i < 8; ++i) {
                    int k = 32 * ks + 8 * lg + i;
                    int g = k >> 4, ch = k & 15;
                    float w = (g < 9 && ch < 9) ? w1[(mt * 16 + n) * 81 + ch * 9 + g] : 0.f;
                    a1[mt][ks][i] = (short)f2bf(w);
                }
#pragma unroll
        for (int ks = 0; ks < 9; ++ks)
#pragma unroll
            for (int i = 0; i < 8; ++i)
                a2[ks][i] = (short)f2bf(w2[n * 288 + (8 * lg + i) * 9 + ks]);
#pragma unroll
        for (int i = 0; i < 8; ++i) {
            int k = 8 * lg + i;
            float v = (k < 25 && n < 9) ? EB[n][k / 5][k % 5] : 0.f;
            sb[i] = (short)f2bf(v);
        }
#pragma unroll
        for (int r = 0; r < 4; ++r) {
            b1v[0][r] = b1[lg * 4 + r]; b1v[1][r] = b1[16 + lg * 4 + r];
            b2v[r] = b2[lg * 4 + r]; wrv[r] = wr[lg * 4 + r]; brv[r] = br[lg * 4 + r];
        }
    }

    int toff[8];
#pragma unroll
    for (int i = 0; i < 8; ++i) {
        int k = 8 * lg + i;
        int t = k < 25 ? k : 24;
        toff[i] = (t / 5) * XS_S + (t % 5);
    }
    int boff[5];
#pragma unroll
    for (int ks = 0; ks < 5; ++ks) {
        int g = 2 * ks + (lg >> 1); if (g > 8) g = 8;
        int dy = g / 3, dx = g - 3 * dy;
        boff[ks] = (lg & 1) * 3200 + (dy * 20 + dx) * 8;
    }

    __syncthreads();

    for (int t = wave; t < 25; t += 4) {
        int px = t * 16 + n;
        int r = px / 20, c = px - 20 * r;
        const short* base = &xs[r * XS_S + c];
        bf16x8 bv;
#pragma unroll
        for (int i = 0; i < 8; ++i) bv[i] = base[toff[i]];
        f32x4 f = {0.f, 0.f, 0.f, 0.f};
        f = __builtin_amdgcn_mfma_f32_16x16x32_bf16(sb, bv, f, 0, 0, 0);
        int fy = by + r - 2, fx = bx + c - 2;
        float m = (fy >= 0 && fy < 512 && fx >= 0 && fx < 512) ? 1.f : 0.f;
        uint2 wv;
        wv.x = pk2(f[0] * m, f[1] * m);
        wv.y = pk2(f[2] * m, f[3] * m);
        *reinterpret_cast<uint2*>(&fs2[((lg >> 1) * 400 + px) * 8 + 4 * (lg & 1)]) = wv;
    }
    __syncthreads();

    for (int t = wave; t < 21; t += 4) {
        int p  = t * 16 + n;
        int pc = p < 323 ? p : 323;
        int r1 = pc / 18, c1 = pc - 18 * r1;
        int base = (r1 * 20 + c1) * 8;
        f32x4 acc0 = {0.f,0.f,0.f,0.f}, acc1 = {0.f,0.f,0.f,0.f};
#pragma unroll
        for (int ks = 0; ks < 5; ++ks) {
            bf16x8 bf = *reinterpret_cast<const bf16x8*>(&fs2[base + boff[ks]]);
            acc0 = __builtin_amdgcn_mfma_f32_16x16x32_bf16(a1[0][ks], bf, acc0, 0, 0, 0);
            acc1 = __builtin_amdgcn_mfma_f32_16x16x32_bf16(a1[1][ks], bf, acc1, 0, 0, 0);
        }
        if (p < 324) {
            int hy = by - 1 + r1, hx = bx - 1 + c1;
            float m = (hy >= 0 && hy < 512 && hx >= 0 && hx < 512) ? 1.f : 0.f;
            uint2 W0;
            W0.x = pk2(fmaxf(acc0[0] + b1v[0][0], 0.f) * m, fmaxf(acc0[1] + b1v[0][1], 0.f) * m);
            W0.y = pk2(fmaxf(acc0[2] + b1v[0][2], 0.f) * m, fmaxf(acc0[3] + b1v[0][3], 0.f) * m);
            *reinterpret_cast<uint2*>(&hs4[((lg >> 1) * 324 + p) * 8 + 4 * (lg & 1)]) = W0;
            uint2 W1;
            W1.x = pk2(fmaxf(acc1[0] + b1v[1][0], 0.f) * m, fmaxf(acc1[1] + b1v[1][1], 0.f) * m);
            W1.y = pk2(fmaxf(acc1[2] + b1v[1][2], 0.f) * m, fmaxf(acc1[3] + b1v[1][3], 0.f) * m);
            *reinterpret_cast<uint2*>(&hs4[((2 + (lg >> 1)) * 324 + p) * 8 + 4 * (lg & 1)]) = W1;
        }
    }
    __syncthreads();

    const int hbase = lg * 324 * 8;
#pragma unroll
    for (int j = 0; j < 4; ++j) {
        int oy = wave + 4 * j;
        f32x4 acc = {0.f,0.f,0.f,0.f};
#pragma unroll
        for (int ks = 0; ks < 9; ++ks) {
            const int dy = ks / 3, dx = ks - 3 * (ks / 3);
            bf16x8 hf = *reinterpret_cast<const bf16x8*>(
                &hs4[hbase + ((oy + dy) * 18 + n + dx) * 8]);
            acc = __builtin_amdgcn_mfma_f32_16x16x32_bf16(a2[ks], hf, acc, 0, 0, 0);
        }
        __hip_bfloat16 xh = *reinterpret_cast<const __hip_bfloat16*>(&xs[(oy + 4) * XS_S + n + 4]);
        float xv = __bfloat162float(xh);
        float* op = out + (((size_t)(b * 16 + lg * 4) * 512 + (by + oy)) * 512) + bx + n;
#pragma unroll
        for (int r = 0; r < 4; ++r) {
            float o = fmaxf(acc[r] + b2v[r], 0.f) + wrv[r] * xv + brv[r];
            *op = o;
            op += 262144;
        }
    }
}

extern "C" void kernel_launch(void* const* d_in, const int* in_sizes, int n_in,
                              void* d_out, int out_size, void* d_ws, size_t ws_size,
                              hipStream_t stream) {
    const float* x  = (const float*)d_in[0];
    const float* w1 = (const float*)d_in[1];
    const float* b1 = (const float*)d_in[2];
    const float* w2 = (const float*)d_in[3];
    const float* b2 = (const float*)d_in[4];
    const float* wr = (const float*)d_in[5];
    const float* br = (const float*)d_in[6];
    float* out = (float*)d_out;
    short* ws = (short*)d_ws;

    dim3 block(256);
    if (ws_size >= WS_FULL) {
        hipLaunchKernelGGL(setup_all, dim3(1025), block, 0, stream,
                           x, w1, b1, w2, b2, wr, br, ws, 1);
        hipLaunchKernelGGL(edge_main, dim3(4832), block, 0, stream, x, ws, out);
    } else if (ws_size >= WS_BYTES) {
        hipLaunchKernelGGL(setup_all, dim3(1), block, 0, stream,
                           x, w1, b1, w2, b2, wr, br, ws, 0);
        hipLaunchKernelGGL(edge_interior4<true>, dim3(16, 30, 8), block, 0, stream,
                           x, w1, b1, w2, b2, wr, br, ws, out);
        hipLaunchKernelGGL(edge_border<true>, dim3(124, 1, 8), block, 0, stream,
                           x, w1, b1, w2, b2, wr, br, ws, out);
    } else {
        hipLaunchKernelGGL(edge_interior4<false>, dim3(16, 30, 8), block, 0, stream,
                           x, w1, b1, w2, b2, wr, br, ws, out);
        hipLaunchKernelGGL(edge_border<false>, dim3(124, 1, 8), block, 0, stream,
                           x, w1, b1, w2, b2, wr, br, ws, out);
    }
}